// Round 15
// baseline (786.464 us; speedup 1.0000x reference)
//
#include <hip/hip_runtime.h>
#include <math.h>

typedef float f4 __attribute__((ext_vector_type(4)));
typedef float f2 __attribute__((ext_vector_type(2)));
typedef float f32x4 __attribute__((ext_vector_type(4)));
typedef _Float16 h8 __attribute__((ext_vector_type(8)));

constexpr int B_ = 4, C_ = 96, T_ = 320, F_ = 256;
constexpr int TF_ = T_ * F_;          // 81920
constexpr float EPS_ = 1e-5f;
constexpr size_t QH_ = (size_t)C_ * TF_;   // 7,864,320 elems per (C,T,F) unit

// W-split scratch layout (f16 elems, appended after the G*3 data units):
constexpr int WHF = 0, WLF = 27648, WHT = 55296, WLT = 73728,
              WHP = 92160, WLP = 101376, WTOT = 110592;

// ---------------------------------------------------------------------------
// One-time prep: split W into hi/lo f16; precompute BN (sc, sh) per channel.
// ---------------------------------------------------------------------------
__global__ __launch_bounds__(256)
void prep_kernel(const float* __restrict__ Wf, const float* __restrict__ Wt,
                 const float* __restrict__ Wp,
                 const float* __restrict__ bf, const float* __restrict__ gf,
                 const float* __restrict__ bef, const float* __restrict__ mf,
                 const float* __restrict__ vf,
                 const float* __restrict__ bt, const float* __restrict__ gt,
                 const float* __restrict__ bet, const float* __restrict__ mt,
                 const float* __restrict__ vt,
                 const float* __restrict__ bp, const float* __restrict__ gp,
                 const float* __restrict__ bep, const float* __restrict__ mp,
                 const float* __restrict__ vp,
                 _Float16* __restrict__ wsp, float* __restrict__ scsh)
{
    const int gtid = blockIdx.x * 256 + threadIdx.x;
    const int gsz  = gridDim.x * 256;
    for (int i = gtid; i < 27648; i += gsz) {
        const float w = Wf[i]; const _Float16 h = (_Float16)w;
        wsp[WHF + i] = h; wsp[WLF + i] = (_Float16)(w - (float)h);
    }
    for (int i = gtid; i < 18432; i += gsz) {
        const float w = Wt[i]; const _Float16 h = (_Float16)w;
        wsp[WHT + i] = h; wsp[WLT + i] = (_Float16)(w - (float)h);
    }
    for (int i = gtid; i < 9216; i += gsz) {
        const float w = Wp[i]; const _Float16 h = (_Float16)w;
        wsp[WHP + i] = h; wsp[WLP + i] = (_Float16)(w - (float)h);
    }
    if (gtid < 288) {
        const float sc = gf[gtid] * rsqrtf(vf[gtid] + EPS_);
        scsh[2 * gtid] = sc;
        scsh[2 * gtid + 1] = fmaf(bf[gtid] - mf[gtid], sc, bef[gtid]);
    } else if (gtid < 480) {
        const int i = gtid - 288;
        const float sc = gt[i] * rsqrtf(vt[i] + EPS_);
        scsh[576 + 2 * i] = sc;
        scsh[576 + 2 * i + 1] = fmaf(bt[i] - mt[i], sc, bet[i]);
    } else if (gtid < 576) {
        const int i = gtid - 480;
        const float sc = gp[i] * rsqrtf(vp[i] + EPS_);
        scsh[960 + 2 * i] = sc;
        scsh[960 + 2 * i + 1] = fmaf(bp[i] - mp[i], sc, bep[i]);
    }
}

// ---------------------------------------------------------------------------
// Fused conv_f + conv_t, group-parallel: one block = one (p-tile, group).
// Sibling-clustering swizzle: id = pchunk*40 + group*8 + p%8 keeps a p-tile's
// 5 group-siblings on the SAME XCD in a 40-id window -> X fetched from HBM
// once, 4 L2 hits.  Body per group identical to the proven round-11 kernel
// (inline W loads, compiler-scheduled, launch_bounds(256,3), 64 VGPR).
// ---------------------------------------------------------------------------
__global__ __launch_bounds__(256, 3)
void conv_ft(const float* __restrict__ x, const _Float16* __restrict__ wsp,
             const float* __restrict__ scsh,
             const float* __restrict__ aPf, const float* __restrict__ aPt,
             _Float16* __restrict__ yf, _Float16* __restrict__ yt,
             int bsx, int bsyf, int bsyt)
{
    constexpr int LS = 200;
    extern __shared__ _Float16 ldsh[];
    _Float16* Xs = ldsh;                   // [64][200]: 0-95 hi, 96-191 lo

    x  += (size_t)blockIdx.y * bsx;
    yf += (size_t)blockIdx.y * bsyf;
    yt += (size_t)blockIdx.y * bsyt;

    // ---- sibling-clustering decode: 160 p-chunks x {5 groups x 8 p} ----
    const int id = blockIdx.x;
    const int pc = id / 40, rr = id % 40;
    const int cg = rr >> 3, pl = rr & 7;
    const int p0 = (pc * 8 + pl) * 64;

    const int tid = threadIdx.x;

    // ---- stage X hi/lo: gather 8 k per p, lanes coalesced on p ----
    const float* xg = x + p0;
    for (int e = tid; e < 64 * 12; e += 256) {
        const int p = e & 63, k0 = (e >> 6) * 8;
        const float* xp = xg + (size_t)k0 * TF_ + p;
        h8 hv, lv;
#pragma unroll
        for (int j = 0; j < 8; ++j) {
            const float xv = xp[(size_t)j * TF_];
            const _Float16 xh = (_Float16)xv;
            hv[j] = xh;
            lv[j] = (_Float16)(xv - (float)xh);
        }
        *(h8*)&Xs[p * LS + k0]      = hv;
        *(h8*)&Xs[p * LS + 96 + k0] = lv;
    }

    const int lane = tid & 63, wid = tid >> 6;
    const int l16 = lane & 15, lg = lane >> 4;
    const int wm = wid >> 1, wn = wid & 1;       // 2x2 wave grid
    __syncthreads();

    // ---- this block's single group ----
    const _Float16 *Wh, *Wl; const float* ss; float a; _Float16* yo;
    if (cg < 3) {
        Wh = wsp + WHF + cg * 9216;  Wl = wsp + WLF + cg * 9216;
        ss = scsh + cg * 192;        a = aPf[0];
        yo = yf + (size_t)cg * QH_;
    } else {
        const int c2 = cg - 3;
        Wh = wsp + WHT + c2 * 9216;  Wl = wsp + WLT + c2 * 9216;
        ss = scsh + 576 + c2 * 192;  a = aPt[0];
        yo = yt + (size_t)c2 * QH_;
    }

    f32x4 acc[3][2];
#pragma unroll
    for (int m = 0; m < 3; ++m)
#pragma unroll
        for (int n = 0; n < 2; ++n) acc[m][n] = (f32x4){0.f, 0.f, 0.f, 0.f};

#pragma unroll
    for (int kk = 0; kk < 3; ++kk) {
        h8 bfh[2], bfl[2];
#pragma unroll
        for (int n = 0; n < 2; ++n) {
            const int prow = (wn * 2 + n) * 16 + l16;
            bfh[n] = *(const h8*)&Xs[prow * LS + kk * 32 + lg * 8];
            bfl[n] = *(const h8*)&Xs[prow * LS + 96 + kk * 32 + lg * 8];
        }
#pragma unroll
        for (int m = 0; m < 3; ++m) {
            const int row = (wm * 3 + m) * 16 + l16;
            const h8 wh = *(const h8*)&Wh[row * 96 + kk * 32 + lg * 8];
            const h8 wl = *(const h8*)&Wl[row * 96 + kk * 32 + lg * 8];
#pragma unroll
            for (int n = 0; n < 2; ++n) {
                acc[m][n] = __builtin_amdgcn_mfma_f32_16x16x32_f16(wh, bfh[n], acc[m][n], 0, 0, 0);
                acc[m][n] = __builtin_amdgcn_mfma_f32_16x16x32_f16(wl, bfh[n], acc[m][n], 0, 0, 0);
                acc[m][n] = __builtin_amdgcn_mfma_f32_16x16x32_f16(wh, bfl[n], acc[m][n], 0, 0, 0);
            }
        }
    }

#pragma unroll
    for (int m = 0; m < 3; ++m) {
#pragma unroll
        for (int r = 0; r < 4; ++r) {
            const int col = (wm * 3 + m) * 16 + lg * 4 + r;
            const f2 sp = *(const f2*)&ss[2 * col];
            _Float16* yr = yo + (size_t)col * TF_ + p0 + wn * 32 + l16;
#pragma unroll
            for (int n = 0; n < 2; ++n) {
                const float v = fmaf(acc[m][n][r], sp[0], sp[1]);
                yr[n * 16] = (_Float16)(v >= 0.f ? v : a * v);
            }
        }
    }
}

// ---------------------------------------------------------------------------
// conv_p: f16 input (F groups, C, T), pre-split W, 160-p tiles, batched.
// ---------------------------------------------------------------------------
__global__ __launch_bounds__(256, 3)
void conv_p(const _Float16* __restrict__ x, const _Float16* __restrict__ wsp,
            const float* __restrict__ scsh, const float* __restrict__ aPp,
            _Float16* __restrict__ y, int bsx, int bsy)
{
    constexpr int LS = 104, PT = 160, NN = 5;
    extern __shared__ _Float16 ldsh[];
    _Float16* Xs = ldsh;                   // [160][104]

    x += (size_t)blockIdx.y * bsx;
    y += (size_t)blockIdx.y * bsy;

    const int tid = threadIdx.x;
    const int pt  = blockIdx.x & 1;
    const int g   = blockIdx.x >> 1;
    const int p0  = pt * PT;

    const _Float16* xg = x + (size_t)g * 96 * T_ + p0;
    for (int e = tid; e < PT * 12; e += 256) {
        const int p = e % PT, k0 = (e / PT) * 8;
        const _Float16* xp = xg + (size_t)k0 * T_ + p;
        h8 hv;
#pragma unroll
        for (int j = 0; j < 8; ++j) hv[j] = xp[(size_t)j * T_];
        *(h8*)&Xs[p * LS + k0] = hv;
    }

    const int lane = tid & 63, wid = tid >> 6;
    const int l16 = lane & 15, lg = lane >> 4;
    const int wm = wid >> 1, wn = wid & 1;
    const float a = aPp[0];
    const _Float16* Wh = wsp + WHP;
    const _Float16* Wl = wsp + WLP;
    const float* ss = scsh + 960;
    __syncthreads();

    f32x4 acc[3][NN];
#pragma unroll
    for (int m = 0; m < 3; ++m)
#pragma unroll
        for (int n = 0; n < NN; ++n) acc[m][n] = (f32x4){0.f, 0.f, 0.f, 0.f};

#pragma unroll
    for (int kk = 0; kk < 3; ++kk) {
        h8 bf[NN];
#pragma unroll
        for (int n = 0; n < NN; ++n)
            bf[n] = *(const h8*)&Xs[((wn * NN + n) * 16 + l16) * LS + kk * 32 + lg * 8];
#pragma unroll
        for (int m = 0; m < 3; ++m) {
            const int row = (wm * 3 + m) * 16 + l16;
            const h8 wh = *(const h8*)&Wh[row * 96 + kk * 32 + lg * 8];
            const h8 wl = *(const h8*)&Wl[row * 96 + kk * 32 + lg * 8];
#pragma unroll
            for (int n = 0; n < NN; ++n) {
                acc[m][n] = __builtin_amdgcn_mfma_f32_16x16x32_f16(wh, bf[n], acc[m][n], 0, 0, 0);
                acc[m][n] = __builtin_amdgcn_mfma_f32_16x16x32_f16(wl, bf[n], acc[m][n], 0, 0, 0);
            }
        }
    }

#pragma unroll
    for (int m = 0; m < 3; ++m) {
#pragma unroll
        for (int r = 0; r < 4; ++r) {
            const int col = (wm * 3 + m) * 16 + lg * 4 + r;
            const f2 sp = *(const f2*)&ss[2 * col];
            _Float16* yr = y + ((size_t)g * 96 + col) * T_ + p0 + wn * NN * 16 + l16;
#pragma unroll
            for (int n = 0; n < NN; ++n) {
                const float v = fmaf(acc[m][n][r], sp[0], sp[1]);
                yr[n * 16] = (_Float16)(v >= 0.f ? v : a * v);
            }
        }
    }
}

// ---------------------------------------------------------------------------
// Merged transpose A: per batch 2 slabs (z = b*2 + t).
//   t=0: fout (unit 3b+0) -> foutT (unit 3b+1)
//   t=1: th2 q-half (doh)  -> tqT   (unit 3b+2)
// ---------------------------------------------------------------------------
__global__ __launch_bounds__(256)
void transpose_trA(const _Float16* __restrict__ doh, _Float16* __restrict__ wsh)
{
    const int b = blockIdx.z >> 1, t = blockIdx.z & 1;
    const _Float16* in  = t ? doh + (size_t)b * 2 * QH_
                            : wsh + (size_t)b * 3 * QH_;
    _Float16*       out = t ? wsh + (size_t)b * 3 * QH_ + 2 * QH_
                            : wsh + (size_t)b * 3 * QH_ + QH_;
    __shared__ _Float16 tile[32][34];
    const int n0 = blockIdx.x * 32, m0 = blockIdx.y * 32;
    const int tx = threadIdx.x, ty = threadIdx.y;
#pragma unroll
    for (int i = 0; i < 32; i += 8)
        tile[ty + i][tx] = in[(size_t)(n0 + ty + i) * F_ + (m0 + tx)];
    __syncthreads();
#pragma unroll
    for (int i = 0; i < 32; i += 8)
        out[(size_t)(m0 + ty + i) * (C_ * T_) + (n0 + tx)] = tile[tx][ty + i];
}

// ---------------------------------------------------------------------------
// Transpose B: th2 k-half (doh+QH) -> tkT (unit 3b+0; fout dead after trA).
// ---------------------------------------------------------------------------
__global__ __launch_bounds__(256)
void transpose_trB(const _Float16* __restrict__ doh, _Float16* __restrict__ wsh)
{
    const int b = blockIdx.z;
    const _Float16* in  = doh + (size_t)b * 2 * QH_ + QH_;
    _Float16*       out = wsh + (size_t)b * 3 * QH_;
    __shared__ _Float16 tile[32][34];
    const int n0 = blockIdx.x * 32, m0 = blockIdx.y * 32;
    const int tx = threadIdx.x, ty = threadIdx.y;
#pragma unroll
    for (int i = 0; i < 32; i += 8)
        tile[ty + i][tx] = in[(size_t)(n0 + ty + i) * F_ + (m0 + tx)];
    __syncthreads();
#pragma unroll
    for (int i = 0; i < 32; i += 8)
        out[(size_t)(m0 + ty + i) * (C_ * T_) + (n0 + tx)] = tile[tx][ty + i];
}

// ---------------------------------------------------------------------------
// f16 in + f32 residual -> f32 out transpose (final step).
// ---------------------------------------------------------------------------
__global__ __launch_bounds__(256)
void transpose_hf_res(const _Float16* __restrict__ in, const float* __restrict__ res,
                      float* __restrict__ out, int Mo, int No, int si, int sr, int so)
{
    __shared__ _Float16 tile[32][34];
    in  += (size_t)blockIdx.z * si;
    res += (size_t)blockIdx.z * sr;
    out += (size_t)blockIdx.z * so;
    const int n0 = blockIdx.x * 32, m0 = blockIdx.y * 32;
    const int tx = threadIdx.x, ty = threadIdx.y;
#pragma unroll
    for (int i = 0; i < 32; i += 8)
        tile[ty + i][tx] = in[(size_t)(n0 + ty + i) * Mo + (m0 + tx)];
    __syncthreads();
#pragma unroll
    for (int i = 0; i < 32; i += 8) {
        const size_t oidx = (size_t)(m0 + ty + i) * No + (n0 + tx);
        out[oidx] = (float)tile[tx][ty + i] + res[oidx];
    }
}

// ---------------------------------------------------------------------------
// MFMA f16 fused attention — all-f16 I/O, batched.  O may alias Q (in-place):
// each block reads Q only in its own output strip, written after all reads.
// ---------------------------------------------------------------------------
template<int MODE>
__global__ __launch_bounds__(256, 2)
void attn_mfma(const _Float16* __restrict__ Qb, const _Float16* __restrict__ Kb,
               const _Float16* __restrict__ Vb, _Float16* __restrict__ Ob,
               int qs, int ks, int vs, int os)
{
    constexpr int NY  = (MODE == 0) ? 256 : 320;
    constexpr int LD  = (MODE == 0) ? TF_ : T_;
    constexpr int NT  = NY / 16;
    constexpr int NYK = NY / 32;
    constexpr int KS  = 104;
    constexpr int VPS = NY + 24;
    constexpr int KVH = (NY * KS > 96 * VPS) ? NY * KS : 96 * VPS;
    constexpr int NG  = (MODE == 0) ? T_ : F_;
    constexpr int GOFF = (MODE == 0) ? F_ : C_ * T_;

    extern __shared__ _Float16 ldsh[];
    _Float16* KV = ldsh;                 // Kt[NY][KS] -> V[96][VPS]
    _Float16* Pw = ldsh + KVH;           // [4][16][40]

    const int lb    = blockIdx.y;
    const int strip = blockIdx.x / NG;
    const int grp   = blockIdx.x % NG;
    const int m0    = strip * 64;
    const size_t off = (size_t)grp * GOFF;
    const _Float16* Q = Qb + (size_t)lb * qs + off;
    const _Float16* K = Kb + (size_t)lb * ks + off;
    const _Float16* V = Vb + (size_t)lb * vs + off;
    _Float16*       O = Ob + (size_t)lb * os + off;

    const int tid  = threadIdx.x;
    const int lane = tid & 63, wid = tid >> 6;
    const int l16  = lane & 15, lg = lane >> 4;
    const int mw   = wid * 16;
    const float scale = 0.10206207261596575f;   // 1/sqrt(96)

    for (int e = tid; e < NY * 12; e += 256) {
        const int yy = e % NY, k0 = (e / NY) * 8;
        const _Float16* kp = K + (size_t)k0 * LD + yy;
        h8 hv;
#pragma unroll
        for (int j = 0; j < 8; ++j) hv[j] = kp[(size_t)j * LD];
        *(h8*)&KV[yy * KS + k0] = hv;
    }

    h8 aQ[3];
#pragma unroll
    for (int kk = 0; kk < 3; ++kk) {
        const _Float16* qp = Q + (size_t)(kk * 32 + lg * 8) * LD + m0 + mw + l16;
#pragma unroll
        for (int j = 0; j < 8; ++j) aQ[kk][j] = qp[(size_t)j * LD];
    }
    __syncthreads();

    f32x4 sacc[NT];
#pragma unroll
    for (int t = 0; t < NT; ++t) sacc[t] = (f32x4){0.f, 0.f, 0.f, 0.f};
#pragma unroll
    for (int kk = 0; kk < 3; ++kk) {
#pragma unroll
        for (int t = 0; t < NT; ++t) {
            const h8 bK = *(const h8*)&KV[(t * 16 + l16) * KS + kk * 32 + lg * 8];
            sacc[t] = __builtin_amdgcn_mfma_f32_16x16x32_f16(aQ[kk], bK, sacc[t], 0, 0, 0);
        }
    }

#pragma unroll
    for (int r = 0; r < 4; ++r) {
        float mx = sacc[0][r];
#pragma unroll
        for (int t = 1; t < NT; ++t) mx = fmaxf(mx, sacc[t][r]);
        for (int d = 1; d < 16; d <<= 1) mx = fmaxf(mx, __shfl_xor(mx, d));
        float pv[NT];
        float sum = 0.f;
#pragma unroll
        for (int t = 0; t < NT; ++t) {
            pv[t] = __expf((sacc[t][r] - mx) * scale); sum += pv[t];
        }
        for (int d = 1; d < 16; d <<= 1) sum += __shfl_xor(sum, d);
        const float inv = 1.f / sum;
#pragma unroll
        for (int t = 0; t < NT; ++t) sacc[t][r] = pv[t] * inv;
    }
    __syncthreads();

    constexpr int NY8 = NY / 8;
    for (int e = tid; e < 96 * NY8; e += 256) {
        const int c = e / NY8, y8 = e - c * NY8;
        *(h8*)&KV[c * VPS + y8 * 8] = *(const h8*)(V + (size_t)c * LD + y8 * 8);
    }
    __syncthreads();

    _Float16* Pme = Pw + wid * 640;      // [16][40]
    f32x4 oacc[6];
#pragma unroll
    for (int ct = 0; ct < 6; ++ct) oacc[ct] = (f32x4){0.f, 0.f, 0.f, 0.f};

#pragma unroll
    for (int yk = 0; yk < NYK; ++yk) {
#pragma unroll
        for (int h = 0; h < 2; ++h)
#pragma unroll
            for (int r = 0; r < 4; ++r)
                Pme[(lg * 4 + r) * 40 + h * 16 + l16] = (_Float16)sacc[2 * yk + h][r];
        const h8 pf = *(const h8*)&Pme[l16 * 40 + lg * 8];   // in-wave DS order
#pragma unroll
        for (int ct = 0; ct < 6; ++ct) {
            const h8 av = *(const h8*)&KV[(ct * 16 + l16) * VPS + yk * 32 + lg * 8];
            oacc[ct] = __builtin_amdgcn_mfma_f32_16x16x32_f16(av, pf, oacc[ct], 0, 0, 0);
        }
    }
#pragma unroll
    for (int ct = 0; ct < 6; ++ct)
#pragma unroll
        for (int r = 0; r < 4; ++r)
            O[(size_t)(ct * 16 + lg * 4 + r) * LD + m0 + mw + l16] = (_Float16)oacc[ct][r];
}

// ---------------------------------------------------------------------------
extern "C" void kernel_launch(void* const* d_in, const int* in_sizes, int n_in,
                              void* d_out, int out_size, void* d_ws, size_t ws_size,
                              hipStream_t stream)
{
    const float* inp = (const float*)d_in[0];
    const float* W_f = (const float*)d_in[1];  const float* b_f = (const float*)d_in[2];
    const float* g_f = (const float*)d_in[3];  const float* be_f = (const float*)d_in[4];
    const float* m_f = (const float*)d_in[5];  const float* v_f = (const float*)d_in[6];
    const float* a_f = (const float*)d_in[7];
    const float* W_t = (const float*)d_in[8];  const float* b_t = (const float*)d_in[9];
    const float* g_t = (const float*)d_in[10]; const float* be_t = (const float*)d_in[11];
    const float* m_t = (const float*)d_in[12]; const float* v_t = (const float*)d_in[13];
    const float* a_t = (const float*)d_in[14];
    const float* W_p = (const float*)d_in[15]; const float* b_p = (const float*)d_in[16];
    const float* g_p = (const float*)d_in[17]; const float* be_p = (const float*)d_in[18];
    const float* m_p = (const float*)d_in[19]; const float* v_p = (const float*)d_in[20];
    const float* a_p = (const float*)d_in[21];

    hipFuncSetAttribute((const void*)conv_ft,
                        hipFuncAttributeMaxDynamicSharedMemorySize, 25600);
    hipFuncSetAttribute((const void*)conv_p,
                        hipFuncAttributeMaxDynamicSharedMemorySize, 33280);
    hipFuncSetAttribute((const void*)attn_mfma<0>,
                        hipFuncAttributeMaxDynamicSharedMemorySize, 58880);
    hipFuncSetAttribute((const void*)attn_mfma<1>,
                        hipFuncAttributeMaxDynamicSharedMemorySize, 71680);

    // Unit plan per batch b (f16 units of QH_ elems, stride 3*QH_):
    //  3b+0: fqkv Q -> fout (attn0 in-place) -> [trA] -> tkT -> tmp
    //  3b+1: fqkv K -> foutT (trA)
    //  3b+2: fqkv V -> tqT (trA) -> tout (attn1 in-place)
    //  d_out slice (2 f16 units/batch): th2 q,k halves.
    constexpr int QH = (int)QH_;
    const size_t need4 = (size_t)12 * QH * 2 + (size_t)WTOT * 2 + 1152 * 4 + 4096;
    const int G = (ws_size >= need4) ? 4 : 2;     // batches per pass

    _Float16* wsh  = (_Float16*)d_ws;
    _Float16* wsp  = wsh + (size_t)3 * G * QH;    // W-split tail
    float*    scsh = (float*)(wsp + WTOT);

    prep_kernel<<<dim3(128), dim3(256), 0, stream>>>(
        W_f, W_t, W_p, b_f, g_f, be_f, m_f, v_f,
        b_t, g_t, be_t, m_t, v_t, b_p, g_p, be_p, m_p, v_p, wsp, scsh);

    for (int p = 0; p < B_ / G; ++p) {
        const float* xb  = inp + (size_t)p * G * QH;
        float*       dob = (float*)d_out + (size_t)p * G * QH;
        _Float16*    doh = (_Float16*)dob;        // th2 (2 units/batch)

        // 1. fused conv_f + conv_t, group-parallel (1280 ptiles x 5 groups)
        conv_ft<<<dim3(1280 * 5, G), dim3(256), 25600, stream>>>(
            xb, wsp, scsh, a_f, a_t, wsh, doh, QH, 3 * QH, 2 * QH);
        // 2. f-attention, O in-place over Q third
        attn_mfma<0><<<dim3(T_ * (F_ / 64), G), dim3(256), 58880, stream>>>(
            wsh, wsh + QH_, wsh + 2 * QH_, wsh, 3 * QH, 3 * QH, 3 * QH, 3 * QH);
        // 3. trA: fout -> foutT (3b+1), th2 q -> tqT (3b+2)
        transpose_trA<<<dim3(960, 8, 2 * G), dim3(32, 8), 0, stream>>>(doh, wsh);
        // 4. trB: th2 k -> tkT (3b+0; fout dead)
        transpose_trB<<<dim3(960, 8, G), dim3(32, 8), 0, stream>>>(doh, wsh);
        // 5. t-attention: Q=tqT(3b+2), K=tkT(3b+0), V=foutT(3b+1), O in-place
        attn_mfma<1><<<dim3(F_ * (T_ / 64), G), dim3(256), 71680, stream>>>(
            wsh + 2 * QH_, wsh, wsh + QH_, wsh + 2 * QH_,
            3 * QH, 3 * QH, 3 * QH, 3 * QH);
        // 6. conv_p(tout = 3b+2) -> tmp (3b+0; tkT dead)
        conv_p<<<dim3(F_ * 2, G), dim3(256), 33280, stream>>>(
            wsh + 2 * QH_, wsp, scsh, a_p, wsh, 3 * QH, 3 * QH);
        // 7. out = transpose(tmp) + inp (th2 dead)
        transpose_hf_res<<<dim3(8, 960, G), dim3(32, 8), 0, stream>>>(
            wsh, xb, dob, C_ * T_, F_, 3 * QH, QH, QH);
    }
}

// Round 16
// 758.921 us; speedup vs baseline: 1.0363x; 1.0363x over previous
//
#include <hip/hip_runtime.h>
#include <math.h>

typedef float f4 __attribute__((ext_vector_type(4)));
typedef float f2 __attribute__((ext_vector_type(2)));
typedef float f32x4 __attribute__((ext_vector_type(4)));
typedef _Float16 h8 __attribute__((ext_vector_type(8)));

constexpr int B_ = 4, C_ = 96, T_ = 320, F_ = 256;
constexpr int TF_ = T_ * F_;          // 81920
constexpr float EPS_ = 1e-5f;
constexpr size_t QH_ = (size_t)C_ * TF_;   // 7,864,320 elems per (C,T,F) unit

// W-split scratch layout (f16 elems, appended after the G*3 data units):
constexpr int WHF = 0, WLF = 27648, WHT = 55296, WLT = 73728,
              WHP = 92160, WLP = 101376, WTOT = 110592;

// ---------------------------------------------------------------------------
// One-time prep: split W into hi/lo f16; precompute BN (sc, sh) per channel.
// ---------------------------------------------------------------------------
__global__ __launch_bounds__(256)
void prep_kernel(const float* __restrict__ Wf, const float* __restrict__ Wt,
                 const float* __restrict__ Wp,
                 const float* __restrict__ bf, const float* __restrict__ gf,
                 const float* __restrict__ bef, const float* __restrict__ mf,
                 const float* __restrict__ vf,
                 const float* __restrict__ bt, const float* __restrict__ gt,
                 const float* __restrict__ bet, const float* __restrict__ mt,
                 const float* __restrict__ vt,
                 const float* __restrict__ bp, const float* __restrict__ gp,
                 const float* __restrict__ bep, const float* __restrict__ mp,
                 const float* __restrict__ vp,
                 _Float16* __restrict__ wsp, float* __restrict__ scsh)
{
    const int gtid = blockIdx.x * 256 + threadIdx.x;
    const int gsz  = gridDim.x * 256;
    for (int i = gtid; i < 27648; i += gsz) {
        const float w = Wf[i]; const _Float16 h = (_Float16)w;
        wsp[WHF + i] = h; wsp[WLF + i] = (_Float16)(w - (float)h);
    }
    for (int i = gtid; i < 18432; i += gsz) {
        const float w = Wt[i]; const _Float16 h = (_Float16)w;
        wsp[WHT + i] = h; wsp[WLT + i] = (_Float16)(w - (float)h);
    }
    for (int i = gtid; i < 9216; i += gsz) {
        const float w = Wp[i]; const _Float16 h = (_Float16)w;
        wsp[WHP + i] = h; wsp[WLP + i] = (_Float16)(w - (float)h);
    }
    if (gtid < 288) {
        const float sc = gf[gtid] * rsqrtf(vf[gtid] + EPS_);
        scsh[2 * gtid] = sc;
        scsh[2 * gtid + 1] = fmaf(bf[gtid] - mf[gtid], sc, bef[gtid]);
    } else if (gtid < 480) {
        const int i = gtid - 288;
        const float sc = gt[i] * rsqrtf(vt[i] + EPS_);
        scsh[576 + 2 * i] = sc;
        scsh[576 + 2 * i + 1] = fmaf(bt[i] - mt[i], sc, bet[i]);
    } else if (gtid < 576) {
        const int i = gtid - 480;
        const float sc = gp[i] * rsqrtf(vp[i] + EPS_);
        scsh[960 + 2 * i] = sc;
        scsh[960 + 2 * i + 1] = fmaf(bp[i] - mp[i], sc, bep[i]);
    }
}

// ---------------------------------------------------------------------------
// Fused conv_f + conv_t — round-14 proven body (serial groups, inline W loads,
// launch_bounds(256,3), 64 VGPR) + WIDENED STORES: per-wave LDS bounce tile
// Tw[48][40] f16 turns 24 scalar 2B stores/group into 3 h8 (16B) stores.
// (Round-15 group-parallel grid regressed: 5x redundant X staging. Reverted.)
// ---------------------------------------------------------------------------
__global__ __launch_bounds__(256, 3)
void conv_ft(const float* __restrict__ x, const _Float16* __restrict__ wsp,
             const float* __restrict__ scsh,
             const float* __restrict__ aPf, const float* __restrict__ aPt,
             _Float16* __restrict__ yf, _Float16* __restrict__ yt,
             int bsx, int bsyf, int bsyt)
{
    constexpr int LS = 200;
    extern __shared__ _Float16 ldsh[];
    _Float16* Xs = ldsh;                   // [64][200]: 0-95 hi, 96-191 lo
    // Tw: 4 per-wave tiles [48][40] f16 after Xs (12800 elems)

    x  += (size_t)blockIdx.y * bsx;
    yf += (size_t)blockIdx.y * bsyf;
    yt += (size_t)blockIdx.y * bsyt;

    const int tid = threadIdx.x;
    const int p0  = blockIdx.x * 64;

    // ---- stage X hi/lo: gather 8 k per p, lanes coalesced on p ----
    const float* xg = x + p0;
    for (int e = tid; e < 64 * 12; e += 256) {
        const int p = e & 63, k0 = (e >> 6) * 8;
        const float* xp = xg + (size_t)k0 * TF_ + p;
        h8 hv, lv;
#pragma unroll
        for (int j = 0; j < 8; ++j) {
            const float xv = xp[(size_t)j * TF_];
            const _Float16 xh = (_Float16)xv;
            hv[j] = xh;
            lv[j] = (_Float16)(xv - (float)xh);
        }
        *(h8*)&Xs[p * LS + k0]      = hv;
        *(h8*)&Xs[p * LS + 96 + k0] = lv;
    }

    const int lane = tid & 63, wid = tid >> 6;
    const int l16 = lane & 15, lg = lane >> 4;
    const int wm = wid >> 1, wn = wid & 1;       // 2x2 wave grid
    const float af_ = aPf[0], at_ = aPt[0];
    _Float16* Tw = ldsh + 12800 + wid * 1920;    // per-wave [48][40]
    __syncthreads();

#pragma unroll 1
    for (int cg = 0; cg < 5; ++cg) {
        const _Float16 *Wh, *Wl; const float* ss; float a; _Float16* yo;
        if (cg < 3) {
            Wh = wsp + WHF + cg * 9216;  Wl = wsp + WLF + cg * 9216;
            ss = scsh + cg * 192;        a = af_;
            yo = yf + (size_t)cg * QH_;
        } else {
            const int c2 = cg - 3;
            Wh = wsp + WHT + c2 * 9216;  Wl = wsp + WLT + c2 * 9216;
            ss = scsh + 576 + c2 * 192;  a = at_;
            yo = yt + (size_t)c2 * QH_;
        }

        f32x4 acc[3][2];
#pragma unroll
        for (int m = 0; m < 3; ++m)
#pragma unroll
            for (int n = 0; n < 2; ++n) acc[m][n] = (f32x4){0.f, 0.f, 0.f, 0.f};

#pragma unroll
        for (int kk = 0; kk < 3; ++kk) {
            h8 bfh[2], bfl[2];
#pragma unroll
            for (int n = 0; n < 2; ++n) {
                const int prow = (wn * 2 + n) * 16 + l16;
                bfh[n] = *(const h8*)&Xs[prow * LS + kk * 32 + lg * 8];
                bfl[n] = *(const h8*)&Xs[prow * LS + 96 + kk * 32 + lg * 8];
            }
#pragma unroll
            for (int m = 0; m < 3; ++m) {
                const int row = (wm * 3 + m) * 16 + l16;
                const h8 wh = *(const h8*)&Wh[row * 96 + kk * 32 + lg * 8];
                const h8 wl = *(const h8*)&Wl[row * 96 + kk * 32 + lg * 8];
#pragma unroll
                for (int n = 0; n < 2; ++n) {
                    acc[m][n] = __builtin_amdgcn_mfma_f32_16x16x32_f16(wh, bfh[n], acc[m][n], 0, 0, 0);
                    acc[m][n] = __builtin_amdgcn_mfma_f32_16x16x32_f16(wl, bfh[n], acc[m][n], 0, 0, 0);
                    acc[m][n] = __builtin_amdgcn_mfma_f32_16x16x32_f16(wh, bfl[n], acc[m][n], 0, 0, 0);
                }
            }
        }

        // ---- BN+PReLU -> per-wave tile (stride 40: 4-row step = +8 banks,
        //      conflict-free) -> 3 h8 stores (in-wave DS ordering, no barrier)
#pragma unroll
        for (int m = 0; m < 3; ++m) {
#pragma unroll
            for (int r = 0; r < 4; ++r) {
                const int col  = (wm * 3 + m) * 16 + lg * 4 + r;   // global co
                const int trow = m * 16 + lg * 4 + r;              // tile row
                const f2 sp = *(const f2*)&ss[2 * col];
#pragma unroll
                for (int n = 0; n < 2; ++n) {
                    const float v = fmaf(acc[m][n][r], sp[0], sp[1]);
                    Tw[trow * 40 + n * 16 + l16] = (_Float16)(v >= 0.f ? v : a * v);
                }
            }
        }
#pragma unroll
        for (int c = 0; c < 3; ++c) {
            const int coL = c * 16 + (lane >> 2);      // 0..47
            const int pL  = (lane & 3) * 8;            // 0..24
            const h8 hv = *(const h8*)&Tw[coL * 40 + pL];
            *(h8*)&yo[(size_t)(wm * 48 + coL) * TF_ + p0 + wn * 32 + pL] = hv;
        }
    }
}

// ---------------------------------------------------------------------------
// conv_p: f16 input (F groups, C, T), pre-split W, 160-p tiles, batched.
// ---------------------------------------------------------------------------
__global__ __launch_bounds__(256, 3)
void conv_p(const _Float16* __restrict__ x, const _Float16* __restrict__ wsp,
            const float* __restrict__ scsh, const float* __restrict__ aPp,
            _Float16* __restrict__ y, int bsx, int bsy)
{
    constexpr int LS = 104, PT = 160, NN = 5;
    extern __shared__ _Float16 ldsh[];
    _Float16* Xs = ldsh;                   // [160][104]

    x += (size_t)blockIdx.y * bsx;
    y += (size_t)blockIdx.y * bsy;

    const int tid = threadIdx.x;
    const int pt  = blockIdx.x & 1;
    const int g   = blockIdx.x >> 1;
    const int p0  = pt * PT;

    const _Float16* xg = x + (size_t)g * 96 * T_ + p0;
    for (int e = tid; e < PT * 12; e += 256) {
        const int p = e % PT, k0 = (e / PT) * 8;
        const _Float16* xp = xg + (size_t)k0 * T_ + p;
        h8 hv;
#pragma unroll
        for (int j = 0; j < 8; ++j) hv[j] = xp[(size_t)j * T_];
        *(h8*)&Xs[p * LS + k0] = hv;
    }

    const int lane = tid & 63, wid = tid >> 6;
    const int l16 = lane & 15, lg = lane >> 4;
    const int wm = wid >> 1, wn = wid & 1;
    const float a = aPp[0];
    const _Float16* Wh = wsp + WHP;
    const _Float16* Wl = wsp + WLP;
    const float* ss = scsh + 960;
    __syncthreads();

    f32x4 acc[3][NN];
#pragma unroll
    for (int m = 0; m < 3; ++m)
#pragma unroll
        for (int n = 0; n < NN; ++n) acc[m][n] = (f32x4){0.f, 0.f, 0.f, 0.f};

#pragma unroll
    for (int kk = 0; kk < 3; ++kk) {
        h8 bf[NN];
#pragma unroll
        for (int n = 0; n < NN; ++n)
            bf[n] = *(const h8*)&Xs[((wn * NN + n) * 16 + l16) * LS + kk * 32 + lg * 8];
#pragma unroll
        for (int m = 0; m < 3; ++m) {
            const int row = (wm * 3 + m) * 16 + l16;
            const h8 wh = *(const h8*)&Wh[row * 96 + kk * 32 + lg * 8];
            const h8 wl = *(const h8*)&Wl[row * 96 + kk * 32 + lg * 8];
#pragma unroll
            for (int n = 0; n < NN; ++n) {
                acc[m][n] = __builtin_amdgcn_mfma_f32_16x16x32_f16(wh, bf[n], acc[m][n], 0, 0, 0);
                acc[m][n] = __builtin_amdgcn_mfma_f32_16x16x32_f16(wl, bf[n], acc[m][n], 0, 0, 0);
            }
        }
    }

#pragma unroll
    for (int m = 0; m < 3; ++m) {
#pragma unroll
        for (int r = 0; r < 4; ++r) {
            const int col = (wm * 3 + m) * 16 + lg * 4 + r;
            const f2 sp = *(const f2*)&ss[2 * col];
            _Float16* yr = y + ((size_t)g * 96 + col) * T_ + p0 + wn * NN * 16 + l16;
#pragma unroll
            for (int n = 0; n < NN; ++n) {
                const float v = fmaf(acc[m][n][r], sp[0], sp[1]);
                yr[n * 16] = (_Float16)(v >= 0.f ? v : a * v);
            }
        }
    }
}

// ---------------------------------------------------------------------------
// Merged transpose A: per batch 2 slabs (z = b*2 + t).
//   t=0: fout (unit 3b+0) -> foutT (unit 3b+1)
//   t=1: th2 q-half (doh)  -> tqT   (unit 3b+2)
// ---------------------------------------------------------------------------
__global__ __launch_bounds__(256)
void transpose_trA(const _Float16* __restrict__ doh, _Float16* __restrict__ wsh)
{
    const int b = blockIdx.z >> 1, t = blockIdx.z & 1;
    const _Float16* in  = t ? doh + (size_t)b * 2 * QH_
                            : wsh + (size_t)b * 3 * QH_;
    _Float16*       out = t ? wsh + (size_t)b * 3 * QH_ + 2 * QH_
                            : wsh + (size_t)b * 3 * QH_ + QH_;
    __shared__ _Float16 tile[32][34];
    const int n0 = blockIdx.x * 32, m0 = blockIdx.y * 32;
    const int tx = threadIdx.x, ty = threadIdx.y;
#pragma unroll
    for (int i = 0; i < 32; i += 8)
        tile[ty + i][tx] = in[(size_t)(n0 + ty + i) * F_ + (m0 + tx)];
    __syncthreads();
#pragma unroll
    for (int i = 0; i < 32; i += 8)
        out[(size_t)(m0 + ty + i) * (C_ * T_) + (n0 + tx)] = tile[tx][ty + i];
}

// ---------------------------------------------------------------------------
// Transpose B: th2 k-half (doh+QH) -> tkT (unit 3b+0; fout dead after trA).
// ---------------------------------------------------------------------------
__global__ __launch_bounds__(256)
void transpose_trB(const _Float16* __restrict__ doh, _Float16* __restrict__ wsh)
{
    const int b = blockIdx.z;
    const _Float16* in  = doh + (size_t)b * 2 * QH_ + QH_;
    _Float16*       out = wsh + (size_t)b * 3 * QH_;
    __shared__ _Float16 tile[32][34];
    const int n0 = blockIdx.x * 32, m0 = blockIdx.y * 32;
    const int tx = threadIdx.x, ty = threadIdx.y;
#pragma unroll
    for (int i = 0; i < 32; i += 8)
        tile[ty + i][tx] = in[(size_t)(n0 + ty + i) * F_ + (m0 + tx)];
    __syncthreads();
#pragma unroll
    for (int i = 0; i < 32; i += 8)
        out[(size_t)(m0 + ty + i) * (C_ * T_) + (n0 + tx)] = tile[tx][ty + i];
}

// ---------------------------------------------------------------------------
// f16 in + f32 residual -> f32 out transpose (final step).
// ---------------------------------------------------------------------------
__global__ __launch_bounds__(256)
void transpose_hf_res(const _Float16* __restrict__ in, const float* __restrict__ res,
                      float* __restrict__ out, int Mo, int No, int si, int sr, int so)
{
    __shared__ _Float16 tile[32][34];
    in  += (size_t)blockIdx.z * si;
    res += (size_t)blockIdx.z * sr;
    out += (size_t)blockIdx.z * so;
    const int n0 = blockIdx.x * 32, m0 = blockIdx.y * 32;
    const int tx = threadIdx.x, ty = threadIdx.y;
#pragma unroll
    for (int i = 0; i < 32; i += 8)
        tile[ty + i][tx] = in[(size_t)(n0 + ty + i) * Mo + (m0 + tx)];
    __syncthreads();
#pragma unroll
    for (int i = 0; i < 32; i += 8) {
        const size_t oidx = (size_t)(m0 + ty + i) * No + (n0 + tx);
        out[oidx] = (float)tile[tx][ty + i] + res[oidx];
    }
}

// ---------------------------------------------------------------------------
// MFMA f16 fused attention — all-f16 I/O, batched.  O may alias Q (in-place):
// each block reads Q only in its own output strip, written after all reads.
// ---------------------------------------------------------------------------
template<int MODE>
__global__ __launch_bounds__(256, 2)
void attn_mfma(const _Float16* __restrict__ Qb, const _Float16* __restrict__ Kb,
               const _Float16* __restrict__ Vb, _Float16* __restrict__ Ob,
               int qs, int ks, int vs, int os)
{
    constexpr int NY  = (MODE == 0) ? 256 : 320;
    constexpr int LD  = (MODE == 0) ? TF_ : T_;
    constexpr int NT  = NY / 16;
    constexpr int NYK = NY / 32;
    constexpr int KS  = 104;
    constexpr int VPS = NY + 24;
    constexpr int KVH = (NY * KS > 96 * VPS) ? NY * KS : 96 * VPS;
    constexpr int NG  = (MODE == 0) ? T_ : F_;
    constexpr int GOFF = (MODE == 0) ? F_ : C_ * T_;

    extern __shared__ _Float16 ldsh[];
    _Float16* KV = ldsh;                 // Kt[NY][KS] -> V[96][VPS]
    _Float16* Pw = ldsh + KVH;           // [4][16][40]

    const int lb    = blockIdx.y;
    const int strip = blockIdx.x / NG;
    const int grp   = blockIdx.x % NG;
    const int m0    = strip * 64;
    const size_t off = (size_t)grp * GOFF;
    const _Float16* Q = Qb + (size_t)lb * qs + off;
    const _Float16* K = Kb + (size_t)lb * ks + off;
    const _Float16* V = Vb + (size_t)lb * vs + off;
    _Float16*       O = Ob + (size_t)lb * os + off;

    const int tid  = threadIdx.x;
    const int lane = tid & 63, wid = tid >> 6;
    const int l16  = lane & 15, lg = lane >> 4;
    const int mw   = wid * 16;
    const float scale = 0.10206207261596575f;   // 1/sqrt(96)

    for (int e = tid; e < NY * 12; e += 256) {
        const int yy = e % NY, k0 = (e / NY) * 8;
        const _Float16* kp = K + (size_t)k0 * LD + yy;
        h8 hv;
#pragma unroll
        for (int j = 0; j < 8; ++j) hv[j] = kp[(size_t)j * LD];
        *(h8*)&KV[yy * KS + k0] = hv;
    }

    h8 aQ[3];
#pragma unroll
    for (int kk = 0; kk < 3; ++kk) {
        const _Float16* qp = Q + (size_t)(kk * 32 + lg * 8) * LD + m0 + mw + l16;
#pragma unroll
        for (int j = 0; j < 8; ++j) aQ[kk][j] = qp[(size_t)j * LD];
    }
    __syncthreads();

    f32x4 sacc[NT];
#pragma unroll
    for (int t = 0; t < NT; ++t) sacc[t] = (f32x4){0.f, 0.f, 0.f, 0.f};
#pragma unroll
    for (int kk = 0; kk < 3; ++kk) {
#pragma unroll
        for (int t = 0; t < NT; ++t) {
            const h8 bK = *(const h8*)&KV[(t * 16 + l16) * KS + kk * 32 + lg * 8];
            sacc[t] = __builtin_amdgcn_mfma_f32_16x16x32_f16(aQ[kk], bK, sacc[t], 0, 0, 0);
        }
    }

#pragma unroll
    for (int r = 0; r < 4; ++r) {
        float mx = sacc[0][r];
#pragma unroll
        for (int t = 1; t < NT; ++t) mx = fmaxf(mx, sacc[t][r]);
        for (int d = 1; d < 16; d <<= 1) mx = fmaxf(mx, __shfl_xor(mx, d));
        float pv[NT];
        float sum = 0.f;
#pragma unroll
        for (int t = 0; t < NT; ++t) {
            pv[t] = __expf((sacc[t][r] - mx) * scale); sum += pv[t];
        }
        for (int d = 1; d < 16; d <<= 1) sum += __shfl_xor(sum, d);
        const float inv = 1.f / sum;
#pragma unroll
        for (int t = 0; t < NT; ++t) sacc[t][r] = pv[t] * inv;
    }
    __syncthreads();

    constexpr int NY8 = NY / 8;
    for (int e = tid; e < 96 * NY8; e += 256) {
        const int c = e / NY8, y8 = e - c * NY8;
        *(h8*)&KV[c * VPS + y8 * 8] = *(const h8*)(V + (size_t)c * LD + y8 * 8);
    }
    __syncthreads();

    _Float16* Pme = Pw + wid * 640;      // [16][40]
    f32x4 oacc[6];
#pragma unroll
    for (int ct = 0; ct < 6; ++ct) oacc[ct] = (f32x4){0.f, 0.f, 0.f, 0.f};

#pragma unroll
    for (int yk = 0; yk < NYK; ++yk) {
#pragma unroll
        for (int h = 0; h < 2; ++h)
#pragma unroll
            for (int r = 0; r < 4; ++r)
                Pme[(lg * 4 + r) * 40 + h * 16 + l16] = (_Float16)sacc[2 * yk + h][r];
        const h8 pf = *(const h8*)&Pme[l16 * 40 + lg * 8];   // in-wave DS order
#pragma unroll
        for (int ct = 0; ct < 6; ++ct) {
            const h8 av = *(const h8*)&KV[(ct * 16 + l16) * VPS + yk * 32 + lg * 8];
            oacc[ct] = __builtin_amdgcn_mfma_f32_16x16x32_f16(av, pf, oacc[ct], 0, 0, 0);
        }
    }
#pragma unroll
    for (int ct = 0; ct < 6; ++ct)
#pragma unroll
        for (int r = 0; r < 4; ++r)
            O[(size_t)(ct * 16 + lg * 4 + r) * LD + m0 + mw + l16] = (_Float16)oacc[ct][r];
}

// ---------------------------------------------------------------------------
extern "C" void kernel_launch(void* const* d_in, const int* in_sizes, int n_in,
                              void* d_out, int out_size, void* d_ws, size_t ws_size,
                              hipStream_t stream)
{
    const float* inp = (const float*)d_in[0];
    const float* W_f = (const float*)d_in[1];  const float* b_f = (const float*)d_in[2];
    const float* g_f = (const float*)d_in[3];  const float* be_f = (const float*)d_in[4];
    const float* m_f = (const float*)d_in[5];  const float* v_f = (const float*)d_in[6];
    const float* a_f = (const float*)d_in[7];
    const float* W_t = (const float*)d_in[8];  const float* b_t = (const float*)d_in[9];
    const float* g_t = (const float*)d_in[10]; const float* be_t = (const float*)d_in[11];
    const float* m_t = (const float*)d_in[12]; const float* v_t = (const float*)d_in[13];
    const float* a_t = (const float*)d_in[14];
    const float* W_p = (const float*)d_in[15]; const float* b_p = (const float*)d_in[16];
    const float* g_p = (const float*)d_in[17]; const float* be_p = (const float*)d_in[18];
    const float* m_p = (const float*)d_in[19]; const float* v_p = (const float*)d_in[20];
    const float* a_p = (const float*)d_in[21];

    hipFuncSetAttribute((const void*)conv_ft,
                        hipFuncAttributeMaxDynamicSharedMemorySize, 40960);
    hipFuncSetAttribute((const void*)conv_p,
                        hipFuncAttributeMaxDynamicSharedMemorySize, 33280);
    hipFuncSetAttribute((const void*)attn_mfma<0>,
                        hipFuncAttributeMaxDynamicSharedMemorySize, 58880);
    hipFuncSetAttribute((const void*)attn_mfma<1>,
                        hipFuncAttributeMaxDynamicSharedMemorySize, 71680);

    // Unit plan per batch b (f16 units of QH_ elems, stride 3*QH_):
    //  3b+0: fqkv Q -> fout (attn0 in-place) -> [trA] -> tkT -> tmp
    //  3b+1: fqkv K -> foutT (trA)
    //  3b+2: fqkv V -> tqT (trA) -> tout (attn1 in-place)
    //  d_out slice (2 f16 units/batch): th2 q,k halves.
    constexpr int QH = (int)QH_;
    const size_t need4 = (size_t)12 * QH * 2 + (size_t)WTOT * 2 + 1152 * 4 + 4096;
    const int G = (ws_size >= need4) ? 4 : 2;     // batches per pass

    _Float16* wsh  = (_Float16*)d_ws;
    _Float16* wsp  = wsh + (size_t)3 * G * QH;    // W-split tail
    float*    scsh = (float*)(wsp + WTOT);

    prep_kernel<<<dim3(128), dim3(256), 0, stream>>>(
        W_f, W_t, W_p, b_f, g_f, be_f, m_f, v_f,
        b_t, g_t, be_t, m_t, v_t, b_p, g_p, be_p, m_p, v_p, wsp, scsh);

    for (int p = 0; p < B_ / G; ++p) {
        const float* xb  = inp + (size_t)p * G * QH;
        float*       dob = (float*)d_out + (size_t)p * G * QH;
        _Float16*    doh = (_Float16*)dob;        // th2 (2 units/batch)

        // 1. fused conv_f + conv_t: fqkv -> ws, th2 -> d_out slice
        conv_ft<<<dim3(1280, G), dim3(256), 40960, stream>>>(
            xb, wsp, scsh, a_f, a_t, wsh, doh, QH, 3 * QH, 2 * QH);
        // 2. f-attention, O in-place over Q third
        attn_mfma<0><<<dim3(T_ * (F_ / 64), G), dim3(256), 58880, stream>>>(
            wsh, wsh + QH_, wsh + 2 * QH_, wsh, 3 * QH, 3 * QH, 3 * QH, 3 * QH);
        // 3. trA: fout -> foutT (3b+1), th2 q -> tqT (3b+2)
        transpose_trA<<<dim3(960, 8, 2 * G), dim3(32, 8), 0, stream>>>(doh, wsh);
        // 4. trB: th2 k -> tkT (3b+0; fout dead)
        transpose_trB<<<dim3(960, 8, G), dim3(32, 8), 0, stream>>>(doh, wsh);
        // 5. t-attention: Q=tqT(3b+2), K=tkT(3b+0), V=foutT(3b+1), O in-place
        attn_mfma<1><<<dim3(F_ * (T_ / 64), G), dim3(256), 71680, stream>>>(
            wsh + 2 * QH_, wsh, wsh + QH_, wsh + 2 * QH_,
            3 * QH, 3 * QH, 3 * QH, 3 * QH);
        // 6. conv_p(tout = 3b+2) -> tmp (3b+0; tkT dead)
        conv_p<<<dim3(F_ * 2, G), dim3(256), 33280, stream>>>(
            wsh + 2 * QH_, wsp, scsh, a_p, wsh, 3 * QH, 3 * QH);
        // 7. out = transpose(tmp) + inp (th2 dead)
        transpose_hf_res<<<dim3(8, 960, G), dim3(32, 8), 0, stream>>>(
            wsh, xb, dob, C_ * T_, F_, 3 * QH, QH, QH);
    }
}

// Round 17
// 724.408 us; speedup vs baseline: 1.0857x; 1.0476x over previous
//
#include <hip/hip_runtime.h>
#include <math.h>

typedef float f4 __attribute__((ext_vector_type(4)));
typedef float f2 __attribute__((ext_vector_type(2)));
typedef float f32x4 __attribute__((ext_vector_type(4)));
typedef _Float16 h8 __attribute__((ext_vector_type(8)));

constexpr int B_ = 4, C_ = 96, T_ = 320, F_ = 256;
constexpr int TF_ = T_ * F_;          // 81920
constexpr float EPS_ = 1e-5f;
constexpr size_t QH_ = (size_t)C_ * TF_;   // 7,864,320 elems per (C,T,F) unit

// W-split scratch layout (f16 elems, appended after the G*3 data units):
constexpr int WHF = 0, WLF = 27648, WHT = 55296, WLT = 73728,
              WHP = 92160, WLP = 101376, WTOT = 110592;

// ---------------------------------------------------------------------------
// One-time prep: split W into hi/lo f16; precompute BN (sc, sh) per channel.
// ---------------------------------------------------------------------------
__global__ __launch_bounds__(256)
void prep_kernel(const float* __restrict__ Wf, const float* __restrict__ Wt,
                 const float* __restrict__ Wp,
                 const float* __restrict__ bf, const float* __restrict__ gf,
                 const float* __restrict__ bef, const float* __restrict__ mf,
                 const float* __restrict__ vf,
                 const float* __restrict__ bt, const float* __restrict__ gt,
                 const float* __restrict__ bet, const float* __restrict__ mt,
                 const float* __restrict__ vt,
                 const float* __restrict__ bp, const float* __restrict__ gp,
                 const float* __restrict__ bep, const float* __restrict__ mp,
                 const float* __restrict__ vp,
                 _Float16* __restrict__ wsp, float* __restrict__ scsh)
{
    const int gtid = blockIdx.x * 256 + threadIdx.x;
    const int gsz  = gridDim.x * 256;
    for (int i = gtid; i < 27648; i += gsz) {
        const float w = Wf[i]; const _Float16 h = (_Float16)w;
        wsp[WHF + i] = h; wsp[WLF + i] = (_Float16)(w - (float)h);
    }
    for (int i = gtid; i < 18432; i += gsz) {
        const float w = Wt[i]; const _Float16 h = (_Float16)w;
        wsp[WHT + i] = h; wsp[WLT + i] = (_Float16)(w - (float)h);
    }
    for (int i = gtid; i < 9216; i += gsz) {
        const float w = Wp[i]; const _Float16 h = (_Float16)w;
        wsp[WHP + i] = h; wsp[WLP + i] = (_Float16)(w - (float)h);
    }
    if (gtid < 288) {
        const float sc = gf[gtid] * rsqrtf(vf[gtid] + EPS_);
        scsh[2 * gtid] = sc;
        scsh[2 * gtid + 1] = fmaf(bf[gtid] - mf[gtid], sc, bef[gtid]);
    } else if (gtid < 480) {
        const int i = gtid - 288;
        const float sc = gt[i] * rsqrtf(vt[i] + EPS_);
        scsh[576 + 2 * i] = sc;
        scsh[576 + 2 * i + 1] = fmaf(bt[i] - mt[i], sc, bet[i]);
    } else if (gtid < 576) {
        const int i = gtid - 480;
        const float sc = gp[i] * rsqrtf(vp[i] + EPS_);
        scsh[960 + 2 * i] = sc;
        scsh[960 + 2 * i + 1] = fmaf(bp[i] - mp[i], sc, bep[i]);
    }
}

// ---------------------------------------------------------------------------
// Fused conv_f + conv_t — EXACT round-14 proven config (230us, 64 VGPR,
// zero spill).  Three epilogue/occupancy/pipeline variants all regressed;
// do not modify this kernel without counter evidence of a new mechanism.
// ---------------------------------------------------------------------------
__global__ __launch_bounds__(256, 3)
void conv_ft(const float* __restrict__ x, const _Float16* __restrict__ wsp,
             const float* __restrict__ scsh,
             const float* __restrict__ aPf, const float* __restrict__ aPt,
             _Float16* __restrict__ yf, _Float16* __restrict__ yt,
             int bsx, int bsyf, int bsyt)
{
    constexpr int LS = 200;
    extern __shared__ _Float16 ldsh[];
    _Float16* Xs = ldsh;                   // [64][200]: 0-95 hi, 96-191 lo

    x  += (size_t)blockIdx.y * bsx;
    yf += (size_t)blockIdx.y * bsyf;
    yt += (size_t)blockIdx.y * bsyt;

    const int tid = threadIdx.x;
    const int p0  = blockIdx.x * 64;

    const float* xg = x + p0;
    for (int e = tid; e < 64 * 12; e += 256) {
        const int p = e & 63, k0 = (e >> 6) * 8;
        const float* xp = xg + (size_t)k0 * TF_ + p;
        h8 hv, lv;
#pragma unroll
        for (int j = 0; j < 8; ++j) {
            const float xv = xp[(size_t)j * TF_];
            const _Float16 xh = (_Float16)xv;
            hv[j] = xh;
            lv[j] = (_Float16)(xv - (float)xh);
        }
        *(h8*)&Xs[p * LS + k0]      = hv;
        *(h8*)&Xs[p * LS + 96 + k0] = lv;
    }

    const int lane = tid & 63, wid = tid >> 6;
    const int l16 = lane & 15, lg = lane >> 4;
    const int wm = wid >> 1, wn = wid & 1;       // 2x2 wave grid
    const float af_ = aPf[0], at_ = aPt[0];
    __syncthreads();

#pragma unroll 1
    for (int cg = 0; cg < 5; ++cg) {
        const _Float16 *Wh, *Wl; const float* ss; float a; _Float16* yo;
        if (cg < 3) {
            Wh = wsp + WHF + cg * 9216;  Wl = wsp + WLF + cg * 9216;
            ss = scsh + cg * 192;        a = af_;
            yo = yf + (size_t)cg * QH_;
        } else {
            const int c2 = cg - 3;
            Wh = wsp + WHT + c2 * 9216;  Wl = wsp + WLT + c2 * 9216;
            ss = scsh + 576 + c2 * 192;  a = at_;
            yo = yt + (size_t)c2 * QH_;
        }

        f32x4 acc[3][2];
#pragma unroll
        for (int m = 0; m < 3; ++m)
#pragma unroll
            for (int n = 0; n < 2; ++n) acc[m][n] = (f32x4){0.f, 0.f, 0.f, 0.f};

#pragma unroll
        for (int kk = 0; kk < 3; ++kk) {
            h8 bfh[2], bfl[2];
#pragma unroll
            for (int n = 0; n < 2; ++n) {
                const int prow = (wn * 2 + n) * 16 + l16;
                bfh[n] = *(const h8*)&Xs[prow * LS + kk * 32 + lg * 8];
                bfl[n] = *(const h8*)&Xs[prow * LS + 96 + kk * 32 + lg * 8];
            }
#pragma unroll
            for (int m = 0; m < 3; ++m) {
                const int row = (wm * 3 + m) * 16 + l16;
                const h8 wh = *(const h8*)&Wh[row * 96 + kk * 32 + lg * 8];
                const h8 wl = *(const h8*)&Wl[row * 96 + kk * 32 + lg * 8];
#pragma unroll
                for (int n = 0; n < 2; ++n) {
                    acc[m][n] = __builtin_amdgcn_mfma_f32_16x16x32_f16(wh, bfh[n], acc[m][n], 0, 0, 0);
                    acc[m][n] = __builtin_amdgcn_mfma_f32_16x16x32_f16(wl, bfh[n], acc[m][n], 0, 0, 0);
                    acc[m][n] = __builtin_amdgcn_mfma_f32_16x16x32_f16(wh, bfl[n], acc[m][n], 0, 0, 0);
                }
            }
        }

#pragma unroll
        for (int m = 0; m < 3; ++m) {
#pragma unroll
            for (int r = 0; r < 4; ++r) {
                const int col = (wm * 3 + m) * 16 + lg * 4 + r;
                const f2 sp = *(const f2*)&ss[2 * col];
                _Float16* yr = yo + (size_t)col * TF_ + p0 + wn * 32 + l16;
#pragma unroll
                for (int n = 0; n < 2; ++n) {
                    const float v = fmaf(acc[m][n][r], sp[0], sp[1]);
                    yr[n * 16] = (_Float16)(v >= 0.f ? v : a * v);
                }
            }
        }
    }
}

// ---------------------------------------------------------------------------
// conv_p: f16 input (F groups, C, T), pre-split W, 160-p tiles, batched.
// ---------------------------------------------------------------------------
__global__ __launch_bounds__(256, 3)
void conv_p(const _Float16* __restrict__ x, const _Float16* __restrict__ wsp,
            const float* __restrict__ scsh, const float* __restrict__ aPp,
            _Float16* __restrict__ y, int bsx, int bsy)
{
    constexpr int LS = 104, PT = 160, NN = 5;
    extern __shared__ _Float16 ldsh[];
    _Float16* Xs = ldsh;                   // [160][104]

    x += (size_t)blockIdx.y * bsx;
    y += (size_t)blockIdx.y * bsy;

    const int tid = threadIdx.x;
    const int pt  = blockIdx.x & 1;
    const int g   = blockIdx.x >> 1;
    const int p0  = pt * PT;

    const _Float16* xg = x + (size_t)g * 96 * T_ + p0;
    for (int e = tid; e < PT * 12; e += 256) {
        const int p = e % PT, k0 = (e / PT) * 8;
        const _Float16* xp = xg + (size_t)k0 * T_ + p;
        h8 hv;
#pragma unroll
        for (int j = 0; j < 8; ++j) hv[j] = xp[(size_t)j * T_];
        *(h8*)&Xs[p * LS + k0] = hv;
    }

    const int lane = tid & 63, wid = tid >> 6;
    const int l16 = lane & 15, lg = lane >> 4;
    const int wm = wid >> 1, wn = wid & 1;
    const float a = aPp[0];
    const _Float16* Wh = wsp + WHP;
    const _Float16* Wl = wsp + WLP;
    const float* ss = scsh + 960;
    __syncthreads();

    f32x4 acc[3][NN];
#pragma unroll
    for (int m = 0; m < 3; ++m)
#pragma unroll
        for (int n = 0; n < NN; ++n) acc[m][n] = (f32x4){0.f, 0.f, 0.f, 0.f};

#pragma unroll
    for (int kk = 0; kk < 3; ++kk) {
        h8 bf[NN];
#pragma unroll
        for (int n = 0; n < NN; ++n)
            bf[n] = *(const h8*)&Xs[((wn * NN + n) * 16 + l16) * LS + kk * 32 + lg * 8];
#pragma unroll
        for (int m = 0; m < 3; ++m) {
            const int row = (wm * 3 + m) * 16 + l16;
            const h8 wh = *(const h8*)&Wh[row * 96 + kk * 32 + lg * 8];
            const h8 wl = *(const h8*)&Wl[row * 96 + kk * 32 + lg * 8];
#pragma unroll
            for (int n = 0; n < NN; ++n) {
                acc[m][n] = __builtin_amdgcn_mfma_f32_16x16x32_f16(wh, bf[n], acc[m][n], 0, 0, 0);
                acc[m][n] = __builtin_amdgcn_mfma_f32_16x16x32_f16(wl, bf[n], acc[m][n], 0, 0, 0);
            }
        }
    }

#pragma unroll
    for (int m = 0; m < 3; ++m) {
#pragma unroll
        for (int r = 0; r < 4; ++r) {
            const int col = (wm * 3 + m) * 16 + lg * 4 + r;
            const f2 sp = *(const f2*)&ss[2 * col];
            _Float16* yr = y + ((size_t)g * 96 + col) * T_ + p0 + wn * NN * 16 + l16;
#pragma unroll
            for (int n = 0; n < NN; ++n) {
                const float v = fmaf(acc[m][n][r], sp[0], sp[1]);
                yr[n * 16] = (_Float16)(v >= 0.f ? v : a * v);
            }
        }
    }
}

// ---------------------------------------------------------------------------
// 64x64 f16 transpose core: h8 global I/O, XOR-swizzled LDS tile [64][72].
// Element (n,m) lives at tile[n][((m>>3)^(n>>3))*8 + (m&7)].
// Load: thread (ty=t>>3, tx8=t&7) does 2 h8 row-loads; store: 2 h8 col-stores
// assembled from 8 swizzled gather reads (2 lanes/bank = free).
// ---------------------------------------------------------------------------
__device__ __forceinline__ void tr64_body(const _Float16* __restrict__ in,
                                          _Float16* __restrict__ out,
                                          int Mo, int No, int n0, int m0,
                                          _Float16* tile)
{
    const int t = threadIdx.x, ty = t >> 3, tx8 = t & 7;
#pragma unroll
    for (int r = 0; r < 2; ++r) {
        const int n = ty + r * 32;
        const h8 v = *(const h8*)&in[(size_t)(n0 + n) * Mo + m0 + tx8 * 8];
        const int c = tx8 ^ (n >> 3);
        *(h8*)&tile[n * 72 + c * 8] = v;
    }
    __syncthreads();
#pragma unroll
    for (int r = 0; r < 2; ++r) {
        const int mt = ty + r * 32;
        h8 v;
#pragma unroll
        for (int j = 0; j < 8; ++j) {
            const int n = tx8 * 8 + j;
            const int c = (mt >> 3) ^ tx8;           // n>>3 == tx8
            v[j] = tile[n * 72 + c * 8 + (mt & 7)];
        }
        *(h8*)&out[(size_t)(m0 + mt) * No + n0 + tx8 * 8] = v;
    }
}

// trA: per batch 2 slabs (z = b*2+t): t=0 fout->foutT, t=1 th2 q->tqT.
__global__ __launch_bounds__(256)
void transpose_trA(const _Float16* __restrict__ doh, _Float16* __restrict__ wsh)
{
    __shared__ _Float16 tile[64 * 72];
    const int b = blockIdx.z >> 1, t = blockIdx.z & 1;
    const _Float16* in  = t ? doh + (size_t)b * 2 * QH_
                            : wsh + (size_t)b * 3 * QH_;
    _Float16*       out = t ? wsh + (size_t)b * 3 * QH_ + 2 * QH_
                            : wsh + (size_t)b * 3 * QH_ + QH_;
    tr64_body(in, out, F_, C_ * T_, blockIdx.x * 64, blockIdx.y * 64, tile);
}

// trB: th2 k-half -> tkT (unit 3b+0; fout dead after trA).
__global__ __launch_bounds__(256)
void transpose_trB(const _Float16* __restrict__ doh, _Float16* __restrict__ wsh)
{
    __shared__ _Float16 tile[64 * 72];
    const int b = blockIdx.z;
    tr64_body(doh + (size_t)b * 2 * QH_ + QH_, wsh + (size_t)b * 3 * QH_,
              F_, C_ * T_, blockIdx.x * 64, blockIdx.y * 64, tile);
}

// hf_res: tmp (F_, C*T) f16 + res f32 -> out (C*T, F_) f32.
__global__ __launch_bounds__(256)
void transpose_hf_res(const _Float16* __restrict__ in, const float* __restrict__ res,
                      float* __restrict__ out, int si, int sr, int so)
{
    __shared__ _Float16 tile[64 * 72];
    in  += (size_t)blockIdx.z * si;
    res += (size_t)blockIdx.z * sr;
    out += (size_t)blockIdx.z * so;
    const int n0 = blockIdx.x * 64, m0 = blockIdx.y * 64;   // n over F_, m over C*T
    const int t = threadIdx.x, ty = t >> 3, tx8 = t & 7;
#pragma unroll
    for (int r = 0; r < 2; ++r) {
        const int n = ty + r * 32;
        const h8 v = *(const h8*)&in[(size_t)(n0 + n) * (C_ * T_) + m0 + tx8 * 8];
        const int c = tx8 ^ (n >> 3);
        *(h8*)&tile[n * 72 + c * 8] = v;
    }
    __syncthreads();
#pragma unroll
    for (int r = 0; r < 2; ++r) {
        const int mt = ty + r * 32;
        const size_t obase = (size_t)(m0 + mt) * F_ + n0 + tx8 * 8;
        const f4 r0 = *(const f4*)&res[obase];
        const f4 r1 = *(const f4*)&res[obase + 4];
        f4 o0, o1;
#pragma unroll
        for (int j = 0; j < 8; ++j) {
            const int n = tx8 * 8 + j;
            const int c = (mt >> 3) ^ tx8;
            const float v = (float)tile[n * 72 + c * 8 + (mt & 7)];
            if (j < 4) o0[j] = v + r0[j]; else o1[j - 4] = v + r1[j - 4];
        }
        *(f4*)&out[obase]     = o0;
        *(f4*)&out[obase + 4] = o1;
    }
}

// ---------------------------------------------------------------------------
// MFMA f16 fused attention — all-f16 I/O, batched.  O may alias Q (in-place).
// ---------------------------------------------------------------------------
template<int MODE>
__global__ __launch_bounds__(256, 2)
void attn_mfma(const _Float16* __restrict__ Qb, const _Float16* __restrict__ Kb,
               const _Float16* __restrict__ Vb, _Float16* __restrict__ Ob,
               int qs, int ks, int vs, int os)
{
    constexpr int NY  = (MODE == 0) ? 256 : 320;
    constexpr int LD  = (MODE == 0) ? TF_ : T_;
    constexpr int NT  = NY / 16;
    constexpr int NYK = NY / 32;
    constexpr int KS  = 104;
    constexpr int VPS = NY + 24;
    constexpr int KVH = (NY * KS > 96 * VPS) ? NY * KS : 96 * VPS;
    constexpr int NG  = (MODE == 0) ? T_ : F_;
    constexpr int GOFF = (MODE == 0) ? F_ : C_ * T_;

    extern __shared__ _Float16 ldsh[];
    _Float16* KV = ldsh;                 // Kt[NY][KS] -> V[96][VPS]
    _Float16* Pw = ldsh + KVH;           // [4][16][40]

    const int lb    = blockIdx.y;
    const int strip = blockIdx.x / NG;
    const int grp   = blockIdx.x % NG;
    const int m0    = strip * 64;
    const size_t off = (size_t)grp * GOFF;
    const _Float16* Q = Qb + (size_t)lb * qs + off;
    const _Float16* K = Kb + (size_t)lb * ks + off;
    const _Float16* V = Vb + (size_t)lb * vs + off;
    _Float16*       O = Ob + (size_t)lb * os + off;

    const int tid  = threadIdx.x;
    const int lane = tid & 63, wid = tid >> 6;
    const int l16  = lane & 15, lg = lane >> 4;
    const int mw   = wid * 16;
    const float scale = 0.10206207261596575f;   // 1/sqrt(96)

    for (int e = tid; e < NY * 12; e += 256) {
        const int yy = e % NY, k0 = (e / NY) * 8;
        const _Float16* kp = K + (size_t)k0 * LD + yy;
        h8 hv;
#pragma unroll
        for (int j = 0; j < 8; ++j) hv[j] = kp[(size_t)j * LD];
        *(h8*)&KV[yy * KS + k0] = hv;
    }

    h8 aQ[3];
#pragma unroll
    for (int kk = 0; kk < 3; ++kk) {
        const _Float16* qp = Q + (size_t)(kk * 32 + lg * 8) * LD + m0 + mw + l16;
#pragma unroll
        for (int j = 0; j < 8; ++j) aQ[kk][j] = qp[(size_t)j * LD];
    }
    __syncthreads();

    f32x4 sacc[NT];
#pragma unroll
    for (int t = 0; t < NT; ++t) sacc[t] = (f32x4){0.f, 0.f, 0.f, 0.f};
#pragma unroll
    for (int kk = 0; kk < 3; ++kk) {
#pragma unroll
        for (int t = 0; t < NT; ++t) {
            const h8 bK = *(const h8*)&KV[(t * 16 + l16) * KS + kk * 32 + lg * 8];
            sacc[t] = __builtin_amdgcn_mfma_f32_16x16x32_f16(aQ[kk], bK, sacc[t], 0, 0, 0);
        }
    }

#pragma unroll
    for (int r = 0; r < 4; ++r) {
        float mx = sacc[0][r];
#pragma unroll
        for (int t = 1; t < NT; ++t) mx = fmaxf(mx, sacc[t][r]);
        for (int d = 1; d < 16; d <<= 1) mx = fmaxf(mx, __shfl_xor(mx, d));
        float pv[NT];
        float sum = 0.f;
#pragma unroll
        for (int t = 0; t < NT; ++t) {
            pv[t] = __expf((sacc[t][r] - mx) * scale); sum += pv[t];
        }
        for (int d = 1; d < 16; d <<= 1) sum += __shfl_xor(sum, d);
        const float inv = 1.f / sum;
#pragma unroll
        for (int t = 0; t < NT; ++t) sacc[t][r] = pv[t] * inv;
    }
    __syncthreads();

    constexpr int NY8 = NY / 8;
    for (int e = tid; e < 96 * NY8; e += 256) {
        const int c = e / NY8, y8 = e - c * NY8;
        *(h8*)&KV[c * VPS + y8 * 8] = *(const h8*)(V + (size_t)c * LD + y8 * 8);
    }
    __syncthreads();

    _Float16* Pme = Pw + wid * 640;      // [16][40]
    f32x4 oacc[6];
#pragma unroll
    for (int ct = 0; ct < 6; ++ct) oacc[ct] = (f32x4){0.f, 0.f, 0.f, 0.f};

#pragma unroll
    for (int yk = 0; yk < NYK; ++yk) {
#pragma unroll
        for (int h = 0; h < 2; ++h)
#pragma unroll
            for (int r = 0; r < 4; ++r)
                Pme[(lg * 4 + r) * 40 + h * 16 + l16] = (_Float16)sacc[2 * yk + h][r];
        const h8 pf = *(const h8*)&Pme[l16 * 40 + lg * 8];   // in-wave DS order
#pragma unroll
        for (int ct = 0; ct < 6; ++ct) {
            const h8 av = *(const h8*)&KV[(ct * 16 + l16) * VPS + yk * 32 + lg * 8];
            oacc[ct] = __builtin_amdgcn_mfma_f32_16x16x32_f16(av, pf, oacc[ct], 0, 0, 0);
        }
    }
#pragma unroll
    for (int ct = 0; ct < 6; ++ct)
#pragma unroll
        for (int r = 0; r < 4; ++r)
            O[(size_t)(ct * 16 + lg * 4 + r) * LD + m0 + mw + l16] = (_Float16)oacc[ct][r];
}

// ---------------------------------------------------------------------------
extern "C" void kernel_launch(void* const* d_in, const int* in_sizes, int n_in,
                              void* d_out, int out_size, void* d_ws, size_t ws_size,
                              hipStream_t stream)
{
    const float* inp = (const float*)d_in[0];
    const float* W_f = (const float*)d_in[1];  const float* b_f = (const float*)d_in[2];
    const float* g_f = (const float*)d_in[3];  const float* be_f = (const float*)d_in[4];
    const float* m_f = (const float*)d_in[5];  const float* v_f = (const float*)d_in[6];
    const float* a_f = (const float*)d_in[7];
    const float* W_t = (const float*)d_in[8];  const float* b_t = (const float*)d_in[9];
    const float* g_t = (const float*)d_in[10]; const float* be_t = (const float*)d_in[11];
    const float* m_t = (const float*)d_in[12]; const float* v_t = (const float*)d_in[13];
    const float* a_t = (const float*)d_in[14];
    const float* W_p = (const float*)d_in[15]; const float* b_p = (const float*)d_in[16];
    const float* g_p = (const float*)d_in[17]; const float* be_p = (const float*)d_in[18];
    const float* m_p = (const float*)d_in[19]; const float* v_p = (const float*)d_in[20];
    const float* a_p = (const float*)d_in[21];

    hipFuncSetAttribute((const void*)conv_ft,
                        hipFuncAttributeMaxDynamicSharedMemorySize, 25600);
    hipFuncSetAttribute((const void*)conv_p,
                        hipFuncAttributeMaxDynamicSharedMemorySize, 33280);
    hipFuncSetAttribute((const void*)attn_mfma<0>,
                        hipFuncAttributeMaxDynamicSharedMemorySize, 58880);
    hipFuncSetAttribute((const void*)attn_mfma<1>,
                        hipFuncAttributeMaxDynamicSharedMemorySize, 71680);

    // Unit plan per batch b (f16 units of QH_ elems, stride 3*QH_):
    //  3b+0: fqkv Q -> fout (attn0 in-place) -> [trA] -> tkT -> tmp
    //  3b+1: fqkv K -> foutT (trA)
    //  3b+2: fqkv V -> tqT (trA) -> tout (attn1 in-place)
    //  d_out slice (2 f16 units/batch): th2 q,k halves.
    constexpr int QH = (int)QH_;
    const size_t need4 = (size_t)12 * QH * 2 + (size_t)WTOT * 2 + 1152 * 4 + 4096;
    const int G = (ws_size >= need4) ? 4 : 2;     // batches per pass

    _Float16* wsh  = (_Float16*)d_ws;
    _Float16* wsp  = wsh + (size_t)3 * G * QH;    // W-split tail
    float*    scsh = (float*)(wsp + WTOT);

    prep_kernel<<<dim3(128), dim3(256), 0, stream>>>(
        W_f, W_t, W_p, b_f, g_f, be_f, m_f, v_f,
        b_t, g_t, be_t, m_t, v_t, b_p, g_p, be_p, m_p, v_p, wsp, scsh);

    for (int p = 0; p < B_ / G; ++p) {
        const float* xb  = inp + (size_t)p * G * QH;
        float*       dob = (float*)d_out + (size_t)p * G * QH;
        _Float16*    doh = (_Float16*)dob;        // th2 (2 units/batch)

        // 1. fused conv_f + conv_t: fqkv -> ws, th2 -> d_out slice
        conv_ft<<<dim3(1280, G), dim3(256), 25600, stream>>>(
            xb, wsp, scsh, a_f, a_t, wsh, doh, QH, 3 * QH, 2 * QH);
        // 2. f-attention, O in-place over Q third
        attn_mfma<0><<<dim3(T_ * (F_ / 64), G), dim3(256), 58880, stream>>>(
            wsh, wsh + QH_, wsh + 2 * QH_, wsh, 3 * QH, 3 * QH, 3 * QH, 3 * QH);
        // 3. trA: fout -> foutT (3b+1), th2 q -> tqT (3b+2)   [64x64 tiles]
        transpose_trA<<<dim3(480, 4, 2 * G), dim3(256), 0, stream>>>(doh, wsh);
        // 4. trB: th2 k -> tkT (3b+0; fout dead)
        transpose_trB<<<dim3(480, 4, G), dim3(256), 0, stream>>>(doh, wsh);
        // 5. t-attention: Q=tqT(3b+2), K=tkT(3b+0), V=foutT(3b+1), O in-place
        attn_mfma<1><<<dim3(F_ * (T_ / 64), G), dim3(256), 71680, stream>>>(
            wsh + 2 * QH_, wsh, wsh + QH_, wsh + 2 * QH_,
            3 * QH, 3 * QH, 3 * QH, 3 * QH);
        // 6. conv_p(tout = 3b+2) -> tmp (3b+0; tkT dead)
        conv_p<<<dim3(F_ * 2, G), dim3(256), 33280, stream>>>(
            wsh + 2 * QH_, wsp, scsh, a_p, wsh, 3 * QH, 3 * QH);
        // 7. out = transpose(tmp) + inp (th2 dead)  [64x64 tiles]
        transpose_hf_res<<<dim3(4, 480, G), dim3(256), 0, stream>>>(
            wsh, xb, dob, 3 * QH, QH, QH);
    }
}

// Round 18
// 713.677 us; speedup vs baseline: 1.1020x; 1.0150x over previous
//
#include <hip/hip_runtime.h>
#include <math.h>

typedef float f4 __attribute__((ext_vector_type(4)));
typedef float f2 __attribute__((ext_vector_type(2)));
typedef float f32x4 __attribute__((ext_vector_type(4)));
typedef _Float16 h8 __attribute__((ext_vector_type(8)));

constexpr int B_ = 4, C_ = 96, T_ = 320, F_ = 256;
constexpr int TF_ = T_ * F_;          // 81920
constexpr float EPS_ = 1e-5f;
constexpr size_t QH_ = (size_t)C_ * TF_;   // 7,864,320 elems per (C,T,F) unit

// W-split scratch layout (f16 elems, appended after the G*3 data units):
constexpr int WHF = 0, WLF = 27648, WHT = 55296, WLT = 73728,
              WHP = 92160, WLP = 101376, WTOT = 110592;

// ---------------------------------------------------------------------------
// One-time prep: split W into hi/lo f16; precompute BN (sc, sh) per channel.
// ---------------------------------------------------------------------------
__global__ __launch_bounds__(256)
void prep_kernel(const float* __restrict__ Wf, const float* __restrict__ Wt,
                 const float* __restrict__ Wp,
                 const float* __restrict__ bf, const float* __restrict__ gf,
                 const float* __restrict__ bef, const float* __restrict__ mf,
                 const float* __restrict__ vf,
                 const float* __restrict__ bt, const float* __restrict__ gt,
                 const float* __restrict__ bet, const float* __restrict__ mt,
                 const float* __restrict__ vt,
                 const float* __restrict__ bp, const float* __restrict__ gp,
                 const float* __restrict__ bep, const float* __restrict__ mp,
                 const float* __restrict__ vp,
                 _Float16* __restrict__ wsp, float* __restrict__ scsh)
{
    const int gtid = blockIdx.x * 256 + threadIdx.x;
    const int gsz  = gridDim.x * 256;
    for (int i = gtid; i < 27648; i += gsz) {
        const float w = Wf[i]; const _Float16 h = (_Float16)w;
        wsp[WHF + i] = h; wsp[WLF + i] = (_Float16)(w - (float)h);
    }
    for (int i = gtid; i < 18432; i += gsz) {
        const float w = Wt[i]; const _Float16 h = (_Float16)w;
        wsp[WHT + i] = h; wsp[WLT + i] = (_Float16)(w - (float)h);
    }
    for (int i = gtid; i < 9216; i += gsz) {
        const float w = Wp[i]; const _Float16 h = (_Float16)w;
        wsp[WHP + i] = h; wsp[WLP + i] = (_Float16)(w - (float)h);
    }
    if (gtid < 288) {
        const float sc = gf[gtid] * rsqrtf(vf[gtid] + EPS_);
        scsh[2 * gtid] = sc;
        scsh[2 * gtid + 1] = fmaf(bf[gtid] - mf[gtid], sc, bef[gtid]);
    } else if (gtid < 480) {
        const int i = gtid - 288;
        const float sc = gt[i] * rsqrtf(vt[i] + EPS_);
        scsh[576 + 2 * i] = sc;
        scsh[576 + 2 * i + 1] = fmaf(bt[i] - mt[i], sc, bet[i]);
    } else if (gtid < 576) {
        const int i = gtid - 480;
        const float sc = gp[i] * rsqrtf(vp[i] + EPS_);
        scsh[960 + 2 * i] = sc;
        scsh[960 + 2 * i + 1] = fmaf(bp[i] - mp[i], sc, bep[i]);
    }
}

// ---------------------------------------------------------------------------
// Fused conv_f + conv_t, 2 p-tiles/block with T14 issue-early/write-late:
// stage A -> issue B's 24 raw loads into VGPRs -> compute A's 5 groups
// (HBM latency hides under ~270 MFMAs) -> convert+write B -> barrier ->
// compute B.  Group body = exact round-14 proven code.  LDS 51.2 KB,
// 3 blocks/CU; xpre statically indexed (rule #20).
// ---------------------------------------------------------------------------
__global__ __launch_bounds__(256, 3)
void conv_ft(const float* __restrict__ x, const _Float16* __restrict__ wsp,
             const float* __restrict__ scsh,
             const float* __restrict__ aPf, const float* __restrict__ aPt,
             _Float16* __restrict__ yf, _Float16* __restrict__ yt,
             int bsx, int bsyf, int bsyt)
{
    constexpr int LS = 200;
    extern __shared__ _Float16 ldsh[];
    _Float16* Xs0 = ldsh;                  // [64][200]: 0-95 hi, 96-191 lo
    _Float16* Xs1 = ldsh + 64 * LS;

    x  += (size_t)blockIdx.y * bsx;
    yf += (size_t)blockIdx.y * bsyf;
    yt += (size_t)blockIdx.y * bsyt;

    const int tid = threadIdx.x;
    const int p0A = blockIdx.x * 128;
    const int p0B = p0A + 64;

    // ---- stage tile A (normal) ----
    {
        const float* xg = x + p0A;
        for (int e = tid; e < 64 * 12; e += 256) {
            const int p = e & 63, k0 = (e >> 6) * 8;
            const float* xp = xg + (size_t)k0 * TF_ + p;
            h8 hv, lv;
#pragma unroll
            for (int j = 0; j < 8; ++j) {
                const float xv = xp[(size_t)j * TF_];
                const _Float16 xh = (_Float16)xv;
                hv[j] = xh;
                lv[j] = (_Float16)(xv - (float)xh);
            }
            *(h8*)&Xs0[p * LS + k0]      = hv;
            *(h8*)&Xs0[p * LS + 96 + k0] = lv;
        }
    }

    const int lane = tid & 63, wid = tid >> 6;
    const int l16 = lane & 15, lg = lane >> 4;
    const int wm = wid >> 1, wn = wid & 1;       // 2x2 wave grid
    const float af_ = aPf[0], at_ = aPt[0];
    __syncthreads();

    // ---- issue tile B loads early (24 VGPRs in flight) ----
    float xpre[3][8];
#pragma unroll
    for (int it = 0; it < 3; ++it) {
        const int e = tid + it * 256;
        const int p = e & 63, k0 = (e >> 6) * 8;
        const float* xp = x + p0B + (size_t)k0 * TF_ + p;
#pragma unroll
        for (int j = 0; j < 8; ++j) xpre[it][j] = xp[(size_t)j * TF_];
    }

    // ---- per-tile 5-group compute (round-14 proven body) ----
    auto compute5 = [&](const _Float16* Xs, int p0) {
#pragma unroll 1
        for (int cg = 0; cg < 5; ++cg) {
            const _Float16 *Wh, *Wl; const float* ss; float a; _Float16* yo;
            if (cg < 3) {
                Wh = wsp + WHF + cg * 9216;  Wl = wsp + WLF + cg * 9216;
                ss = scsh + cg * 192;        a = af_;
                yo = yf + (size_t)cg * QH_;
            } else {
                const int c2 = cg - 3;
                Wh = wsp + WHT + c2 * 9216;  Wl = wsp + WLT + c2 * 9216;
                ss = scsh + 576 + c2 * 192;  a = at_;
                yo = yt + (size_t)c2 * QH_;
            }

            f32x4 acc[3][2];
#pragma unroll
            for (int m = 0; m < 3; ++m)
#pragma unroll
                for (int n = 0; n < 2; ++n) acc[m][n] = (f32x4){0.f, 0.f, 0.f, 0.f};

#pragma unroll
            for (int kk = 0; kk < 3; ++kk) {
                h8 bfh[2], bfl[2];
#pragma unroll
                for (int n = 0; n < 2; ++n) {
                    const int prow = (wn * 2 + n) * 16 + l16;
                    bfh[n] = *(const h8*)&Xs[prow * LS + kk * 32 + lg * 8];
                    bfl[n] = *(const h8*)&Xs[prow * LS + 96 + kk * 32 + lg * 8];
                }
#pragma unroll
                for (int m = 0; m < 3; ++m) {
                    const int row = (wm * 3 + m) * 16 + l16;
                    const h8 wh = *(const h8*)&Wh[row * 96 + kk * 32 + lg * 8];
                    const h8 wl = *(const h8*)&Wl[row * 96 + kk * 32 + lg * 8];
#pragma unroll
                    for (int n = 0; n < 2; ++n) {
                        acc[m][n] = __builtin_amdgcn_mfma_f32_16x16x32_f16(wh, bfh[n], acc[m][n], 0, 0, 0);
                        acc[m][n] = __builtin_amdgcn_mfma_f32_16x16x32_f16(wl, bfh[n], acc[m][n], 0, 0, 0);
                        acc[m][n] = __builtin_amdgcn_mfma_f32_16x16x32_f16(wh, bfl[n], acc[m][n], 0, 0, 0);
                    }
                }
            }

#pragma unroll
            for (int m = 0; m < 3; ++m) {
#pragma unroll
                for (int r = 0; r < 4; ++r) {
                    const int col = (wm * 3 + m) * 16 + lg * 4 + r;
                    const f2 sp = *(const f2*)&ss[2 * col];
                    _Float16* yr = yo + (size_t)col * TF_ + p0 + wn * 32 + l16;
#pragma unroll
                    for (int n = 0; n < 2; ++n) {
                        const float v = fmaf(acc[m][n][r], sp[0], sp[1]);
                        yr[n * 16] = (_Float16)(v >= 0.f ? v : a * v);
                    }
                }
            }
        }
    };

    compute5(Xs0, p0A);

    // ---- write-late: convert tile B and stage to Xs1 ----
#pragma unroll
    for (int it = 0; it < 3; ++it) {
        const int e = tid + it * 256;
        const int p = e & 63, k0 = (e >> 6) * 8;
        h8 hv, lv;
#pragma unroll
        for (int j = 0; j < 8; ++j) {
            const _Float16 xh = (_Float16)xpre[it][j];
            hv[j] = xh;
            lv[j] = (_Float16)(xpre[it][j] - (float)xh);
        }
        *(h8*)&Xs1[p * LS + k0]      = hv;
        *(h8*)&Xs1[p * LS + 96 + k0] = lv;
    }
    __syncthreads();

    compute5(Xs1, p0B);
}

// ---------------------------------------------------------------------------
// conv_p: f16 input (F groups, C, T), pre-split W, 160-p tiles, batched.
// ---------------------------------------------------------------------------
__global__ __launch_bounds__(256, 3)
void conv_p(const _Float16* __restrict__ x, const _Float16* __restrict__ wsp,
            const float* __restrict__ scsh, const float* __restrict__ aPp,
            _Float16* __restrict__ y, int bsx, int bsy)
{
    constexpr int LS = 104, PT = 160, NN = 5;
    extern __shared__ _Float16 ldsh[];
    _Float16* Xs = ldsh;                   // [160][104]

    x += (size_t)blockIdx.y * bsx;
    y += (size_t)blockIdx.y * bsy;

    const int tid = threadIdx.x;
    const int pt  = blockIdx.x & 1;
    const int g   = blockIdx.x >> 1;
    const int p0  = pt * PT;

    const _Float16* xg = x + (size_t)g * 96 * T_ + p0;
    for (int e = tid; e < PT * 12; e += 256) {
        const int p = e % PT, k0 = (e / PT) * 8;
        const _Float16* xp = xg + (size_t)k0 * T_ + p;
        h8 hv;
#pragma unroll
        for (int j = 0; j < 8; ++j) hv[j] = xp[(size_t)j * T_];
        *(h8*)&Xs[p * LS + k0] = hv;
    }

    const int lane = tid & 63, wid = tid >> 6;
    const int l16 = lane & 15, lg = lane >> 4;
    const int wm = wid >> 1, wn = wid & 1;
    const float a = aPp[0];
    const _Float16* Wh = wsp + WHP;
    const _Float16* Wl = wsp + WLP;
    const float* ss = scsh + 960;
    __syncthreads();

    f32x4 acc[3][NN];
#pragma unroll
    for (int m = 0; m < 3; ++m)
#pragma unroll
        for (int n = 0; n < NN; ++n) acc[m][n] = (f32x4){0.f, 0.f, 0.f, 0.f};

#pragma unroll
    for (int kk = 0; kk < 3; ++kk) {
        h8 bf[NN];
#pragma unroll
        for (int n = 0; n < NN; ++n)
            bf[n] = *(const h8*)&Xs[((wn * NN + n) * 16 + l16) * LS + kk * 32 + lg * 8];
#pragma unroll
        for (int m = 0; m < 3; ++m) {
            const int row = (wm * 3 + m) * 16 + l16;
            const h8 wh = *(const h8*)&Wh[row * 96 + kk * 32 + lg * 8];
            const h8 wl = *(const h8*)&Wl[row * 96 + kk * 32 + lg * 8];
#pragma unroll
            for (int n = 0; n < NN; ++n) {
                acc[m][n] = __builtin_amdgcn_mfma_f32_16x16x32_f16(wh, bf[n], acc[m][n], 0, 0, 0);
                acc[m][n] = __builtin_amdgcn_mfma_f32_16x16x32_f16(wl, bf[n], acc[m][n], 0, 0, 0);
            }
        }
    }

#pragma unroll
    for (int m = 0; m < 3; ++m) {
#pragma unroll
        for (int r = 0; r < 4; ++r) {
            const int col = (wm * 3 + m) * 16 + lg * 4 + r;
            const f2 sp = *(const f2*)&ss[2 * col];
            _Float16* yr = y + ((size_t)g * 96 + col) * T_ + p0 + wn * NN * 16 + l16;
#pragma unroll
            for (int n = 0; n < NN; ++n) {
                const float v = fmaf(acc[m][n][r], sp[0], sp[1]);
                yr[n * 16] = (_Float16)(v >= 0.f ? v : a * v);
            }
        }
    }
}

// ---------------------------------------------------------------------------
// 64x64 f16 transpose core: h8 global I/O, XOR-swizzled LDS tile [64][72].
// ---------------------------------------------------------------------------
__device__ __forceinline__ void tr64_body(const _Float16* __restrict__ in,
                                          _Float16* __restrict__ out,
                                          int Mo, int No, int n0, int m0,
                                          _Float16* tile)
{
    const int t = threadIdx.x, ty = t >> 3, tx8 = t & 7;
#pragma unroll
    for (int r = 0; r < 2; ++r) {
        const int n = ty + r * 32;
        const h8 v = *(const h8*)&in[(size_t)(n0 + n) * Mo + m0 + tx8 * 8];
        const int c = tx8 ^ (n >> 3);
        *(h8*)&tile[n * 72 + c * 8] = v;
    }
    __syncthreads();
#pragma unroll
    for (int r = 0; r < 2; ++r) {
        const int mt = ty + r * 32;
        h8 v;
#pragma unroll
        for (int j = 0; j < 8; ++j) {
            const int n = tx8 * 8 + j;
            const int c = (mt >> 3) ^ tx8;           // n>>3 == tx8
            v[j] = tile[n * 72 + c * 8 + (mt & 7)];
        }
        *(h8*)&out[(size_t)(m0 + mt) * No + n0 + tx8 * 8] = v;
    }
}

// trA: per batch 2 slabs (z = b*2+t): t=0 fout->foutT, t=1 th2 q->tqT.
__global__ __launch_bounds__(256)
void transpose_trA(const _Float16* __restrict__ doh, _Float16* __restrict__ wsh)
{
    __shared__ _Float16 tile[64 * 72];
    const int b = blockIdx.z >> 1, t = blockIdx.z & 1;
    const _Float16* in  = t ? doh + (size_t)b * 2 * QH_
                            : wsh + (size_t)b * 3 * QH_;
    _Float16*       out = t ? wsh + (size_t)b * 3 * QH_ + 2 * QH_
                            : wsh + (size_t)b * 3 * QH_ + QH_;
    tr64_body(in, out, F_, C_ * T_, blockIdx.x * 64, blockIdx.y * 64, tile);
}

// trB: th2 k-half -> tkT (unit 3b+0; fout dead after trA).
__global__ __launch_bounds__(256)
void transpose_trB(const _Float16* __restrict__ doh, _Float16* __restrict__ wsh)
{
    __shared__ _Float16 tile[64 * 72];
    const int b = blockIdx.z;
    tr64_body(doh + (size_t)b * 2 * QH_ + QH_, wsh + (size_t)b * 3 * QH_,
              F_, C_ * T_, blockIdx.x * 64, blockIdx.y * 64, tile);
}

// hf_res: tmp (F_, C*T) f16 + res f32 -> out (C*T, F_) f32.
__global__ __launch_bounds__(256)
void transpose_hf_res(const _Float16* __restrict__ in, const float* __restrict__ res,
                      float* __restrict__ out, int si, int sr, int so)
{
    __shared__ _Float16 tile[64 * 72];
    in  += (size_t)blockIdx.z * si;
    res += (size_t)blockIdx.z * sr;
    out += (size_t)blockIdx.z * so;
    const int n0 = blockIdx.x * 64, m0 = blockIdx.y * 64;   // n over F_, m over C*T
    const int t = threadIdx.x, ty = t >> 3, tx8 = t & 7;
#pragma unroll
    for (int r = 0; r < 2; ++r) {
        const int n = ty + r * 32;
        const h8 v = *(const h8*)&in[(size_t)(n0 + n) * (C_ * T_) + m0 + tx8 * 8];
        const int c = tx8 ^ (n >> 3);
        *(h8*)&tile[n * 72 + c * 8] = v;
    }
    __syncthreads();
#pragma unroll
    for (int r = 0; r < 2; ++r) {
        const int mt = ty + r * 32;
        const size_t obase = (size_t)(m0 + mt) * F_ + n0 + tx8 * 8;
        const f4 r0 = *(const f4*)&res[obase];
        const f4 r1 = *(const f4*)&res[obase + 4];
        f4 o0, o1;
#pragma unroll
        for (int j = 0; j < 8; ++j) {
            const int n = tx8 * 8 + j;
            const int c = (mt >> 3) ^ tx8;
            const float v = (float)tile[n * 72 + c * 8 + (mt & 7)];
            if (j < 4) o0[j] = v + r0[j]; else o1[j - 4] = v + r1[j - 4];
        }
        *(f4*)&out[obase]     = o0;
        *(f4*)&out[obase + 4] = o1;
    }
}

// ---------------------------------------------------------------------------
// MFMA f16 fused attention — all-f16 I/O, batched.  O may alias Q (in-place).
// ---------------------------------------------------------------------------
template<int MODE>
__global__ __launch_bounds__(256, 2)
void attn_mfma(const _Float16* __restrict__ Qb, const _Float16* __restrict__ Kb,
               const _Float16* __restrict__ Vb, _Float16* __restrict__ Ob,
               int qs, int ks, int vs, int os)
{
    constexpr int NY  = (MODE == 0) ? 256 : 320;
    constexpr int LD  = (MODE == 0) ? TF_ : T_;
    constexpr int NT  = NY / 16;
    constexpr int NYK = NY / 32;
    constexpr int KS  = 104;
    constexpr int VPS = NY + 24;
    constexpr int KVH = (NY * KS > 96 * VPS) ? NY * KS : 96 * VPS;
    constexpr int NG  = (MODE == 0) ? T_ : F_;
    constexpr int GOFF = (MODE == 0) ? F_ : C_ * T_;

    extern __shared__ _Float16 ldsh[];
    _Float16* KV = ldsh;                 // Kt[NY][KS] -> V[96][VPS]
    _Float16* Pw = ldsh + KVH;           // [4][16][40]

    const int lb    = blockIdx.y;
    const int strip = blockIdx.x / NG;
    const int grp   = blockIdx.x % NG;
    const int m0    = strip * 64;
    const size_t off = (size_t)grp * GOFF;
    const _Float16* Q = Qb + (size_t)lb * qs + off;
    const _Float16* K = Kb + (size_t)lb * ks + off;
    const _Float16* V = Vb + (size_t)lb * vs + off;
    _Float16*       O = Ob + (size_t)lb * os + off;

    const int tid  = threadIdx.x;
    const int lane = tid & 63, wid = tid >> 6;
    const int l16  = lane & 15, lg = lane >> 4;
    const int mw   = wid * 16;
    const float scale = 0.10206207261596575f;   // 1/sqrt(96)

    for (int e = tid; e < NY * 12; e += 256) {
        const int yy = e % NY, k0 = (e / NY) * 8;
        const _Float16* kp = K + (size_t)k0 * LD + yy;
        h8 hv;
#pragma unroll
        for (int j = 0; j < 8; ++j) hv[j] = kp[(size_t)j * LD];
        *(h8*)&KV[yy * KS + k0] = hv;
    }

    h8 aQ[3];
#pragma unroll
    for (int kk = 0; kk < 3; ++kk) {
        const _Float16* qp = Q + (size_t)(kk * 32 + lg * 8) * LD + m0 + mw + l16;
#pragma unroll
        for (int j = 0; j < 8; ++j) aQ[kk][j] = qp[(size_t)j * LD];
    }
    __syncthreads();

    f32x4 sacc[NT];
#pragma unroll
    for (int t = 0; t < NT; ++t) sacc[t] = (f32x4){0.f, 0.f, 0.f, 0.f};
#pragma unroll
    for (int kk = 0; kk < 3; ++kk) {
#pragma unroll
        for (int t = 0; t < NT; ++t) {
            const h8 bK = *(const h8*)&KV[(t * 16 + l16) * KS + kk * 32 + lg * 8];
            sacc[t] = __builtin_amdgcn_mfma_f32_16x16x32_f16(aQ[kk], bK, sacc[t], 0, 0, 0);
        }
    }

#pragma unroll
    for (int r = 0; r < 4; ++r) {
        float mx = sacc[0][r];
#pragma unroll
        for (int t = 1; t < NT; ++t) mx = fmaxf(mx, sacc[t][r]);
        for (int d = 1; d < 16; d <<= 1) mx = fmaxf(mx, __shfl_xor(mx, d));
        float pv[NT];
        float sum = 0.f;
#pragma unroll
        for (int t = 0; t < NT; ++t) {
            pv[t] = __expf((sacc[t][r] - mx) * scale); sum += pv[t];
        }
        for (int d = 1; d < 16; d <<= 1) sum += __shfl_xor(sum, d);
        const float inv = 1.f / sum;
#pragma unroll
        for (int t = 0; t < NT; ++t) sacc[t][r] = pv[t] * inv;
    }
    __syncthreads();

    constexpr int NY8 = NY / 8;
    for (int e = tid; e < 96 * NY8; e += 256) {
        const int c = e / NY8, y8 = e - c * NY8;
        *(h8*)&KV[c * VPS + y8 * 8] = *(const h8*)(V + (size_t)c * LD + y8 * 8);
    }
    __syncthreads();

    _Float16* Pme = Pw + wid * 640;      // [16][40]
    f32x4 oacc[6];
#pragma unroll
    for (int ct = 0; ct < 6; ++ct) oacc[ct] = (f32x4){0.f, 0.f, 0.f, 0.f};

#pragma unroll
    for (int yk = 0; yk < NYK; ++yk) {
#pragma unroll
        for (int h = 0; h < 2; ++h)
#pragma unroll
            for (int r = 0; r < 4; ++r)
                Pme[(lg * 4 + r) * 40 + h * 16 + l16] = (_Float16)sacc[2 * yk + h][r];
        const h8 pf = *(const h8*)&Pme[l16 * 40 + lg * 8];   // in-wave DS order
#pragma unroll
        for (int ct = 0; ct < 6; ++ct) {
            const h8 av = *(const h8*)&KV[(ct * 16 + l16) * VPS + yk * 32 + lg * 8];
            oacc[ct] = __builtin_amdgcn_mfma_f32_16x16x32_f16(av, pf, oacc[ct], 0, 0, 0);
        }
    }
#pragma unroll
    for (int ct = 0; ct < 6; ++ct)
#pragma unroll
        for (int r = 0; r < 4; ++r)
            O[(size_t)(ct * 16 + lg * 4 + r) * LD + m0 + mw + l16] = (_Float16)oacc[ct][r];
}

// ---------------------------------------------------------------------------
extern "C" void kernel_launch(void* const* d_in, const int* in_sizes, int n_in,
                              void* d_out, int out_size, void* d_ws, size_t ws_size,
                              hipStream_t stream)
{
    const float* inp = (const float*)d_in[0];
    const float* W_f = (const float*)d_in[1];  const float* b_f = (const float*)d_in[2];
    const float* g_f = (const float*)d_in[3];  const float* be_f = (const float*)d_in[4];
    const float* m_f = (const float*)d_in[5];  const float* v_f = (const float*)d_in[6];
    const float* a_f = (const float*)d_in[7];
    const float* W_t = (const float*)d_in[8];  const float* b_t = (const float*)d_in[9];
    const float* g_t = (const float*)d_in[10]; const float* be_t = (const float*)d_in[11];
    const float* m_t = (const float*)d_in[12]; const float* v_t = (const float*)d_in[13];
    const float* a_t = (const float*)d_in[14];
    const float* W_p = (const float*)d_in[15]; const float* b_p = (const float*)d_in[16];
    const float* g_p = (const float*)d_in[17]; const float* be_p = (const float*)d_in[18];
    const float* m_p = (const float*)d_in[19]; const float* v_p = (const float*)d_in[20];
    const float* a_p = (const float*)d_in[21];

    hipFuncSetAttribute((const void*)conv_ft,
                        hipFuncAttributeMaxDynamicSharedMemorySize, 51200);
    hipFuncSetAttribute((const void*)conv_p,
                        hipFuncAttributeMaxDynamicSharedMemorySize, 33280);
    hipFuncSetAttribute((const void*)attn_mfma<0>,
                        hipFuncAttributeMaxDynamicSharedMemorySize, 58880);
    hipFuncSetAttribute((const void*)attn_mfma<1>,
                        hipFuncAttributeMaxDynamicSharedMemorySize, 71680);

    // Unit plan per batch b (f16 units of QH_ elems, stride 3*QH_):
    //  3b+0: fqkv Q -> fout (attn0 in-place) -> [trA] -> tkT -> tmp
    //  3b+1: fqkv K -> foutT (trA)
    //  3b+2: fqkv V -> tqT (trA) -> tout (attn1 in-place)
    //  d_out slice (2 f16 units/batch): th2 q,k halves.
    constexpr int QH = (int)QH_;
    const size_t need4 = (size_t)12 * QH * 2 + (size_t)WTOT * 2 + 1152 * 4 + 4096;
    const int G = (ws_size >= need4) ? 4 : 2;     // batches per pass

    _Float16* wsh  = (_Float16*)d_ws;
    _Float16* wsp  = wsh + (size_t)3 * G * QH;    // W-split tail
    float*    scsh = (float*)(wsp + WTOT);

    prep_kernel<<<dim3(128), dim3(256), 0, stream>>>(
        W_f, W_t, W_p, b_f, g_f, be_f, m_f, v_f,
        b_t, g_t, be_t, m_t, v_t, b_p, g_p, be_p, m_p, v_p, wsp, scsh);

    for (int p = 0; p < B_ / G; ++p) {
        const float* xb  = inp + (size_t)p * G * QH;
        float*       dob = (float*)d_out + (size_t)p * G * QH;
        _Float16*    doh = (_Float16*)dob;        // th2 (2 units/batch)

        // 1. fused conv_f + conv_t: 2 tiles/block, T14 prefetch
        conv_ft<<<dim3(640, G), dim3(256), 51200, stream>>>(
            xb, wsp, scsh, a_f, a_t, wsh, doh, QH, 3 * QH, 2 * QH);
        // 2. f-attention, O in-place over Q third
        attn_mfma<0><<<dim3(T_ * (F_ / 64), G), dim3(256), 58880, stream>>>(
            wsh, wsh + QH_, wsh + 2 * QH_, wsh, 3 * QH, 3 * QH, 3 * QH, 3 * QH);
        // 3. trA: fout -> foutT (3b+1), th2 q -> tqT (3b+2)   [64x64 tiles]
        transpose_trA<<<dim3(480, 4, 2 * G), dim3(256), 0, stream>>>(doh, wsh);
        // 4. trB: th2 k -> tkT (3b+0; fout dead)
        transpose_trB<<<dim3(480, 4, G), dim3(256), 0, stream>>>(doh, wsh);
        // 5. t-attention: Q=tqT(3b+2), K=tkT(3b+0), V=foutT(3b+1), O in-place
        attn_mfma<1><<<dim3(F_ * (T_ / 64), G), dim3(256), 71680, stream>>>(
            wsh + 2 * QH_, wsh, wsh + QH_, wsh + 2 * QH_,
            3 * QH, 3 * QH, 3 * QH, 3 * QH);
        // 6. conv_p(tout = 3b+2) -> tmp (3b+0; tkT dead)
        conv_p<<<dim3(F_ * 2, G), dim3(256), 33280, stream>>>(
            wsh + 2 * QH_, wsp, scsh, a_p, wsh, 3 * QH, 3 * QH);
        // 7. out = transpose(tmp) + inp (th2 dead)  [64x64 tiles]
        transpose_hf_res<<<dim3(4, 480, G), dim3(256), 0, stream>>>(
            wsh, xb, dob, 3 * QH, QH, QH);
    }
}

// Round 19
// 712.837 us; speedup vs baseline: 1.1033x; 1.0012x over previous
//
#include <hip/hip_runtime.h>
#include <math.h>

typedef float f4 __attribute__((ext_vector_type(4)));
typedef float f2 __attribute__((ext_vector_type(2)));
typedef float f32x4 __attribute__((ext_vector_type(4)));
typedef _Float16 h8 __attribute__((ext_vector_type(8)));

constexpr int B_ = 4, C_ = 96, T_ = 320, F_ = 256;
constexpr int TF_ = T_ * F_;          // 81920
constexpr float EPS_ = 1e-5f;
constexpr size_t QH_ = (size_t)C_ * TF_;   // 7,864,320 elems per (C,T,F) unit

// W-split scratch layout (f16 elems, appended after the data units):
constexpr int WHF = 0, WLF = 27648, WHT = 55296, WLT = 73728,
              WHP = 92160, WLP = 101376, WTOT = 110592;

// ---------------------------------------------------------------------------
// One-time prep: split W into hi/lo f16; precompute BN (sc, sh) per channel.
// ---------------------------------------------------------------------------
__global__ __launch_bounds__(256)
void prep_kernel(const float* __restrict__ Wf, const float* __restrict__ Wt,
                 const float* __restrict__ Wp,
                 const float* __restrict__ bf, const float* __restrict__ gf,
                 const float* __restrict__ bef, const float* __restrict__ mf,
                 const float* __restrict__ vf,
                 const float* __restrict__ bt, const float* __restrict__ gt,
                 const float* __restrict__ bet, const float* __restrict__ mt,
                 const float* __restrict__ vt,
                 const float* __restrict__ bp, const float* __restrict__ gp,
                 const float* __restrict__ bep, const float* __restrict__ mp,
                 const float* __restrict__ vp,
                 _Float16* __restrict__ wsp, float* __restrict__ scsh)
{
    const int gtid = blockIdx.x * 256 + threadIdx.x;
    const int gsz  = gridDim.x * 256;
    for (int i = gtid; i < 27648; i += gsz) {
        const float w = Wf[i]; const _Float16 h = (_Float16)w;
        wsp[WHF + i] = h; wsp[WLF + i] = (_Float16)(w - (float)h);
    }
    for (int i = gtid; i < 18432; i += gsz) {
        const float w = Wt[i]; const _Float16 h = (_Float16)w;
        wsp[WHT + i] = h; wsp[WLT + i] = (_Float16)(w - (float)h);
    }
    for (int i = gtid; i < 9216; i += gsz) {
        const float w = Wp[i]; const _Float16 h = (_Float16)w;
        wsp[WHP + i] = h; wsp[WLP + i] = (_Float16)(w - (float)h);
    }
    if (gtid < 288) {
        const float sc = gf[gtid] * rsqrtf(vf[gtid] + EPS_);
        scsh[2 * gtid] = sc;
        scsh[2 * gtid + 1] = fmaf(bf[gtid] - mf[gtid], sc, bef[gtid]);
    } else if (gtid < 480) {
        const int i = gtid - 288;
        const float sc = gt[i] * rsqrtf(vt[i] + EPS_);
        scsh[576 + 2 * i] = sc;
        scsh[576 + 2 * i + 1] = fmaf(bt[i] - mt[i], sc, bet[i]);
    } else if (gtid < 576) {
        const int i = gtid - 480;
        const float sc = gp[i] * rsqrtf(vp[i] + EPS_);
        scsh[960 + 2 * i] = sc;
        scsh[960 + 2 * i + 1] = fmaf(bp[i] - mp[i], sc, bep[i]);
    }
}

// ---------------------------------------------------------------------------
// Fused conv_f + conv_t, 2 p-tiles/block with T14 issue-early/write-late.
// Proven at 224us / 84 VGPR / no spill.  FROZEN.
// ---------------------------------------------------------------------------
__global__ __launch_bounds__(256, 3)
void conv_ft(const float* __restrict__ x, const _Float16* __restrict__ wsp,
             const float* __restrict__ scsh,
             const float* __restrict__ aPf, const float* __restrict__ aPt,
             _Float16* __restrict__ yf, _Float16* __restrict__ yt,
             int bsx, int bsyf, int bsyt)
{
    constexpr int LS = 200;
    extern __shared__ _Float16 ldsh[];
    _Float16* Xs0 = ldsh;                  // [64][200]: 0-95 hi, 96-191 lo
    _Float16* Xs1 = ldsh + 64 * LS;

    x  += (size_t)blockIdx.y * bsx;
    yf += (size_t)blockIdx.y * bsyf;
    yt += (size_t)blockIdx.y * bsyt;

    const int tid = threadIdx.x;
    const int p0A = blockIdx.x * 128;
    const int p0B = p0A + 64;

    {
        const float* xg = x + p0A;
        for (int e = tid; e < 64 * 12; e += 256) {
            const int p = e & 63, k0 = (e >> 6) * 8;
            const float* xp = xg + (size_t)k0 * TF_ + p;
            h8 hv, lv;
#pragma unroll
            for (int j = 0; j < 8; ++j) {
                const float xv = xp[(size_t)j * TF_];
                const _Float16 xh = (_Float16)xv;
                hv[j] = xh;
                lv[j] = (_Float16)(xv - (float)xh);
            }
            *(h8*)&Xs0[p * LS + k0]      = hv;
            *(h8*)&Xs0[p * LS + 96 + k0] = lv;
        }
    }

    const int lane = tid & 63, wid = tid >> 6;
    const int l16 = lane & 15, lg = lane >> 4;
    const int wm = wid >> 1, wn = wid & 1;       // 2x2 wave grid
    const float af_ = aPf[0], at_ = aPt[0];
    __syncthreads();

    float xpre[3][8];
#pragma unroll
    for (int it = 0; it < 3; ++it) {
        const int e = tid + it * 256;
        const int p = e & 63, k0 = (e >> 6) * 8;
        const float* xp = x + p0B + (size_t)k0 * TF_ + p;
#pragma unroll
        for (int j = 0; j < 8; ++j) xpre[it][j] = xp[(size_t)j * TF_];
    }

    auto compute5 = [&](const _Float16* Xs, int p0) {
#pragma unroll 1
        for (int cg = 0; cg < 5; ++cg) {
            const _Float16 *Wh, *Wl; const float* ss; float a; _Float16* yo;
            if (cg < 3) {
                Wh = wsp + WHF + cg * 9216;  Wl = wsp + WLF + cg * 9216;
                ss = scsh + cg * 192;        a = af_;
                yo = yf + (size_t)cg * QH_;
            } else {
                const int c2 = cg - 3;
                Wh = wsp + WHT + c2 * 9216;  Wl = wsp + WLT + c2 * 9216;
                ss = scsh + 576 + c2 * 192;  a = at_;
                yo = yt + (size_t)c2 * QH_;
            }

            f32x4 acc[3][2];
#pragma unroll
            for (int m = 0; m < 3; ++m)
#pragma unroll
                for (int n = 0; n < 2; ++n) acc[m][n] = (f32x4){0.f, 0.f, 0.f, 0.f};

#pragma unroll
            for (int kk = 0; kk < 3; ++kk) {
                h8 bfh[2], bfl[2];
#pragma unroll
                for (int n = 0; n < 2; ++n) {
                    const int prow = (wn * 2 + n) * 16 + l16;
                    bfh[n] = *(const h8*)&Xs[prow * LS + kk * 32 + lg * 8];
                    bfl[n] = *(const h8*)&Xs[prow * LS + 96 + kk * 32 + lg * 8];
                }
#pragma unroll
                for (int m = 0; m < 3; ++m) {
                    const int row = (wm * 3 + m) * 16 + l16;
                    const h8 wh = *(const h8*)&Wh[row * 96 + kk * 32 + lg * 8];
                    const h8 wl = *(const h8*)&Wl[row * 96 + kk * 32 + lg * 8];
#pragma unroll
                    for (int n = 0; n < 2; ++n) {
                        acc[m][n] = __builtin_amdgcn_mfma_f32_16x16x32_f16(wh, bfh[n], acc[m][n], 0, 0, 0);
                        acc[m][n] = __builtin_amdgcn_mfma_f32_16x16x32_f16(wl, bfh[n], acc[m][n], 0, 0, 0);
                        acc[m][n] = __builtin_amdgcn_mfma_f32_16x16x32_f16(wh, bfl[n], acc[m][n], 0, 0, 0);
                    }
                }
            }

#pragma unroll
            for (int m = 0; m < 3; ++m) {
#pragma unroll
                for (int r = 0; r < 4; ++r) {
                    const int col = (wm * 3 + m) * 16 + lg * 4 + r;
                    const f2 sp = *(const f2*)&ss[2 * col];
                    _Float16* yr = yo + (size_t)col * TF_ + p0 + wn * 32 + l16;
#pragma unroll
                    for (int n = 0; n < 2; ++n) {
                        const float v = fmaf(acc[m][n][r], sp[0], sp[1]);
                        yr[n * 16] = (_Float16)(v >= 0.f ? v : a * v);
                    }
                }
            }
        }
    };

    compute5(Xs0, p0A);

#pragma unroll
    for (int it = 0; it < 3; ++it) {
        const int e = tid + it * 256;
        const int p = e & 63, k0 = (e >> 6) * 8;
        h8 hv, lv;
#pragma unroll
        for (int j = 0; j < 8; ++j) {
            const _Float16 xh = (_Float16)xpre[it][j];
            hv[j] = xh;
            lv[j] = (_Float16)(xpre[it][j] - (float)xh);
        }
        *(h8*)&Xs1[p * LS + k0]      = hv;
        *(h8*)&Xs1[p * LS + 96 + k0] = lv;
    }
    __syncthreads();

    compute5(Xs1, p0B);
}

// ---------------------------------------------------------------------------
// conv_p (fallback path only): f16 input (F groups, C, T), pre-split W.
// ---------------------------------------------------------------------------
__global__ __launch_bounds__(256, 3)
void conv_p(const _Float16* __restrict__ x, const _Float16* __restrict__ wsp,
            const float* __restrict__ scsh, const float* __restrict__ aPp,
            _Float16* __restrict__ y, int bsx, int bsy)
{
    constexpr int LS = 104, PT = 160, NN = 5;
    extern __shared__ _Float16 ldsh[];
    _Float16* Xs = ldsh;                   // [160][104]

    x += (size_t)blockIdx.y * bsx;
    y += (size_t)blockIdx.y * bsy;

    const int tid = threadIdx.x;
    const int pt  = blockIdx.x & 1;
    const int g   = blockIdx.x >> 1;
    const int p0  = pt * PT;

    const _Float16* xg = x + (size_t)g * 96 * T_ + p0;
    for (int e = tid; e < PT * 12; e += 256) {
        const int p = e % PT, k0 = (e / PT) * 8;
        const _Float16* xp = xg + (size_t)k0 * T_ + p;
        h8 hv;
#pragma unroll
        for (int j = 0; j < 8; ++j) hv[j] = xp[(size_t)j * T_];
        *(h8*)&Xs[p * LS + k0] = hv;
    }

    const int lane = tid & 63, wid = tid >> 6;
    const int l16 = lane & 15, lg = lane >> 4;
    const int wm = wid >> 1, wn = wid & 1;
    const float a = aPp[0];
    const _Float16* Wh = wsp + WHP;
    const _Float16* Wl = wsp + WLP;
    const float* ss = scsh + 960;
    __syncthreads();

    f32x4 acc[3][NN];
#pragma unroll
    for (int m = 0; m < 3; ++m)
#pragma unroll
        for (int n = 0; n < NN; ++n) acc[m][n] = (f32x4){0.f, 0.f, 0.f, 0.f};

#pragma unroll
    for (int kk = 0; kk < 3; ++kk) {
        h8 bf[NN];
#pragma unroll
        for (int n = 0; n < NN; ++n)
            bf[n] = *(const h8*)&Xs[((wn * NN + n) * 16 + l16) * LS + kk * 32 + lg * 8];
#pragma unroll
        for (int m = 0; m < 3; ++m) {
            const int row = (wm * 3 + m) * 16 + l16;
            const h8 wh = *(const h8*)&Wh[row * 96 + kk * 32 + lg * 8];
            const h8 wl = *(const h8*)&Wl[row * 96 + kk * 32 + lg * 8];
#pragma unroll
            for (int n = 0; n < NN; ++n) {
                acc[m][n] = __builtin_amdgcn_mfma_f32_16x16x32_f16(wh, bf[n], acc[m][n], 0, 0, 0);
                acc[m][n] = __builtin_amdgcn_mfma_f32_16x16x32_f16(wl, bf[n], acc[m][n], 0, 0, 0);
            }
        }
    }

#pragma unroll
    for (int m = 0; m < 3; ++m) {
#pragma unroll
        for (int r = 0; r < 4; ++r) {
            const int col = (wm * 3 + m) * 16 + lg * 4 + r;
            const f2 sp = *(const f2*)&ss[2 * col];
            _Float16* yr = y + ((size_t)g * 96 + col) * T_ + p0 + wn * NN * 16 + l16;
#pragma unroll
            for (int n = 0; n < NN; ++n) {
                const float v = fmaf(acc[m][n][r], sp[0], sp[1]);
                yr[n * 16] = (_Float16)(v >= 0.f ? v : a * v);
            }
        }
    }
}

// ---------------------------------------------------------------------------
// 64x64 f16 transpose core: h8 global I/O, XOR-swizzled LDS tile [64][72].
// ---------------------------------------------------------------------------
__device__ __forceinline__ void tr64_body(const _Float16* __restrict__ in,
                                          _Float16* __restrict__ out,
                                          int Mo, int No, int n0, int m0,
                                          _Float16* tile)
{
    const int t = threadIdx.x, ty = t >> 3, tx8 = t & 7;
#pragma unroll
    for (int r = 0; r < 2; ++r) {
        const int n = ty + r * 32;
        const h8 v = *(const h8*)&in[(size_t)(n0 + n) * Mo + m0 + tx8 * 8];
        const int c = tx8 ^ (n >> 3);
        *(h8*)&tile[n * 72 + c * 8] = v;
    }
    __syncthreads();
#pragma unroll
    for (int r = 0; r < 2; ++r) {
        const int mt = ty + r * 32;
        h8 v;
#pragma unroll
        for (int j = 0; j < 8; ++j) {
            const int n = tx8 * 8 + j;
            const int c = (mt >> 3) ^ tx8;           // n>>3 == tx8
            v[j] = tile[n * 72 + c * 8 + (mt & 7)];
        }
        *(h8*)&out[(size_t)(m0 + mt) * No + n0 + tx8 * 8] = v;
    }
}

// trA: per batch 2 slabs (z = b*2+t): t=0 fout->foutT, t=1 th2 q->tqT.
__global__ __launch_bounds__(256)
void transpose_trA(const _Float16* __restrict__ doh, _Float16* __restrict__ wsh)
{
    __shared__ _Float16 tile[64 * 72];
    const int b = blockIdx.z >> 1, t = blockIdx.z & 1;
    const _Float16* in  = t ? doh + (size_t)b * 2 * QH_
                            : wsh + (size_t)b * 3 * QH_;
    _Float16*       out = t ? wsh + (size_t)b * 3 * QH_ + 2 * QH_
                            : wsh + (size_t)b * 3 * QH_ + QH_;
    tr64_body(in, out, F_, C_ * T_, blockIdx.x * 64, blockIdx.y * 64, tile);
}

// trB: th2 k-half -> tkT (unit 3b+0; fout dead after trA).
__global__ __launch_bounds__(256)
void transpose_trB(const _Float16* __restrict__ doh, _Float16* __restrict__ wsh)
{
    __shared__ _Float16 tile[64 * 72];
    const int b = blockIdx.z;
    tr64_body(doh + (size_t)b * 2 * QH_ + QH_, wsh + (size_t)b * 3 * QH_,
              F_, C_ * T_, blockIdx.x * 64, blockIdx.y * 64, tile);
}

// hf_res: tmp (F_, C*T) f16 + res f32 -> out (C*T, F_) f32.
__global__ __launch_bounds__(256)
void transpose_hf_res(const _Float16* __restrict__ in, const float* __restrict__ res,
                      float* __restrict__ out, int si, int sr, int so)
{
    __shared__ _Float16 tile[64 * 72];
    in  += (size_t)blockIdx.z * si;
    res += (size_t)blockIdx.z * sr;
    out += (size_t)blockIdx.z * so;
    const int n0 = blockIdx.x * 64, m0 = blockIdx.y * 64;
    const int t = threadIdx.x, ty = t >> 3, tx8 = t & 7;
#pragma unroll
    for (int r = 0; r < 2; ++r) {
        const int n = ty + r * 32;
        const h8 v = *(const h8*)&in[(size_t)(n0 + n) * (C_ * T_) + m0 + tx8 * 8];
        const int c = tx8 ^ (n >> 3);
        *(h8*)&tile[n * 72 + c * 8] = v;
    }
    __syncthreads();
#pragma unroll
    for (int r = 0; r < 2; ++r) {
        const int mt = ty + r * 32;
        const size_t obase = (size_t)(m0 + mt) * F_ + n0 + tx8 * 8;
        const f4 r0 = *(const f4*)&res[obase];
        const f4 r1 = *(const f4*)&res[obase + 4];
        f4 o0, o1;
#pragma unroll
        for (int j = 0; j < 8; ++j) {
            const int n = tx8 * 8 + j;
            const int c = (mt >> 3) ^ tx8;
            const float v = (float)tile[n * 72 + c * 8 + (mt & 7)];
            if (j < 4) o0[j] = v + r0[j]; else o1[j - 4] = v + r1[j - 4];
        }
        *(f4*)&out[obase]     = o0;
        *(f4*)&out[obase + 4] = o1;
    }
}

// ---------------------------------------------------------------------------
// MFMA f16 fused attention (fallback mode 1 + mode 0).  O may alias Q.
// ---------------------------------------------------------------------------
template<int MODE>
__global__ __launch_bounds__(256, 2)
void attn_mfma(const _Float16* __restrict__ Qb, const _Float16* __restrict__ Kb,
               const _Float16* __restrict__ Vb, _Float16* __restrict__ Ob,
               int qs, int ks, int vs, int os)
{
    constexpr int NY  = (MODE == 0) ? 256 : 320;
    constexpr int LD  = (MODE == 0) ? TF_ : T_;
    constexpr int NT  = NY / 16;
    constexpr int NYK = NY / 32;
    constexpr int KS  = 104;
    constexpr int VPS = NY + 24;
    constexpr int KVH = (NY * KS > 96 * VPS) ? NY * KS : 96 * VPS;
    constexpr int NG  = (MODE == 0) ? T_ : F_;
    constexpr int GOFF = (MODE == 0) ? F_ : C_ * T_;

    extern __shared__ _Float16 ldsh[];
    _Float16* KV = ldsh;                 // Kt[NY][KS] -> V[96][VPS]
    _Float16* Pw = ldsh + KVH;           // [4][16][40]

    const int lb    = blockIdx.y;
    const int strip = blockIdx.x / NG;
    const int grp   = blockIdx.x % NG;
    const int m0    = strip * 64;
    const size_t off = (size_t)grp * GOFF;
    const _Float16* Q = Qb + (size_t)lb * qs + off;
    const _Float16* K = Kb + (size_t)lb * ks + off;
    const _Float16* V = Vb + (size_t)lb * vs + off;
    _Float16*       O = Ob + (size_t)lb * os + off;

    const int tid  = threadIdx.x;
    const int lane = tid & 63, wid = tid >> 6;
    const int l16  = lane & 15, lg = lane >> 4;
    const int mw   = wid * 16;
    const float scale = 0.10206207261596575f;   // 1/sqrt(96)

    for (int e = tid; e < NY * 12; e += 256) {
        const int yy = e % NY, k0 = (e / NY) * 8;
        const _Float16* kp = K + (size_t)k0 * LD + yy;
        h8 hv;
#pragma unroll
        for (int j = 0; j < 8; ++j) hv[j] = kp[(size_t)j * LD];
        *(h8*)&KV[yy * KS + k0] = hv;
    }

    h8 aQ[3];
#pragma unroll
    for (int kk = 0; kk < 3; ++kk) {
        const _Float16* qp = Q + (size_t)(kk * 32 + lg * 8) * LD + m0 + mw + l16;
#pragma unroll
        for (int j = 0; j < 8; ++j) aQ[kk][j] = qp[(size_t)j * LD];
    }
    __syncthreads();

    f32x4 sacc[NT];
#pragma unroll
    for (int t = 0; t < NT; ++t) sacc[t] = (f32x4){0.f, 0.f, 0.f, 0.f};
#pragma unroll
    for (int kk = 0; kk < 3; ++kk) {
#pragma unroll
        for (int t = 0; t < NT; ++t) {
            const h8 bK = *(const h8*)&KV[(t * 16 + l16) * KS + kk * 32 + lg * 8];
            sacc[t] = __builtin_amdgcn_mfma_f32_16x16x32_f16(aQ[kk], bK, sacc[t], 0, 0, 0);
        }
    }

#pragma unroll
    for (int r = 0; r < 4; ++r) {
        float mx = sacc[0][r];
#pragma unroll
        for (int t = 1; t < NT; ++t) mx = fmaxf(mx, sacc[t][r]);
        for (int d = 1; d < 16; d <<= 1) mx = fmaxf(mx, __shfl_xor(mx, d));
        float pv[NT];
        float sum = 0.f;
#pragma unroll
        for (int t = 0; t < NT; ++t) {
            pv[t] = __expf((sacc[t][r] - mx) * scale); sum += pv[t];
        }
        for (int d = 1; d < 16; d <<= 1) sum += __shfl_xor(sum, d);
        const float inv = 1.f / sum;
#pragma unroll
        for (int t = 0; t < NT; ++t) sacc[t][r] = pv[t] * inv;
    }
    __syncthreads();

    constexpr int NY8 = NY / 8;
    for (int e = tid; e < 96 * NY8; e += 256) {
        const int c = e / NY8, y8 = e - c * NY8;
        *(h8*)&KV[c * VPS + y8 * 8] = *(const h8*)(V + (size_t)c * LD + y8 * 8);
    }
    __syncthreads();

    _Float16* Pme = Pw + wid * 640;      // [16][40]
    f32x4 oacc[6];
#pragma unroll
    for (int ct = 0; ct < 6; ++ct) oacc[ct] = (f32x4){0.f, 0.f, 0.f, 0.f};

#pragma unroll
    for (int yk = 0; yk < NYK; ++yk) {
#pragma unroll
        for (int h = 0; h < 2; ++h)
#pragma unroll
            for (int r = 0; r < 4; ++r)
                Pme[(lg * 4 + r) * 40 + h * 16 + l16] = (_Float16)sacc[2 * yk + h][r];
        const h8 pf = *(const h8*)&Pme[l16 * 40 + lg * 8];   // in-wave DS order
#pragma unroll
        for (int ct = 0; ct < 6; ++ct) {
            const h8 av = *(const h8*)&KV[(ct * 16 + l16) * VPS + yk * 32 + lg * 8];
            oacc[ct] = __builtin_amdgcn_mfma_f32_16x16x32_f16(av, pf, oacc[ct], 0, 0, 0);
        }
    }
#pragma unroll
    for (int ct = 0; ct < 6; ++ct)
#pragma unroll
        for (int r = 0; r < 4; ++r)
            O[(size_t)(ct * 16 + lg * 4 + r) * LD + m0 + mw + l16] = (_Float16)oacc[ct][r];
}

// ---------------------------------------------------------------------------
// attn1_fused: t-attention (mode 1) + conv_p fused in-block.
// After PV, the O tile [96c][64t] goes to LDS Ot (over dead V region, stride
// 104), then a 36-MFMA pass vs pre-split W_p + BN/PReLU writes tmp (F,C,T)
// directly.  No tout round-trip, no conv_p dispatch.
// ---------------------------------------------------------------------------
__global__ __launch_bounds__(256, 2)
void attn1_fused(const _Float16* __restrict__ Qb, const _Float16* __restrict__ Kb,
                 const _Float16* __restrict__ Vb, _Float16* __restrict__ tmpb,
                 const _Float16* __restrict__ wsp, const float* __restrict__ scsh,
                 const float* __restrict__ aPp,
                 int qs, int ks, int vs, int ts)
{
    constexpr int NY = 320, LD = T_, NT = 20, NYK = 10;
    constexpr int KS = 104, VPS = 344;
    constexpr int KVH = NY * KS;         // 33280 >= 96*VPS=33024 and >= Ot 6656
    constexpr int OS  = 104;             // Ot stride

    extern __shared__ _Float16 ldsh[];
    _Float16* KV = ldsh;                 // Kt -> V -> Ot
    _Float16* Pw = ldsh + KVH;
    _Float16* Ot = ldsh;                 // [64 t][OS] over dead V

    const int lb    = blockIdx.y;
    const int strip = blockIdx.x / F_;
    const int grp   = blockIdx.x % F_;
    const int m0    = strip * 64;
    const size_t off = (size_t)grp * (C_ * T_);
    const _Float16* Q = Qb + (size_t)lb * qs + off;
    const _Float16* K = Kb + (size_t)lb * ks + off;
    const _Float16* V = Vb + (size_t)lb * vs + off;
    _Float16*     tmp = tmpb + (size_t)lb * ts + (size_t)grp * (96 * T_);

    const int tid  = threadIdx.x;
    const int lane = tid & 63, wid = tid >> 6;
    const int l16  = lane & 15, lg = lane >> 4;
    const int mw   = wid * 16;
    const float scale = 0.10206207261596575f;

    for (int e = tid; e < NY * 12; e += 256) {
        const int yy = e % NY, k0 = (e / NY) * 8;
        const _Float16* kp = K + (size_t)k0 * LD + yy;
        h8 hv;
#pragma unroll
        for (int j = 0; j < 8; ++j) hv[j] = kp[(size_t)j * LD];
        *(h8*)&KV[yy * KS + k0] = hv;
    }

    h8 aQ[3];
#pragma unroll
    for (int kk = 0; kk < 3; ++kk) {
        const _Float16* qp = Q + (size_t)(kk * 32 + lg * 8) * LD + m0 + mw + l16;
#pragma unroll
        for (int j = 0; j < 8; ++j) aQ[kk][j] = qp[(size_t)j * LD];
    }
    __syncthreads();

    f32x4 sacc[NT];
#pragma unroll
    for (int t = 0; t < NT; ++t) sacc[t] = (f32x4){0.f, 0.f, 0.f, 0.f};
#pragma unroll
    for (int kk = 0; kk < 3; ++kk) {
#pragma unroll
        for (int t = 0; t < NT; ++t) {
            const h8 bK = *(const h8*)&KV[(t * 16 + l16) * KS + kk * 32 + lg * 8];
            sacc[t] = __builtin_amdgcn_mfma_f32_16x16x32_f16(aQ[kk], bK, sacc[t], 0, 0, 0);
        }
    }

#pragma unroll
    for (int r = 0; r < 4; ++r) {
        float mx = sacc[0][r];
#pragma unroll
        for (int t = 1; t < NT; ++t) mx = fmaxf(mx, sacc[t][r]);
        for (int d = 1; d < 16; d <<= 1) mx = fmaxf(mx, __shfl_xor(mx, d));
        float pv[NT];
        float sum = 0.f;
#pragma unroll
        for (int t = 0; t < NT; ++t) {
            pv[t] = __expf((sacc[t][r] - mx) * scale); sum += pv[t];
        }
        for (int d = 1; d < 16; d <<= 1) sum += __shfl_xor(sum, d);
        const float inv = 1.f / sum;
#pragma unroll
        for (int t = 0; t < NT; ++t) sacc[t][r] = pv[t] * inv;
    }
    __syncthreads();

    for (int e = tid; e < 96 * 40; e += 256) {       // V stage (NY8=40)
        const int c = e / 40, y8 = e - c * 40;
        *(h8*)&KV[c * VPS + y8 * 8] = *(const h8*)(V + (size_t)c * LD + y8 * 8);
    }
    __syncthreads();

    _Float16* Pme = Pw + wid * 640;
    f32x4 oacc[6];
#pragma unroll
    for (int ct = 0; ct < 6; ++ct) oacc[ct] = (f32x4){0.f, 0.f, 0.f, 0.f};

#pragma unroll
    for (int yk = 0; yk < NYK; ++yk) {
#pragma unroll
        for (int h = 0; h < 2; ++h)
#pragma unroll
            for (int r = 0; r < 4; ++r)
                Pme[(lg * 4 + r) * 40 + h * 16 + l16] = (_Float16)sacc[2 * yk + h][r];
        const h8 pf = *(const h8*)&Pme[l16 * 40 + lg * 8];
#pragma unroll
        for (int ct = 0; ct < 6; ++ct) {
            const h8 av = *(const h8*)&KV[(ct * 16 + l16) * VPS + yk * 32 + lg * 8];
            oacc[ct] = __builtin_amdgcn_mfma_f32_16x16x32_f16(av, pf, oacc[ct], 0, 0, 0);
        }
    }

    // ---- O tile -> LDS Ot[t][c] over dead V (all V reads done) ----
    __syncthreads();
#pragma unroll
    for (int ct = 0; ct < 6; ++ct)
#pragma unroll
        for (int r = 0; r < 4; ++r)
            Ot[(mw + l16) * OS + ct * 16 + lg * 4 + r] = (_Float16)oacc[ct][r];
    __syncthreads();

    // ---- conv_p pass: D[co][t] = act(BN(sum_c Wp[co][c] Ot[t][c])) ----
    const int wm = wid >> 1, wn = wid & 1;
    const float a = aPp[0];
    const _Float16* Wh = wsp + WHP;
    const _Float16* Wl = wsp + WLP;
    const float* ss = scsh + 960;

    f32x4 acc2[3][2];
#pragma unroll
    for (int m = 0; m < 3; ++m)
#pragma unroll
        for (int n = 0; n < 2; ++n) acc2[m][n] = (f32x4){0.f, 0.f, 0.f, 0.f};

#pragma unroll
    for (int kk = 0; kk < 3; ++kk) {
        h8 bf[2];
#pragma unroll
        for (int n = 0; n < 2; ++n)
            bf[n] = *(const h8*)&Ot[((wn * 2 + n) * 16 + l16) * OS + kk * 32 + lg * 8];
#pragma unroll
        for (int m = 0; m < 3; ++m) {
            const int row = (wm * 3 + m) * 16 + l16;
            const h8 wh = *(const h8*)&Wh[row * 96 + kk * 32 + lg * 8];
            const h8 wl = *(const h8*)&Wl[row * 96 + kk * 32 + lg * 8];
#pragma unroll
            for (int n = 0; n < 2; ++n) {
                acc2[m][n] = __builtin_amdgcn_mfma_f32_16x16x32_f16(wh, bf[n], acc2[m][n], 0, 0, 0);
                acc2[m][n] = __builtin_amdgcn_mfma_f32_16x16x32_f16(wl, bf[n], acc2[m][n], 0, 0, 0);
            }
        }
    }

#pragma unroll
    for (int m = 0; m < 3; ++m) {
#pragma unroll
        for (int r = 0; r < 4; ++r) {
            const int co = (wm * 3 + m) * 16 + lg * 4 + r;
            const f2 sp = *(const f2*)&ss[2 * co];
            _Float16* yr = tmp + (size_t)co * T_ + m0 + wn * 32 + l16;
#pragma unroll
            for (int n = 0; n < 2; ++n) {
                const float v = fmaf(acc2[m][n][r], sp[0], sp[1]);
                yr[n * 16] = (_Float16)(v >= 0.f ? v : a * v);
            }
        }
    }
}

// ---------------------------------------------------------------------------
extern "C" void kernel_launch(void* const* d_in, const int* in_sizes, int n_in,
                              void* d_out, int out_size, void* d_ws, size_t ws_size,
                              hipStream_t stream)
{
    const float* inp = (const float*)d_in[0];
    const float* W_f = (const float*)d_in[1];  const float* b_f = (const float*)d_in[2];
    const float* g_f = (const float*)d_in[3];  const float* be_f = (const float*)d_in[4];
    const float* m_f = (const float*)d_in[5];  const float* v_f = (const float*)d_in[6];
    const float* a_f = (const float*)d_in[7];
    const float* W_t = (const float*)d_in[8];  const float* b_t = (const float*)d_in[9];
    const float* g_t = (const float*)d_in[10]; const float* be_t = (const float*)d_in[11];
    const float* m_t = (const float*)d_in[12]; const float* v_t = (const float*)d_in[13];
    const float* a_t = (const float*)d_in[14];
    const float* W_p = (const float*)d_in[15]; const float* b_p = (const float*)d_in[16];
    const float* g_p = (const float*)d_in[17]; const float* be_p = (const float*)d_in[18];
    const float* m_p = (const float*)d_in[19]; const float* v_p = (const float*)d_in[20];
    const float* a_p = (const float*)d_in[21];

    hipFuncSetAttribute((const void*)conv_ft,
                        hipFuncAttributeMaxDynamicSharedMemorySize, 51200);
    hipFuncSetAttribute((const void*)conv_p,
                        hipFuncAttributeMaxDynamicSharedMemorySize, 33280);
    hipFuncSetAttribute((const void*)attn_mfma<0>,
                        hipFuncAttributeMaxDynamicSharedMemorySize, 58880);
    hipFuncSetAttribute((const void*)attn_mfma<1>,
                        hipFuncAttributeMaxDynamicSharedMemorySize, 71680);
    hipFuncSetAttribute((const void*)attn1_fused,
                        hipFuncAttributeMaxDynamicSharedMemorySize, 71680);

    constexpr int QH = (int)QH_;
    const size_t tail  = (size_t)WTOT * 2 + 1152 * 4 + 4096;
    const size_t need4 = (size_t)12 * QH * 2 + tail;
    const size_t need16 = (size_t)16 * QH * 2 + tail;   // +4 tmp units (fused)
    const int G = (ws_size >= need4) ? 4 : 2;
    const bool FUSED = (G == 4) && (ws_size >= need16);

    _Float16* wsh  = (_Float16*)d_ws;
    _Float16* wsp  = wsh + (size_t)(3 * G + (FUSED ? 4 : 0)) * QH;
    float*    scsh = (float*)(wsp + WTOT);
    _Float16* tmpf = wsh + (size_t)3 * G * QH;    // fused tmp units (12..15)

    prep_kernel<<<dim3(128), dim3(256), 0, stream>>>(
        W_f, W_t, W_p, b_f, g_f, be_f, m_f, v_f,
        b_t, g_t, be_t, m_t, v_t, b_p, g_p, be_p, m_p, v_p, wsp, scsh);

    for (int p = 0; p < B_ / G; ++p) {
        const float* xb  = inp + (size_t)p * G * QH;
        float*       dob = (float*)d_out + (size_t)p * G * QH;
        _Float16*    doh = (_Float16*)dob;        // th2 (2 units/batch)

        // 1. fused conv_f + conv_t
        conv_ft<<<dim3(640, G), dim3(256), 51200, stream>>>(
            xb, wsp, scsh, a_f, a_t, wsh, doh, QH, 3 * QH, 2 * QH);
        // 2. f-attention, O in-place over Q third
        attn_mfma<0><<<dim3(T_ * (F_ / 64), G), dim3(256), 58880, stream>>>(
            wsh, wsh + QH_, wsh + 2 * QH_, wsh, 3 * QH, 3 * QH, 3 * QH, 3 * QH);
        // 3. trA: fout -> foutT (3b+1), th2 q -> tqT (3b+2)
        transpose_trA<<<dim3(480, 4, 2 * G), dim3(256), 0, stream>>>(doh, wsh);
        // 4. trB: th2 k -> tkT (3b+0)
        transpose_trB<<<dim3(480, 4, G), dim3(256), 0, stream>>>(doh, wsh);

        if (FUSED) {
            // 5. t-attention + conv_p fused -> tmpf units
            attn1_fused<<<dim3(F_ * (T_ / 64), G), dim3(256), 71680, stream>>>(
                wsh + 2 * QH_, wsh, wsh + QH_, tmpf, wsp, scsh, a_p,
                3 * QH, 3 * QH, 3 * QH, QH);
            // 6. out = transpose(tmpf) + inp
            transpose_hf_res<<<dim3(4, 480, G), dim3(256), 0, stream>>>(
                tmpf, xb, dob, QH, QH, QH);
        } else {
            // 5. t-attention, O in-place over tqT
            attn_mfma<1><<<dim3(F_ * (T_ / 64), G), dim3(256), 71680, stream>>>(
                wsh + 2 * QH_, wsh, wsh + QH_, wsh + 2 * QH_,
                3 * QH, 3 * QH, 3 * QH, 3 * QH);
            // 6. conv_p(tout = 3b+2) -> tmp (3b+0)
            conv_p<<<dim3(F_ * 2, G), dim3(256), 33280, stream>>>(
                wsh + 2 * QH_, wsp, scsh, a_p, wsh, 3 * QH, 3 * QH);
            // 7. out = transpose(tmp) + inp
            transpose_hf_res<<<dim3(4, 480, G), dim3(256), 0, stream>>>(
                wsh, xb, dob, 3 * QH, QH, QH);
        }
    }
}

// Round 20
// 671.034 us; speedup vs baseline: 1.1720x; 1.0623x over previous
//
#include <hip/hip_runtime.h>
#include <math.h>

typedef float f4 __attribute__((ext_vector_type(4)));
typedef float f2 __attribute__((ext_vector_type(2)));
typedef float f32x4 __attribute__((ext_vector_type(4)));
typedef _Float16 h8 __attribute__((ext_vector_type(8)));

constexpr int B_ = 4, C_ = 96, T_ = 320, F_ = 256;
constexpr int TF_ = T_ * F_;          // 81920
constexpr float EPS_ = 1e-5f;
constexpr size_t QH_ = (size_t)C_ * TF_;   // 7,864,320 elems per (C,T,F) unit

// W-split scratch layout (f16 elems, appended after the data units):
constexpr int WHF = 0, WLF = 27648, WHT = 55296, WLT = 73728,
              WHP = 92160, WLP = 101376, WTOT = 110592;

// ---------------------------------------------------------------------------
// One-time prep: split W into hi/lo f16; precompute BN (sc, sh) per channel.
// ---------------------------------------------------------------------------
__global__ __launch_bounds__(256)
void prep_kernel(const float* __restrict__ Wf, const float* __restrict__ Wt,
                 const float* __restrict__ Wp,
                 const float* __restrict__ bf, const float* __restrict__ gf,
                 const float* __restrict__ bef, const float* __restrict__ mf,
                 const float* __restrict__ vf,
                 const float* __restrict__ bt, const float* __restrict__ gt,
                 const float* __restrict__ bet, const float* __restrict__ mt,
                 const float* __restrict__ vt,
                 const float* __restrict__ bp, const float* __restrict__ gp,
                 const float* __restrict__ bep, const float* __restrict__ mp,
                 const float* __restrict__ vp,
                 _Float16* __restrict__ wsp, float* __restrict__ scsh)
{
    const int gtid = blockIdx.x * 256 + threadIdx.x;
    const int gsz  = gridDim.x * 256;
    for (int i = gtid; i < 27648; i += gsz) {
        const float w = Wf[i]; const _Float16 h = (_Float16)w;
        wsp[WHF + i] = h; wsp[WLF + i] = (_Float16)(w - (float)h);
    }
    for (int i = gtid; i < 18432; i += gsz) {
        const float w = Wt[i]; const _Float16 h = (_Float16)w;
        wsp[WHT + i] = h; wsp[WLT + i] = (_Float16)(w - (float)h);
    }
    for (int i = gtid; i < 9216; i += gsz) {
        const float w = Wp[i]; const _Float16 h = (_Float16)w;
        wsp[WHP + i] = h; wsp[WLP + i] = (_Float16)(w - (float)h);
    }
    if (gtid < 288) {
        const float sc = gf[gtid] * rsqrtf(vf[gtid] + EPS_);
        scsh[2 * gtid] = sc;
        scsh[2 * gtid + 1] = fmaf(bf[gtid] - mf[gtid], sc, bef[gtid]);
    } else if (gtid < 480) {
        const int i = gtid - 288;
        const float sc = gt[i] * rsqrtf(vt[i] + EPS_);
        scsh[576 + 2 * i] = sc;
        scsh[576 + 2 * i + 1] = fmaf(bt[i] - mt[i], sc, bet[i]);
    } else if (gtid < 576) {
        const int i = gtid - 480;
        const float sc = gp[i] * rsqrtf(vp[i] + EPS_);
        scsh[960 + 2 * i] = sc;
        scsh[960 + 2 * i + 1] = fmaf(bp[i] - mp[i], sc, bep[i]);
    }
}

// ---------------------------------------------------------------------------
// Fused conv_f + conv_t, 2 p-tiles/block with T14 issue-early/write-late.
// Proven at 224us / 84 VGPR / no spill.  FROZEN.
// ---------------------------------------------------------------------------
__global__ __launch_bounds__(256, 3)
void conv_ft(const float* __restrict__ x, const _Float16* __restrict__ wsp,
             const float* __restrict__ scsh,
             const float* __restrict__ aPf, const float* __restrict__ aPt,
             _Float16* __restrict__ yf, _Float16* __restrict__ yt,
             int bsx, int bsyf, int bsyt)
{
    constexpr int LS = 200;
    extern __shared__ _Float16 ldsh[];
    _Float16* Xs0 = ldsh;                  // [64][200]: 0-95 hi, 96-191 lo
    _Float16* Xs1 = ldsh + 64 * LS;

    x  += (size_t)blockIdx.y * bsx;
    yf += (size_t)blockIdx.y * bsyf;
    yt += (size_t)blockIdx.y * bsyt;

    const int tid = threadIdx.x;
    const int p0A = blockIdx.x * 128;
    const int p0B = p0A + 64;

    {
        const float* xg = x + p0A;
        for (int e = tid; e < 64 * 12; e += 256) {
            const int p = e & 63, k0 = (e >> 6) * 8;
            const float* xp = xg + (size_t)k0 * TF_ + p;
            h8 hv, lv;
#pragma unroll
            for (int j = 0; j < 8; ++j) {
                const float xv = xp[(size_t)j * TF_];
                const _Float16 xh = (_Float16)xv;
                hv[j] = xh;
                lv[j] = (_Float16)(xv - (float)xh);
            }
            *(h8*)&Xs0[p * LS + k0]      = hv;
            *(h8*)&Xs0[p * LS + 96 + k0] = lv;
        }
    }

    const int lane = tid & 63, wid = tid >> 6;
    const int l16 = lane & 15, lg = lane >> 4;
    const int wm = wid >> 1, wn = wid & 1;       // 2x2 wave grid
    const float af_ = aPf[0], at_ = aPt[0];
    __syncthreads();

    float xpre[3][8];
#pragma unroll
    for (int it = 0; it < 3; ++it) {
        const int e = tid + it * 256;
        const int p = e & 63, k0 = (e >> 6) * 8;
        const float* xp = x + p0B + (size_t)k0 * TF_ + p;
#pragma unroll
        for (int j = 0; j < 8; ++j) xpre[it][j] = xp[(size_t)j * TF_];
    }

    auto compute5 = [&](const _Float16* Xs, int p0) {
#pragma unroll 1
        for (int cg = 0; cg < 5; ++cg) {
            const _Float16 *Wh, *Wl; const float* ss; float a; _Float16* yo;
            if (cg < 3) {
                Wh = wsp + WHF + cg * 9216;  Wl = wsp + WLF + cg * 9216;
                ss = scsh + cg * 192;        a = af_;
                yo = yf + (size_t)cg * QH_;
            } else {
                const int c2 = cg - 3;
                Wh = wsp + WHT + c2 * 9216;  Wl = wsp + WLT + c2 * 9216;
                ss = scsh + 576 + c2 * 192;  a = at_;
                yo = yt + (size_t)c2 * QH_;
            }

            f32x4 acc[3][2];
#pragma unroll
            for (int m = 0; m < 3; ++m)
#pragma unroll
                for (int n = 0; n < 2; ++n) acc[m][n] = (f32x4){0.f, 0.f, 0.f, 0.f};

#pragma unroll
            for (int kk = 0; kk < 3; ++kk) {
                h8 bfh[2], bfl[2];
#pragma unroll
                for (int n = 0; n < 2; ++n) {
                    const int prow = (wn * 2 + n) * 16 + l16;
                    bfh[n] = *(const h8*)&Xs[prow * LS + kk * 32 + lg * 8];
                    bfl[n] = *(const h8*)&Xs[prow * LS + 96 + kk * 32 + lg * 8];
                }
#pragma unroll
                for (int m = 0; m < 3; ++m) {
                    const int row = (wm * 3 + m) * 16 + l16;
                    const h8 wh = *(const h8*)&Wh[row * 96 + kk * 32 + lg * 8];
                    const h8 wl = *(const h8*)&Wl[row * 96 + kk * 32 + lg * 8];
#pragma unroll
                    for (int n = 0; n < 2; ++n) {
                        acc[m][n] = __builtin_amdgcn_mfma_f32_16x16x32_f16(wh, bfh[n], acc[m][n], 0, 0, 0);
                        acc[m][n] = __builtin_amdgcn_mfma_f32_16x16x32_f16(wl, bfh[n], acc[m][n], 0, 0, 0);
                        acc[m][n] = __builtin_amdgcn_mfma_f32_16x16x32_f16(wh, bfl[n], acc[m][n], 0, 0, 0);
                    }
                }
            }

#pragma unroll
            for (int m = 0; m < 3; ++m) {
#pragma unroll
                for (int r = 0; r < 4; ++r) {
                    const int col = (wm * 3 + m) * 16 + lg * 4 + r;
                    const f2 sp = *(const f2*)&ss[2 * col];
                    _Float16* yr = yo + (size_t)col * TF_ + p0 + wn * 32 + l16;
#pragma unroll
                    for (int n = 0; n < 2; ++n) {
                        const float v = fmaf(acc[m][n][r], sp[0], sp[1]);
                        yr[n * 16] = (_Float16)(v >= 0.f ? v : a * v);
                    }
                }
            }
        }
    };

    compute5(Xs0, p0A);

#pragma unroll
    for (int it = 0; it < 3; ++it) {
        const int e = tid + it * 256;
        const int p = e & 63, k0 = (e >> 6) * 8;
        h8 hv, lv;
#pragma unroll
        for (int j = 0; j < 8; ++j) {
            const _Float16 xh = (_Float16)xpre[it][j];
            hv[j] = xh;
            lv[j] = (_Float16)(xpre[it][j] - (float)xh);
        }
        *(h8*)&Xs1[p * LS + k0]      = hv;
        *(h8*)&Xs1[p * LS + 96 + k0] = lv;
    }
    __syncthreads();

    compute5(Xs1, p0B);
}

// ---------------------------------------------------------------------------
// conv_p (fallback path only): f16 input (F groups, C, T), pre-split W.
// ---------------------------------------------------------------------------
__global__ __launch_bounds__(256, 3)
void conv_p(const _Float16* __restrict__ x, const _Float16* __restrict__ wsp,
            const float* __restrict__ scsh, const float* __restrict__ aPp,
            _Float16* __restrict__ y, int bsx, int bsy)
{
    constexpr int LS = 104, PT = 160, NN = 5;
    extern __shared__ _Float16 ldsh[];
    _Float16* Xs = ldsh;                   // [160][104]

    x += (size_t)blockIdx.y * bsx;
    y += (size_t)blockIdx.y * bsy;

    const int tid = threadIdx.x;
    const int pt  = blockIdx.x & 1;
    const int g   = blockIdx.x >> 1;
    const int p0  = pt * PT;

    const _Float16* xg = x + (size_t)g * 96 * T_ + p0;
    for (int e = tid; e < PT * 12; e += 256) {
        const int p = e % PT, k0 = (e / PT) * 8;
        const _Float16* xp = xg + (size_t)k0 * T_ + p;
        h8 hv;
#pragma unroll
        for (int j = 0; j < 8; ++j) hv[j] = xp[(size_t)j * T_];
        *(h8*)&Xs[p * LS + k0] = hv;
    }

    const int lane = tid & 63, wid = tid >> 6;
    const int l16 = lane & 15, lg = lane >> 4;
    const int wm = wid >> 1, wn = wid & 1;
    const float a = aPp[0];
    const _Float16* Wh = wsp + WHP;
    const _Float16* Wl = wsp + WLP;
    const float* ss = scsh + 960;
    __syncthreads();

    f32x4 acc[3][NN];
#pragma unroll
    for (int m = 0; m < 3; ++m)
#pragma unroll
        for (int n = 0; n < NN; ++n) acc[m][n] = (f32x4){0.f, 0.f, 0.f, 0.f};

#pragma unroll
    for (int kk = 0; kk < 3; ++kk) {
        h8 bf[NN];
#pragma unroll
        for (int n = 0; n < NN; ++n)
            bf[n] = *(const h8*)&Xs[((wn * NN + n) * 16 + l16) * LS + kk * 32 + lg * 8];
#pragma unroll
        for (int m = 0; m < 3; ++m) {
            const int row = (wm * 3 + m) * 16 + l16;
            const h8 wh = *(const h8*)&Wh[row * 96 + kk * 32 + lg * 8];
            const h8 wl = *(const h8*)&Wl[row * 96 + kk * 32 + lg * 8];
#pragma unroll
            for (int n = 0; n < NN; ++n) {
                acc[m][n] = __builtin_amdgcn_mfma_f32_16x16x32_f16(wh, bf[n], acc[m][n], 0, 0, 0);
                acc[m][n] = __builtin_amdgcn_mfma_f32_16x16x32_f16(wl, bf[n], acc[m][n], 0, 0, 0);
            }
        }
    }

#pragma unroll
    for (int m = 0; m < 3; ++m) {
#pragma unroll
        for (int r = 0; r < 4; ++r) {
            const int col = (wm * 3 + m) * 16 + lg * 4 + r;
            const f2 sp = *(const f2*)&ss[2 * col];
            _Float16* yr = y + ((size_t)g * 96 + col) * T_ + p0 + wn * NN * 16 + l16;
#pragma unroll
            for (int n = 0; n < NN; ++n) {
                const float v = fmaf(acc[m][n][r], sp[0], sp[1]);
                yr[n * 16] = (_Float16)(v >= 0.f ? v : a * v);
            }
        }
    }
}

// ---------------------------------------------------------------------------
// 64x64 f16 transpose core: h8 global I/O, XOR-swizzled LDS tile [64][72].
// ---------------------------------------------------------------------------
__device__ __forceinline__ void tr64_body(const _Float16* __restrict__ in,
                                          _Float16* __restrict__ out,
                                          int Mo, int No, int n0, int m0,
                                          _Float16* tile)
{
    const int t = threadIdx.x, ty = t >> 3, tx8 = t & 7;
#pragma unroll
    for (int r = 0; r < 2; ++r) {
        const int n = ty + r * 32;
        const h8 v = *(const h8*)&in[(size_t)(n0 + n) * Mo + m0 + tx8 * 8];
        const int c = tx8 ^ (n >> 3);
        *(h8*)&tile[n * 72 + c * 8] = v;
    }
    __syncthreads();
#pragma unroll
    for (int r = 0; r < 2; ++r) {
        const int mt = ty + r * 32;
        h8 v;
#pragma unroll
        for (int j = 0; j < 8; ++j) {
            const int n = tx8 * 8 + j;
            const int c = (mt >> 3) ^ tx8;           // n>>3 == tx8
            v[j] = tile[n * 72 + c * 8 + (mt & 7)];
        }
        *(h8*)&out[(size_t)(m0 + mt) * No + n0 + tx8 * 8] = v;
    }
}

// trA: per batch 2 slabs (z = b*2+t): t=0 fout->foutT, t=1 th2 q->tqT.
__global__ __launch_bounds__(256)
void transpose_trA(const _Float16* __restrict__ doh, _Float16* __restrict__ wsh)
{
    __shared__ _Float16 tile[64 * 72];
    const int b = blockIdx.z >> 1, t = blockIdx.z & 1;
    const _Float16* in  = t ? doh + (size_t)b * 2 * QH_
                            : wsh + (size_t)b * 3 * QH_;
    _Float16*       out = t ? wsh + (size_t)b * 3 * QH_ + 2 * QH_
                            : wsh + (size_t)b * 3 * QH_ + QH_;
    tr64_body(in, out, F_, C_ * T_, blockIdx.x * 64, blockIdx.y * 64, tile);
}

// trB: th2 k-half -> tkT (unit 3b+0; fout dead after trA).
__global__ __launch_bounds__(256)
void transpose_trB(const _Float16* __restrict__ doh, _Float16* __restrict__ wsh)
{
    __shared__ _Float16 tile[64 * 72];
    const int b = blockIdx.z;
    tr64_body(doh + (size_t)b * 2 * QH_ + QH_, wsh + (size_t)b * 3 * QH_,
              F_, C_ * T_, blockIdx.x * 64, blockIdx.y * 64, tile);
}

// hf_res: tmp (F_, C*T) f16 + res f32 -> out (C*T, F_) f32.
__global__ __launch_bounds__(256)
void transpose_hf_res(const _Float16* __restrict__ in, const float* __restrict__ res,
                      float* __restrict__ out, int si, int sr, int so)
{
    __shared__ _Float16 tile[64 * 72];
    in  += (size_t)blockIdx.z * si;
    res += (size_t)blockIdx.z * sr;
    out += (size_t)blockIdx.z * so;
    const int n0 = blockIdx.x * 64, m0 = blockIdx.y * 64;
    const int t = threadIdx.x, ty = t >> 3, tx8 = t & 7;
#pragma unroll
    for (int r = 0; r < 2; ++r) {
        const int n = ty + r * 32;
        const h8 v = *(const h8*)&in[(size_t)(n0 + n) * (C_ * T_) + m0 + tx8 * 8];
        const int c = tx8 ^ (n >> 3);
        *(h8*)&tile[n * 72 + c * 8] = v;
    }
    __syncthreads();
#pragma unroll
    for (int r = 0; r < 2; ++r) {
        const int mt = ty + r * 32;
        const size_t obase = (size_t)(m0 + mt) * F_ + n0 + tx8 * 8;
        const f4 r0 = *(const f4*)&res[obase];
        const f4 r1 = *(const f4*)&res[obase + 4];
        f4 o0, o1;
#pragma unroll
        for (int j = 0; j < 8; ++j) {
            const int n = tx8 * 8 + j;
            const int c = (mt >> 3) ^ tx8;
            const float v = (float)tile[n * 72 + c * 8 + (mt & 7)];
            if (j < 4) o0[j] = v + r0[j]; else o1[j - 4] = v + r1[j - 4];
        }
        *(f4*)&out[obase]     = o0;
        *(f4*)&out[obase + 4] = o1;
    }
}

// ---------------------------------------------------------------------------
// MFMA f16 fused attention.  O may alias Q (in-place).
// MODE 0 LDS DIET (3 blocks/CU): V [96][256] XOR-swizzled (chunk ^= c&31,
// same XOR on read: bijective, element j still maps to y=yk*32+lg*8+j);
// Pw relocated into the dead-K gap [24576,26624), stride 32.  Total 53,248 B
// <= 54,613 (160KB/3).  MODE 1 unchanged (66+KB cannot fit 3).
// ---------------------------------------------------------------------------
template<int MODE>
__global__ __launch_bounds__(256, 2)
void attn_mfma(const _Float16* __restrict__ Qb, const _Float16* __restrict__ Kb,
               const _Float16* __restrict__ Vb, _Float16* __restrict__ Ob,
               int qs, int ks, int vs, int os)
{
    constexpr int NY  = (MODE == 0) ? 256 : 320;
    constexpr int LD  = (MODE == 0) ? TF_ : T_;
    constexpr int NT  = NY / 16;
    constexpr int NYK = NY / 32;
    constexpr int KS  = 104;
    constexpr int VPS = (MODE == 0) ? 256 : 344;
    constexpr int KVH = (NY * KS > 96 * VPS) ? NY * KS : 96 * VPS;
    constexpr int PMS = (MODE == 0) ? 32 : 40;     // Pme stride
    constexpr int PWO = (MODE == 0) ? 24576 : KVH; // Pw offset
    constexpr int NG  = (MODE == 0) ? T_ : F_;
    constexpr int GOFF = (MODE == 0) ? F_ : C_ * T_;

    extern __shared__ _Float16 ldsh[];
    _Float16* KV = ldsh;                 // Kt[NY][KS] -> V[96][VPS]
    _Float16* Pw = ldsh + PWO;           // [4][16][PMS]

    const int lb    = blockIdx.y;
    const int strip = blockIdx.x / NG;
    const int grp   = blockIdx.x % NG;
    const int m0    = strip * 64;
    const size_t off = (size_t)grp * GOFF;
    const _Float16* Q = Qb + (size_t)lb * qs + off;
    const _Float16* K = Kb + (size_t)lb * ks + off;
    const _Float16* V = Vb + (size_t)lb * vs + off;
    _Float16*       O = Ob + (size_t)lb * os + off;

    const int tid  = threadIdx.x;
    const int lane = tid & 63, wid = tid >> 6;
    const int l16  = lane & 15, lg = lane >> 4;
    const int mw   = wid * 16;
    const float scale = 0.10206207261596575f;   // 1/sqrt(96)

    for (int e = tid; e < NY * 12; e += 256) {
        const int yy = e % NY, k0 = (e / NY) * 8;
        const _Float16* kp = K + (size_t)k0 * LD + yy;
        h8 hv;
#pragma unroll
        for (int j = 0; j < 8; ++j) hv[j] = kp[(size_t)j * LD];
        *(h8*)&KV[yy * KS + k0] = hv;
    }

    h8 aQ[3];
#pragma unroll
    for (int kk = 0; kk < 3; ++kk) {
        const _Float16* qp = Q + (size_t)(kk * 32 + lg * 8) * LD + m0 + mw + l16;
#pragma unroll
        for (int j = 0; j < 8; ++j) aQ[kk][j] = qp[(size_t)j * LD];
    }
    __syncthreads();

    f32x4 sacc[NT];
#pragma unroll
    for (int t = 0; t < NT; ++t) sacc[t] = (f32x4){0.f, 0.f, 0.f, 0.f};
#pragma unroll
    for (int kk = 0; kk < 3; ++kk) {
#pragma unroll
        for (int t = 0; t < NT; ++t) {
            const h8 bK = *(const h8*)&KV[(t * 16 + l16) * KS + kk * 32 + lg * 8];
            sacc[t] = __builtin_amdgcn_mfma_f32_16x16x32_f16(aQ[kk], bK, sacc[t], 0, 0, 0);
        }
    }

#pragma unroll
    for (int r = 0; r < 4; ++r) {
        float mx = sacc[0][r];
#pragma unroll
        for (int t = 1; t < NT; ++t) mx = fmaxf(mx, sacc[t][r]);
        for (int d = 1; d < 16; d <<= 1) mx = fmaxf(mx, __shfl_xor(mx, d));
        float pv[NT];
        float sum = 0.f;
#pragma unroll
        for (int t = 0; t < NT; ++t) {
            pv[t] = __expf((sacc[t][r] - mx) * scale); sum += pv[t];
        }
        for (int d = 1; d < 16; d <<= 1) sum += __shfl_xor(sum, d);
        const float inv = 1.f / sum;
#pragma unroll
        for (int t = 0; t < NT; ++t) sacc[t][r] = pv[t] * inv;
    }
    __syncthreads();     // all K reads done; K region reusable (V + Pw)

    constexpr int NY8 = NY / 8;
    for (int e = tid; e < 96 * NY8; e += 256) {
        const int c = e / NY8, y8 = e - c * NY8;
        const int yc = (MODE == 0) ? (y8 ^ (c & 31)) : y8;   // V chunk swizzle
        *(h8*)&KV[c * VPS + yc * 8] = *(const h8*)(V + (size_t)c * LD + y8 * 8);
    }
    __syncthreads();

    _Float16* Pme = Pw + wid * (16 * PMS);
    f32x4 oacc[6];
#pragma unroll
    for (int ct = 0; ct < 6; ++ct) oacc[ct] = (f32x4){0.f, 0.f, 0.f, 0.f};

#pragma unroll
    for (int yk = 0; yk < NYK; ++yk) {
#pragma unroll
        for (int h = 0; h < 2; ++h)
#pragma unroll
            for (int r = 0; r < 4; ++r)
                Pme[(lg * 4 + r) * PMS + h * 16 + l16] = (_Float16)sacc[2 * yk + h][r];
        const h8 pf = *(const h8*)&Pme[l16 * PMS + lg * 8];   // in-wave DS order
#pragma unroll
        for (int ct = 0; ct < 6; ++ct) {
            const int c = ct * 16 + l16;
            const int ch = (MODE == 0) ? ((yk * 4 + lg) ^ (c & 31)) : (yk * 4 + lg);
            const h8 av = *(const h8*)&KV[c * VPS + ch * 8];
            oacc[ct] = __builtin_amdgcn_mfma_f32_16x16x32_f16(av, pf, oacc[ct], 0, 0, 0);
        }
    }
#pragma unroll
    for (int ct = 0; ct < 6; ++ct)
#pragma unroll
        for (int r = 0; r < 4; ++r)
            O[(size_t)(ct * 16 + lg * 4 + r) * LD + m0 + mw + l16] = (_Float16)oacc[ct][r];
}

// ---------------------------------------------------------------------------
// attn1_fused: t-attention (mode 1) + conv_p fused in-block (round-19 form).
// ---------------------------------------------------------------------------
__global__ __launch_bounds__(256, 2)
void attn1_fused(const _Float16* __restrict__ Qb, const _Float16* __restrict__ Kb,
                 const _Float16* __restrict__ Vb, _Float16* __restrict__ tmpb,
                 const _Float16* __restrict__ wsp, const float* __restrict__ scsh,
                 const float* __restrict__ aPp,
                 int qs, int ks, int vs, int ts)
{
    constexpr int NY = 320, LD = T_, NT = 20, NYK = 10;
    constexpr int KS = 104, VPS = 344;
    constexpr int KVH = NY * KS;
    constexpr int OS  = 104;

    extern __shared__ _Float16 ldsh[];
    _Float16* KV = ldsh;
    _Float16* Pw = ldsh + KVH;
    _Float16* Ot = ldsh;

    const int lb    = blockIdx.y;
    const int strip = blockIdx.x / F_;
    const int grp   = blockIdx.x % F_;
    const int m0    = strip * 64;
    const size_t off = (size_t)grp * (C_ * T_);
    const _Float16* Q = Qb + (size_t)lb * qs + off;
    const _Float16* K = Kb + (size_t)lb * ks + off;
    const _Float16* V = Vb + (size_t)lb * vs + off;
    _Float16*     tmp = tmpb + (size_t)lb * ts + (size_t)grp * (96 * T_);

    const int tid  = threadIdx.x;
    const int lane = tid & 63, wid = tid >> 6;
    const int l16  = lane & 15, lg = lane >> 4;
    const int mw   = wid * 16;
    const float scale = 0.10206207261596575f;

    for (int e = tid; e < NY * 12; e += 256) {
        const int yy = e % NY, k0 = (e / NY) * 8;
        const _Float16* kp = K + (size_t)k0 * LD + yy;
        h8 hv;
#pragma unroll
        for (int j = 0; j < 8; ++j) hv[j] = kp[(size_t)j * LD];
        *(h8*)&KV[yy * KS + k0] = hv;
    }

    h8 aQ[3];
#pragma unroll
    for (int kk = 0; kk < 3; ++kk) {
        const _Float16* qp = Q + (size_t)(kk * 32 + lg * 8) * LD + m0 + mw + l16;
#pragma unroll
        for (int j = 0; j < 8; ++j) aQ[kk][j] = qp[(size_t)j * LD];
    }
    __syncthreads();

    f32x4 sacc[NT];
#pragma unroll
    for (int t = 0; t < NT; ++t) sacc[t] = (f32x4){0.f, 0.f, 0.f, 0.f};
#pragma unroll
    for (int kk = 0; kk < 3; ++kk) {
#pragma unroll
        for (int t = 0; t < NT; ++t) {
            const h8 bK = *(const h8*)&KV[(t * 16 + l16) * KS + kk * 32 + lg * 8];
            sacc[t] = __builtin_amdgcn_mfma_f32_16x16x32_f16(aQ[kk], bK, sacc[t], 0, 0, 0);
        }
    }

#pragma unroll
    for (int r = 0; r < 4; ++r) {
        float mx = sacc[0][r];
#pragma unroll
        for (int t = 1; t < NT; ++t) mx = fmaxf(mx, sacc[t][r]);
        for (int d = 1; d < 16; d <<= 1) mx = fmaxf(mx, __shfl_xor(mx, d));
        float pv[NT];
        float sum = 0.f;
#pragma unroll
        for (int t = 0; t < NT; ++t) {
            pv[t] = __expf((sacc[t][r] - mx) * scale); sum += pv[t];
        }
        for (int d = 1; d < 16; d <<= 1) sum += __shfl_xor(sum, d);
        const float inv = 1.f / sum;
#pragma unroll
        for (int t = 0; t < NT; ++t) sacc[t][r] = pv[t] * inv;
    }
    __syncthreads();

    for (int e = tid; e < 96 * 40; e += 256) {
        const int c = e / 40, y8 = e - c * 40;
        *(h8*)&KV[c * VPS + y8 * 8] = *(const h8*)(V + (size_t)c * LD + y8 * 8);
    }
    __syncthreads();

    _Float16* Pme = Pw + wid * 640;
    f32x4 oacc[6];
#pragma unroll
    for (int ct = 0; ct < 6; ++ct) oacc[ct] = (f32x4){0.f, 0.f, 0.f, 0.f};

#pragma unroll
    for (int yk = 0; yk < NYK; ++yk) {
#pragma unroll
        for (int h = 0; h < 2; ++h)
#pragma unroll
            for (int r = 0; r < 4; ++r)
                Pme[(lg * 4 + r) * 40 + h * 16 + l16] = (_Float16)sacc[2 * yk + h][r];
        const h8 pf = *(const h8*)&Pme[l16 * 40 + lg * 8];
#pragma unroll
        for (int ct = 0; ct < 6; ++ct) {
            const h8 av = *(const h8*)&KV[(ct * 16 + l16) * VPS + yk * 32 + lg * 8];
            oacc[ct] = __builtin_amdgcn_mfma_f32_16x16x32_f16(av, pf, oacc[ct], 0, 0, 0);
        }
    }

    __syncthreads();
#pragma unroll
    for (int ct = 0; ct < 6; ++ct)
#pragma unroll
        for (int r = 0; r < 4; ++r)
            Ot[(mw + l16) * OS + ct * 16 + lg * 4 + r] = (_Float16)oacc[ct][r];
    __syncthreads();

    const int wm = wid >> 1, wn = wid & 1;
    const float a = aPp[0];
    const _Float16* Wh = wsp + WHP;
    const _Float16* Wl = wsp + WLP;
    const float* ss = scsh + 960;

    f32x4 acc2[3][2];
#pragma unroll
    for (int m = 0; m < 3; ++m)
#pragma unroll
        for (int n = 0; n < 2; ++n) acc2[m][n] = (f32x4){0.f, 0.f, 0.f, 0.f};

#pragma unroll
    for (int kk = 0; kk < 3; ++kk) {
        h8 bf[2];
#pragma unroll
        for (int n = 0; n < 2; ++n)
            bf[n] = *(const h8*)&Ot[((wn * 2 + n) * 16 + l16) * OS + kk * 32 + lg * 8];
#pragma unroll
        for (int m = 0; m < 3; ++m) {
            const int row = (wm * 3 + m) * 16 + l16;
            const h8 wh = *(const h8*)&Wh[row * 96 + kk * 32 + lg * 8];
            const h8 wl = *(const h8*)&Wl[row * 96 + kk * 32 + lg * 8];
#pragma unroll
            for (int n = 0; n < 2; ++n) {
                acc2[m][n] = __builtin_amdgcn_mfma_f32_16x16x32_f16(wh, bf[n], acc2[m][n], 0, 0, 0);
                acc2[m][n] = __builtin_amdgcn_mfma_f32_16x16x32_f16(wl, bf[n], acc2[m][n], 0, 0, 0);
            }
        }
    }

#pragma unroll
    for (int m = 0; m < 3; ++m) {
#pragma unroll
        for (int r = 0; r < 4; ++r) {
            const int co = (wm * 3 + m) * 16 + lg * 4 + r;
            const f2 sp = *(const f2*)&ss[2 * co];
            _Float16* yr = tmp + (size_t)co * T_ + m0 + wn * 32 + l16;
#pragma unroll
            for (int n = 0; n < 2; ++n) {
                const float v = fmaf(acc2[m][n][r], sp[0], sp[1]);
                yr[n * 16] = (_Float16)(v >= 0.f ? v : a * v);
            }
        }
    }
}

// ---------------------------------------------------------------------------
extern "C" void kernel_launch(void* const* d_in, const int* in_sizes, int n_in,
                              void* d_out, int out_size, void* d_ws, size_t ws_size,
                              hipStream_t stream)
{
    const float* inp = (const float*)d_in[0];
    const float* W_f = (const float*)d_in[1];  const float* b_f = (const float*)d_in[2];
    const float* g_f = (const float*)d_in[3];  const float* be_f = (const float*)d_in[4];
    const float* m_f = (const float*)d_in[5];  const float* v_f = (const float*)d_in[6];
    const float* a_f = (const float*)d_in[7];
    const float* W_t = (const float*)d_in[8];  const float* b_t = (const float*)d_in[9];
    const float* g_t = (const float*)d_in[10]; const float* be_t = (const float*)d_in[11];
    const float* m_t = (const float*)d_in[12]; const float* v_t = (const float*)d_in[13];
    const float* a_t = (const float*)d_in[14];
    const float* W_p = (const float*)d_in[15]; const float* b_p = (const float*)d_in[16];
    const float* g_p = (const float*)d_in[17]; const float* be_p = (const float*)d_in[18];
    const float* m_p = (const float*)d_in[19]; const float* v_p = (const float*)d_in[20];
    const float* a_p = (const float*)d_in[21];

    hipFuncSetAttribute((const void*)conv_ft,
                        hipFuncAttributeMaxDynamicSharedMemorySize, 51200);
    hipFuncSetAttribute((const void*)conv_p,
                        hipFuncAttributeMaxDynamicSharedMemorySize, 33280);
    hipFuncSetAttribute((const void*)attn_mfma<0>,
                        hipFuncAttributeMaxDynamicSharedMemorySize, 53248);
    hipFuncSetAttribute((const void*)attn_mfma<1>,
                        hipFuncAttributeMaxDynamicSharedMemorySize, 71680);
    hipFuncSetAttribute((const void*)attn1_fused,
                        hipFuncAttributeMaxDynamicSharedMemorySize, 71680);

    constexpr int QH = (int)QH_;
    const size_t tail  = (size_t)WTOT * 2 + 1152 * 4 + 4096;
    const size_t need4 = (size_t)12 * QH * 2 + tail;
    const size_t need16 = (size_t)16 * QH * 2 + tail;   // +4 tmp units (fused)
    const int G = (ws_size >= need4) ? 4 : 2;
    const bool FUSED = (G == 4) && (ws_size >= need16);

    _Float16* wsh  = (_Float16*)d_ws;
    _Float16* wsp  = wsh + (size_t)(3 * G + (FUSED ? 4 : 0)) * QH;
    float*    scsh = (float*)(wsp + WTOT);
    _Float16* tmpf = wsh + (size_t)3 * G * QH;    // fused tmp units (12..15)

    prep_kernel<<<dim3(128), dim3(256), 0, stream>>>(
        W_f, W_t, W_p, b_f, g_f, be_f, m_f, v_f,
        b_t, g_t, be_t, m_t, v_t, b_p, g_p, be_p, m_p, v_p, wsp, scsh);

    for (int p = 0; p < B_ / G; ++p) {
        const float* xb  = inp + (size_t)p * G * QH;
        float*       dob = (float*)d_out + (size_t)p * G * QH;
        _Float16*    doh = (_Float16*)dob;        // th2 (2 units/batch)

        // 1. fused conv_f + conv_t
        conv_ft<<<dim3(640, G), dim3(256), 51200, stream>>>(
            xb, wsp, scsh, a_f, a_t, wsh, doh, QH, 3 * QH, 2 * QH);
        // 2. f-attention (3 blocks/CU diet), O in-place over Q third
        attn_mfma<0><<<dim3(T_ * (F_ / 64), G), dim3(256), 53248, stream>>>(
            wsh, wsh + QH_, wsh + 2 * QH_, wsh, 3 * QH, 3 * QH, 3 * QH, 3 * QH);
        // 3. trA: fout -> foutT (3b+1), th2 q -> tqT (3b+2)
        transpose_trA<<<dim3(480, 4, 2 * G), dim3(256), 0, stream>>>(doh, wsh);
        // 4. trB: th2 k -> tkT (3b+0)
        transpose_trB<<<dim3(480, 4, G), dim3(256), 0, stream>>>(doh, wsh);

        if (FUSED) {
            // 5. t-attention + conv_p fused -> tmpf units
            attn1_fused<<<dim3(F_ * (T_ / 64), G), dim3(256), 71680, stream>>>(
                wsh + 2 * QH_, wsh, wsh + QH_, tmpf, wsp, scsh, a_p,
                3 * QH, 3 * QH, 3 * QH, QH);
            // 6. out = transpose(tmpf) + inp
            transpose_hf_res<<<dim3(4, 480, G), dim3(256), 0, stream>>>(
                tmpf, xb, dob, QH, QH, QH);
        } else {
            // 5. t-attention, O in-place over tqT
            attn_mfma<1><<<dim3(F_ * (T_ / 64), G), dim3(256), 71680, stream>>>(
                wsh + 2 * QH_, wsh, wsh + QH_, wsh + 2 * QH_,
                3 * QH, 3 * QH, 3 * QH, 3 * QH);
            // 6. conv_p(tout = 3b+2) -> tmp (3b+0)
            conv_p<<<dim3(F_ * 2, G), dim3(256), 33280, stream>>>(
                wsh + 2 * QH_, wsp, scsh, a_p, wsh, 3 * QH, 3 * QH);
            // 7. out = transpose(tmp) + inp
            transpose_hf_res<<<dim3(4, 480, G), dim3(256), 0, stream>>>(
                wsh, xb, dob, 3 * QH, QH, QH);
        }
    }
}

// Round 21
// 658.981 us; speedup vs baseline: 1.1935x; 1.0183x over previous
//
#include <hip/hip_runtime.h>
#include <math.h>

typedef float f4 __attribute__((ext_vector_type(4)));
typedef float f2 __attribute__((ext_vector_type(2)));
typedef float f32x4 __attribute__((ext_vector_type(4)));
typedef _Float16 h8 __attribute__((ext_vector_type(8)));

constexpr int B_ = 4, C_ = 96, T_ = 320, F_ = 256;
constexpr int TF_ = T_ * F_;          // 81920
constexpr float EPS_ = 1e-5f;
constexpr size_t QH_ = (size_t)C_ * TF_;   // 7,864,320 elems per (C,T,F) unit

// W-split scratch layout (f16 elems, appended after the data units):
constexpr int WHF = 0, WLF = 27648, WHT = 55296, WLT = 73728,
              WHP = 92160, WLP = 101376, WTOT = 110592;

// ---------------------------------------------------------------------------
// One-time prep: split W into hi/lo f16; precompute BN (sc, sh) per channel.
// ---------------------------------------------------------------------------
__global__ __launch_bounds__(256)
void prep_kernel(const float* __restrict__ Wf, const float* __restrict__ Wt,
                 const float* __restrict__ Wp,
                 const float* __restrict__ bf, const float* __restrict__ gf,
                 const float* __restrict__ bef, const float* __restrict__ mf,
                 const float* __restrict__ vf,
                 const float* __restrict__ bt, const float* __restrict__ gt,
                 const float* __restrict__ bet, const float* __restrict__ mt,
                 const float* __restrict__ vt,
                 const float* __restrict__ bp, const float* __restrict__ gp,
                 const float* __restrict__ bep, const float* __restrict__ mp,
                 const float* __restrict__ vp,
                 _Float16* __restrict__ wsp, float* __restrict__ scsh)
{
    const int gtid = blockIdx.x * 256 + threadIdx.x;
    const int gsz  = gridDim.x * 256;
    for (int i = gtid; i < 27648; i += gsz) {
        const float w = Wf[i]; const _Float16 h = (_Float16)w;
        wsp[WHF + i] = h; wsp[WLF + i] = (_Float16)(w - (float)h);
    }
    for (int i = gtid; i < 18432; i += gsz) {
        const float w = Wt[i]; const _Float16 h = (_Float16)w;
        wsp[WHT + i] = h; wsp[WLT + i] = (_Float16)(w - (float)h);
    }
    for (int i = gtid; i < 9216; i += gsz) {
        const float w = Wp[i]; const _Float16 h = (_Float16)w;
        wsp[WHP + i] = h; wsp[WLP + i] = (_Float16)(w - (float)h);
    }
    if (gtid < 288) {
        const float sc = gf[gtid] * rsqrtf(vf[gtid] + EPS_);
        scsh[2 * gtid] = sc;
        scsh[2 * gtid + 1] = fmaf(bf[gtid] - mf[gtid], sc, bef[gtid]);
    } else if (gtid < 480) {
        const int i = gtid - 288;
        const float sc = gt[i] * rsqrtf(vt[i] + EPS_);
        scsh[576 + 2 * i] = sc;
        scsh[576 + 2 * i + 1] = fmaf(bt[i] - mt[i], sc, bet[i]);
    } else if (gtid < 576) {
        const int i = gtid - 480;
        const float sc = gp[i] * rsqrtf(vp[i] + EPS_);
        scsh[960 + 2 * i] = sc;
        scsh[960 + 2 * i + 1] = fmaf(bp[i] - mp[i], sc, bep[i]);
    }
}

// ---------------------------------------------------------------------------
// Fused conv_f + conv_t, 2 p-tiles/block with T14 issue-early/write-late.
// Proven at 224us / 84 VGPR / no spill.  FROZEN.
// ---------------------------------------------------------------------------
__global__ __launch_bounds__(256, 3)
void conv_ft(const float* __restrict__ x, const _Float16* __restrict__ wsp,
             const float* __restrict__ scsh,
             const float* __restrict__ aPf, const float* __restrict__ aPt,
             _Float16* __restrict__ yf, _Float16* __restrict__ yt,
             int bsx, int bsyf, int bsyt)
{
    constexpr int LS = 200;
    extern __shared__ _Float16 ldsh[];
    _Float16* Xs0 = ldsh;                  // [64][200]: 0-95 hi, 96-191 lo
    _Float16* Xs1 = ldsh + 64 * LS;

    x  += (size_t)blockIdx.y * bsx;
    yf += (size_t)blockIdx.y * bsyf;
    yt += (size_t)blockIdx.y * bsyt;

    const int tid = threadIdx.x;
    const int p0A = blockIdx.x * 128;
    const int p0B = p0A + 64;

    {
        const float* xg = x + p0A;
        for (int e = tid; e < 64 * 12; e += 256) {
            const int p = e & 63, k0 = (e >> 6) * 8;
            const float* xp = xg + (size_t)k0 * TF_ + p;
            h8 hv, lv;
#pragma unroll
            for (int j = 0; j < 8; ++j) {
                const float xv = xp[(size_t)j * TF_];
                const _Float16 xh = (_Float16)xv;
                hv[j] = xh;
                lv[j] = (_Float16)(xv - (float)xh);
            }
            *(h8*)&Xs0[p * LS + k0]      = hv;
            *(h8*)&Xs0[p * LS + 96 + k0] = lv;
        }
    }

    const int lane = tid & 63, wid = tid >> 6;
    const int l16 = lane & 15, lg = lane >> 4;
    const int wm = wid >> 1, wn = wid & 1;       // 2x2 wave grid
    const float af_ = aPf[0], at_ = aPt[0];
    __syncthreads();

    float xpre[3][8];
#pragma unroll
    for (int it = 0; it < 3; ++it) {
        const int e = tid + it * 256;
        const int p = e & 63, k0 = (e >> 6) * 8;
        const float* xp = x + p0B + (size_t)k0 * TF_ + p;
#pragma unroll
        for (int j = 0; j < 8; ++j) xpre[it][j] = xp[(size_t)j * TF_];
    }

    auto compute5 = [&](const _Float16* Xs, int p0) {
#pragma unroll 1
        for (int cg = 0; cg < 5; ++cg) {
            const _Float16 *Wh, *Wl; const float* ss; float a; _Float16* yo;
            if (cg < 3) {
                Wh = wsp + WHF + cg * 9216;  Wl = wsp + WLF + cg * 9216;
                ss = scsh + cg * 192;        a = af_;
                yo = yf + (size_t)cg * QH_;
            } else {
                const int c2 = cg - 3;
                Wh = wsp + WHT + c2 * 9216;  Wl = wsp + WLT + c2 * 9216;
                ss = scsh + 576 + c2 * 192;  a = at_;
                yo = yt + (size_t)c2 * QH_;
            }

            f32x4 acc[3][2];
#pragma unroll
            for (int m = 0; m < 3; ++m)
#pragma unroll
                for (int n = 0; n < 2; ++n) acc[m][n] = (f32x4){0.f, 0.f, 0.f, 0.f};

#pragma unroll
            for (int kk = 0; kk < 3; ++kk) {
                h8 bfh[2], bfl[2];
#pragma unroll
                for (int n = 0; n < 2; ++n) {
                    const int prow = (wn * 2 + n) * 16 + l16;
                    bfh[n] = *(const h8*)&Xs[prow * LS + kk * 32 + lg * 8];
                    bfl[n] = *(const h8*)&Xs[prow * LS + 96 + kk * 32 + lg * 8];
                }
#pragma unroll
                for (int m = 0; m < 3; ++m) {
                    const int row = (wm * 3 + m) * 16 + l16;
                    const h8 wh = *(const h8*)&Wh[row * 96 + kk * 32 + lg * 8];
                    const h8 wl = *(const h8*)&Wl[row * 96 + kk * 32 + lg * 8];
#pragma unroll
                    for (int n = 0; n < 2; ++n) {
                        acc[m][n] = __builtin_amdgcn_mfma_f32_16x16x32_f16(wh, bfh[n], acc[m][n], 0, 0, 0);
                        acc[m][n] = __builtin_amdgcn_mfma_f32_16x16x32_f16(wl, bfh[n], acc[m][n], 0, 0, 0);
                        acc[m][n] = __builtin_amdgcn_mfma_f32_16x16x32_f16(wh, bfl[n], acc[m][n], 0, 0, 0);
                    }
                }
            }

#pragma unroll
            for (int m = 0; m < 3; ++m) {
#pragma unroll
                for (int r = 0; r < 4; ++r) {
                    const int col = (wm * 3 + m) * 16 + lg * 4 + r;
                    const f2 sp = *(const f2*)&ss[2 * col];
                    _Float16* yr = yo + (size_t)col * TF_ + p0 + wn * 32 + l16;
#pragma unroll
                    for (int n = 0; n < 2; ++n) {
                        const float v = fmaf(acc[m][n][r], sp[0], sp[1]);
                        yr[n * 16] = (_Float16)(v >= 0.f ? v : a * v);
                    }
                }
            }
        }
    };

    compute5(Xs0, p0A);

#pragma unroll
    for (int it = 0; it < 3; ++it) {
        const int e = tid + it * 256;
        const int p = e & 63, k0 = (e >> 6) * 8;
        h8 hv, lv;
#pragma unroll
        for (int j = 0; j < 8; ++j) {
            const _Float16 xh = (_Float16)xpre[it][j];
            hv[j] = xh;
            lv[j] = (_Float16)(xpre[it][j] - (float)xh);
        }
        *(h8*)&Xs1[p * LS + k0]      = hv;
        *(h8*)&Xs1[p * LS + 96 + k0] = lv;
    }
    __syncthreads();

    compute5(Xs1, p0B);
}

// ---------------------------------------------------------------------------
// 64x64 f16 transpose core: h8 global I/O, XOR-swizzled LDS tile [64][72].
// ---------------------------------------------------------------------------
__device__ __forceinline__ void tr64_body(const _Float16* __restrict__ in,
                                          _Float16* __restrict__ out,
                                          int Mo, int No, int n0, int m0,
                                          _Float16* tile)
{
    const int t = threadIdx.x, ty = t >> 3, tx8 = t & 7;
#pragma unroll
    for (int r = 0; r < 2; ++r) {
        const int n = ty + r * 32;
        const h8 v = *(const h8*)&in[(size_t)(n0 + n) * Mo + m0 + tx8 * 8];
        const int c = tx8 ^ (n >> 3);
        *(h8*)&tile[n * 72 + c * 8] = v;
    }
    __syncthreads();
#pragma unroll
    for (int r = 0; r < 2; ++r) {
        const int mt = ty + r * 32;
        h8 v;
#pragma unroll
        for (int j = 0; j < 8; ++j) {
            const int n = tx8 * 8 + j;
            const int c = (mt >> 3) ^ tx8;           // n>>3 == tx8
            v[j] = tile[n * 72 + c * 8 + (mt & 7)];
        }
        *(h8*)&out[(size_t)(m0 + mt) * No + n0 + tx8 * 8] = v;
    }
}

// trA: per batch 2 slabs (z = b*2+t): t=0 fout->foutT, t=1 th2 q->tqT.
__global__ __launch_bounds__(256)
void transpose_trA(const _Float16* __restrict__ doh, _Float16* __restrict__ wsh)
{
    __shared__ _Float16 tile[64 * 72];
    const int b = blockIdx.z >> 1, t = blockIdx.z & 1;
    const _Float16* in  = t ? doh + (size_t)b * 2 * QH_
                            : wsh + (size_t)b * 3 * QH_;
    _Float16*       out = t ? wsh + (size_t)b * 3 * QH_ + 2 * QH_
                            : wsh + (size_t)b * 3 * QH_ + QH_;
    tr64_body(in, out, F_, C_ * T_, blockIdx.x * 64, blockIdx.y * 64, tile);
}

// trB: th2 k-half -> tkT (unit 3b+0; fout dead after trA).
__global__ __launch_bounds__(256)
void transpose_trB(const _Float16* __restrict__ doh, _Float16* __restrict__ wsh)
{
    __shared__ _Float16 tile[64 * 72];
    const int b = blockIdx.z;
    tr64_body(doh + (size_t)b * 2 * QH_ + QH_, wsh + (size_t)b * 3 * QH_,
              F_, C_ * T_, blockIdx.x * 64, blockIdx.y * 64, tile);
}

// hf_res: tmp (F_, C*T) f16 + res f32 -> out (C*T, F_) f32.
__global__ __launch_bounds__(256)
void transpose_hf_res(const _Float16* __restrict__ in, const float* __restrict__ res,
                      float* __restrict__ out, int si, int sr, int so)
{
    __shared__ _Float16 tile[64 * 72];
    in  += (size_t)blockIdx.z * si;
    res += (size_t)blockIdx.z * sr;
    out += (size_t)blockIdx.z * so;
    const int n0 = blockIdx.x * 64, m0 = blockIdx.y * 64;
    const int t = threadIdx.x, ty = t >> 3, tx8 = t & 7;
#pragma unroll
    for (int r = 0; r < 2; ++r) {
        const int n = ty + r * 32;
        const h8 v = *(const h8*)&in[(size_t)(n0 + n) * (C_ * T_) + m0 + tx8 * 8];
        const int c = tx8 ^ (n >> 3);
        *(h8*)&tile[n * 72 + c * 8] = v;
    }
    __syncthreads();
#pragma unroll
    for (int r = 0; r < 2; ++r) {
        const int mt = ty + r * 32;
        const size_t obase = (size_t)(m0 + mt) * F_ + n0 + tx8 * 8;
        const f4 r0 = *(const f4*)&res[obase];
        const f4 r1 = *(const f4*)&res[obase + 4];
        f4 o0, o1;
#pragma unroll
        for (int j = 0; j < 8; ++j) {
            const int n = tx8 * 8 + j;
            const int c = (mt >> 3) ^ tx8;
            const float v = (float)tile[n * 72 + c * 8 + (mt & 7)];
            if (j < 4) o0[j] = v + r0[j]; else o1[j - 4] = v + r1[j - 4];
        }
        *(f4*)&out[obase]     = o0;
        *(f4*)&out[obase + 4] = o1;
    }
}

// ---------------------------------------------------------------------------
// MFMA f16 f-attention (MODE 0 diet: 3 blocks/CU).  O may alias Q (in-place).
// ---------------------------------------------------------------------------
template<int MODE>
__global__ __launch_bounds__(256, 2)
void attn_mfma(const _Float16* __restrict__ Qb, const _Float16* __restrict__ Kb,
               const _Float16* __restrict__ Vb, _Float16* __restrict__ Ob,
               int qs, int ks, int vs, int os)
{
    constexpr int NY  = (MODE == 0) ? 256 : 320;
    constexpr int LD  = (MODE == 0) ? TF_ : T_;
    constexpr int NT  = NY / 16;
    constexpr int NYK = NY / 32;
    constexpr int KS  = 104;
    constexpr int VPS = (MODE == 0) ? 256 : 344;
    constexpr int KVH = (NY * KS > 96 * VPS) ? NY * KS : 96 * VPS;
    constexpr int PMS = (MODE == 0) ? 32 : 40;     // Pme stride
    constexpr int PWO = (MODE == 0) ? 24576 : KVH; // Pw offset
    constexpr int NG  = (MODE == 0) ? T_ : F_;
    constexpr int GOFF = (MODE == 0) ? F_ : C_ * T_;

    extern __shared__ _Float16 ldsh[];
    _Float16* KV = ldsh;                 // Kt[NY][KS] -> V[96][VPS]
    _Float16* Pw = ldsh + PWO;           // [4][16][PMS]

    const int lb    = blockIdx.y;
    const int strip = blockIdx.x / NG;
    const int grp   = blockIdx.x % NG;
    const int m0    = strip * 64;
    const size_t off = (size_t)grp * GOFF;
    const _Float16* Q = Qb + (size_t)lb * qs + off;
    const _Float16* K = Kb + (size_t)lb * ks + off;
    const _Float16* V = Vb + (size_t)lb * vs + off;
    _Float16*       O = Ob + (size_t)lb * os + off;

    const int tid  = threadIdx.x;
    const int lane = tid & 63, wid = tid >> 6;
    const int l16  = lane & 15, lg = lane >> 4;
    const int mw   = wid * 16;
    const float scale = 0.10206207261596575f;   // 1/sqrt(96)

    for (int e = tid; e < NY * 12; e += 256) {
        const int yy = e % NY, k0 = (e / NY) * 8;
        const _Float16* kp = K + (size_t)k0 * LD + yy;
        h8 hv;
#pragma unroll
        for (int j = 0; j < 8; ++j) hv[j] = kp[(size_t)j * LD];
        *(h8*)&KV[yy * KS + k0] = hv;
    }

    h8 aQ[3];
#pragma unroll
    for (int kk = 0; kk < 3; ++kk) {
        const _Float16* qp = Q + (size_t)(kk * 32 + lg * 8) * LD + m0 + mw + l16;
#pragma unroll
        for (int j = 0; j < 8; ++j) aQ[kk][j] = qp[(size_t)j * LD];
    }
    __syncthreads();

    f32x4 sacc[NT];
#pragma unroll
    for (int t = 0; t < NT; ++t) sacc[t] = (f32x4){0.f, 0.f, 0.f, 0.f};
#pragma unroll
    for (int kk = 0; kk < 3; ++kk) {
#pragma unroll
        for (int t = 0; t < NT; ++t) {
            const h8 bK = *(const h8*)&KV[(t * 16 + l16) * KS + kk * 32 + lg * 8];
            sacc[t] = __builtin_amdgcn_mfma_f32_16x16x32_f16(aQ[kk], bK, sacc[t], 0, 0, 0);
        }
    }

#pragma unroll
    for (int r = 0; r < 4; ++r) {
        float mx = sacc[0][r];
#pragma unroll
        for (int t = 1; t < NT; ++t) mx = fmaxf(mx, sacc[t][r]);
        for (int d = 1; d < 16; d <<= 1) mx = fmaxf(mx, __shfl_xor(mx, d));
        float pv[NT];
        float sum = 0.f;
#pragma unroll
        for (int t = 0; t < NT; ++t) {
            pv[t] = __expf((sacc[t][r] - mx) * scale); sum += pv[t];
        }
        for (int d = 1; d < 16; d <<= 1) sum += __shfl_xor(sum, d);
        const float inv = 1.f / sum;
#pragma unroll
        for (int t = 0; t < NT; ++t) sacc[t][r] = pv[t] * inv;
    }
    __syncthreads();     // all K reads done; K region reusable (V + Pw)

    constexpr int NY8 = NY / 8;
    for (int e = tid; e < 96 * NY8; e += 256) {
        const int c = e / NY8, y8 = e - c * NY8;
        const int yc = (MODE == 0) ? (y8 ^ (c & 31)) : y8;   // V chunk swizzle
        *(h8*)&KV[c * VPS + yc * 8] = *(const h8*)(V + (size_t)c * LD + y8 * 8);
    }
    __syncthreads();

    _Float16* Pme = Pw + wid * (16 * PMS);
    f32x4 oacc[6];
#pragma unroll
    for (int ct = 0; ct < 6; ++ct) oacc[ct] = (f32x4){0.f, 0.f, 0.f, 0.f};

#pragma unroll
    for (int yk = 0; yk < NYK; ++yk) {
#pragma unroll
        for (int h = 0; h < 2; ++h)
#pragma unroll
            for (int r = 0; r < 4; ++r)
                Pme[(lg * 4 + r) * PMS + h * 16 + l16] = (_Float16)sacc[2 * yk + h][r];
        const h8 pf = *(const h8*)&Pme[l16 * PMS + lg * 8];   // in-wave DS order
#pragma unroll
        for (int ct = 0; ct < 6; ++ct) {
            const int c = ct * 16 + l16;
            const int ch = (MODE == 0) ? ((yk * 4 + lg) ^ (c & 31)) : (yk * 4 + lg);
            const h8 av = *(const h8*)&KV[c * VPS + ch * 8];
            oacc[ct] = __builtin_amdgcn_mfma_f32_16x16x32_f16(av, pf, oacc[ct], 0, 0, 0);
        }
    }
#pragma unroll
    for (int ct = 0; ct < 6; ++ct)
#pragma unroll
        for (int r = 0; r < 4; ++r)
            O[(size_t)(ct * 16 + lg * 4 + r) * LD + m0 + mw + l16] = (_Float16)oacc[ct][r];
}

// ---------------------------------------------------------------------------
// attn1_fused: t-attention + conv_p fused.  tmp writes IN-PLACE over the tqT
// unit (tmpb aliases Qb): block (grp,strip) reads Q only in columns
// [m0,m0+64) of its grp region (all into registers before the first barrier)
// and writes tmp only in those same columns; other strips/grps are disjoint.
// Same audited pattern as O-over-Q (proven since round 11).
// ---------------------------------------------------------------------------
__global__ __launch_bounds__(256, 2)
void attn1_fused(const _Float16* __restrict__ Qb, const _Float16* __restrict__ Kb,
                 const _Float16* __restrict__ Vb, _Float16* __restrict__ tmpb,
                 const _Float16* __restrict__ wsp, const float* __restrict__ scsh,
                 const float* __restrict__ aPp,
                 int qs, int ks, int vs, int ts)
{
    constexpr int NY = 320, LD = T_, NT = 20, NYK = 10;
    constexpr int KS = 104, VPS = 344;
    constexpr int KVH = NY * KS;
    constexpr int OS  = 104;

    extern __shared__ _Float16 ldsh[];
    _Float16* KV = ldsh;
    _Float16* Pw = ldsh + KVH;
    _Float16* Ot = ldsh;

    const int lb    = blockIdx.y;
    const int strip = blockIdx.x / F_;
    const int grp   = blockIdx.x % F_;
    const int m0    = strip * 64;
    const size_t off = (size_t)grp * (C_ * T_);
    const _Float16* Q = Qb + (size_t)lb * qs + off;
    const _Float16* K = Kb + (size_t)lb * ks + off;
    const _Float16* V = Vb + (size_t)lb * vs + off;
    _Float16*     tmp = tmpb + (size_t)lb * ts + (size_t)grp * (96 * T_);

    const int tid  = threadIdx.x;
    const int lane = tid & 63, wid = tid >> 6;
    const int l16  = lane & 15, lg = lane >> 4;
    const int mw   = wid * 16;
    const float scale = 0.10206207261596575f;

    for (int e = tid; e < NY * 12; e += 256) {
        const int yy = e % NY, k0 = (e / NY) * 8;
        const _Float16* kp = K + (size_t)k0 * LD + yy;
        h8 hv;
#pragma unroll
        for (int j = 0; j < 8; ++j) hv[j] = kp[(size_t)j * LD];
        *(h8*)&KV[yy * KS + k0] = hv;
    }

    h8 aQ[3];
#pragma unroll
    for (int kk = 0; kk < 3; ++kk) {
        const _Float16* qp = Q + (size_t)(kk * 32 + lg * 8) * LD + m0 + mw + l16;
#pragma unroll
        for (int j = 0; j < 8; ++j) aQ[kk][j] = qp[(size_t)j * LD];
    }
    __syncthreads();

    f32x4 sacc[NT];
#pragma unroll
    for (int t = 0; t < NT; ++t) sacc[t] = (f32x4){0.f, 0.f, 0.f, 0.f};
#pragma unroll
    for (int kk = 0; kk < 3; ++kk) {
#pragma unroll
        for (int t = 0; t < NT; ++t) {
            const h8 bK = *(const h8*)&KV[(t * 16 + l16) * KS + kk * 32 + lg * 8];
            sacc[t] = __builtin_amdgcn_mfma_f32_16x16x32_f16(aQ[kk], bK, sacc[t], 0, 0, 0);
        }
    }

#pragma unroll
    for (int r = 0; r < 4; ++r) {
        float mx = sacc[0][r];
#pragma unroll
        for (int t = 1; t < NT; ++t) mx = fmaxf(mx, sacc[t][r]);
        for (int d = 1; d < 16; d <<= 1) mx = fmaxf(mx, __shfl_xor(mx, d));
        float pv[NT];
        float sum = 0.f;
#pragma unroll
        for (int t = 0; t < NT; ++t) {
            pv[t] = __expf((sacc[t][r] - mx) * scale); sum += pv[t];
        }
        for (int d = 1; d < 16; d <<= 1) sum += __shfl_xor(sum, d);
        const float inv = 1.f / sum;
#pragma unroll
        for (int t = 0; t < NT; ++t) sacc[t][r] = pv[t] * inv;
    }
    __syncthreads();

    for (int e = tid; e < 96 * 40; e += 256) {
        const int c = e / 40, y8 = e - c * 40;
        *(h8*)&KV[c * VPS + y8 * 8] = *(const h8*)(V + (size_t)c * LD + y8 * 8);
    }
    __syncthreads();

    _Float16* Pme = Pw + wid * 640;
    f32x4 oacc[6];
#pragma unroll
    for (int ct = 0; ct < 6; ++ct) oacc[ct] = (f32x4){0.f, 0.f, 0.f, 0.f};

#pragma unroll
    for (int yk = 0; yk < NYK; ++yk) {
#pragma unroll
        for (int h = 0; h < 2; ++h)
#pragma unroll
            for (int r = 0; r < 4; ++r)
                Pme[(lg * 4 + r) * 40 + h * 16 + l16] = (_Float16)sacc[2 * yk + h][r];
        const h8 pf = *(const h8*)&Pme[l16 * 40 + lg * 8];
#pragma unroll
        for (int ct = 0; ct < 6; ++ct) {
            const h8 av = *(const h8*)&KV[(ct * 16 + l16) * VPS + yk * 32 + lg * 8];
            oacc[ct] = __builtin_amdgcn_mfma_f32_16x16x32_f16(av, pf, oacc[ct], 0, 0, 0);
        }
    }

    // ---- O tile -> LDS Ot[t][c] over dead V ----
    __syncthreads();
#pragma unroll
    for (int ct = 0; ct < 6; ++ct)
#pragma unroll
        for (int r = 0; r < 4; ++r)
            Ot[(mw + l16) * OS + ct * 16 + lg * 4 + r] = (_Float16)oacc[ct][r];
    __syncthreads();

    // ---- conv_p pass: tmp[co][t] = act(BN(sum_c Wp[co][c] Ot[t][c])) ----
    const int wm = wid >> 1, wn = wid & 1;
    const float a = aPp[0];
    const _Float16* Wh = wsp + WHP;
    const _Float16* Wl = wsp + WLP;
    const float* ss = scsh + 960;

    f32x4 acc2[3][2];
#pragma unroll
    for (int m = 0; m < 3; ++m)
#pragma unroll
        for (int n = 0; n < 2; ++n) acc2[m][n] = (f32x4){0.f, 0.f, 0.f, 0.f};

#pragma unroll
    for (int kk = 0; kk < 3; ++kk) {
        h8 bf[2];
#pragma unroll
        for (int n = 0; n < 2; ++n)
            bf[n] = *(const h8*)&Ot[((wn * 2 + n) * 16 + l16) * OS + kk * 32 + lg * 8];
#pragma unroll
        for (int m = 0; m < 3; ++m) {
            const int row = (wm * 3 + m) * 16 + l16;
            const h8 wh = *(const h8*)&Wh[row * 96 + kk * 32 + lg * 8];
            const h8 wl = *(const h8*)&Wl[row * 96 + kk * 32 + lg * 8];
#pragma unroll
            for (int n = 0; n < 2; ++n) {
                acc2[m][n] = __builtin_amdgcn_mfma_f32_16x16x32_f16(wh, bf[n], acc2[m][n], 0, 0, 0);
                acc2[m][n] = __builtin_amdgcn_mfma_f32_16x16x32_f16(wl, bf[n], acc2[m][n], 0, 0, 0);
            }
        }
    }

#pragma unroll
    for (int m = 0; m < 3; ++m) {
#pragma unroll
        for (int r = 0; r < 4; ++r) {
            const int co = (wm * 3 + m) * 16 + lg * 4 + r;
            const f2 sp = *(const f2*)&ss[2 * co];
            _Float16* yr = tmp + (size_t)co * T_ + m0 + wn * 32 + l16;
#pragma unroll
            for (int n = 0; n < 2; ++n) {
                const float v = fmaf(acc2[m][n][r], sp[0], sp[1]);
                yr[n * 16] = (_Float16)(v >= 0.f ? v : a * v);
            }
        }
    }
}

// ---------------------------------------------------------------------------
extern "C" void kernel_launch(void* const* d_in, const int* in_sizes, int n_in,
                              void* d_out, int out_size, void* d_ws, size_t ws_size,
                              hipStream_t stream)
{
    const float* inp = (const float*)d_in[0];
    const float* W_f = (const float*)d_in[1];  const float* b_f = (const float*)d_in[2];
    const float* g_f = (const float*)d_in[3];  const float* be_f = (const float*)d_in[4];
    const float* m_f = (const float*)d_in[5];  const float* v_f = (const float*)d_in[6];
    const float* a_f = (const float*)d_in[7];
    const float* W_t = (const float*)d_in[8];  const float* b_t = (const float*)d_in[9];
    const float* g_t = (const float*)d_in[10]; const float* be_t = (const float*)d_in[11];
    const float* m_t = (const float*)d_in[12]; const float* v_t = (const float*)d_in[13];
    const float* a_t = (const float*)d_in[14];
    const float* W_p = (const float*)d_in[15]; const float* b_p = (const float*)d_in[16];
    const float* g_p = (const float*)d_in[17]; const float* be_p = (const float*)d_in[18];
    const float* m_p = (const float*)d_in[19]; const float* v_p = (const float*)d_in[20];
    const float* a_p = (const float*)d_in[21];

    hipFuncSetAttribute((const void*)conv_ft,
                        hipFuncAttributeMaxDynamicSharedMemorySize, 51200);
    hipFuncSetAttribute((const void*)attn_mfma<0>,
                        hipFuncAttributeMaxDynamicSharedMemorySize, 53248);
    hipFuncSetAttribute((const void*)attn1_fused,
                        hipFuncAttributeMaxDynamicSharedMemorySize, 71680);

    // Unit plan per batch b (f16 units of QH_ elems, stride 3*QH_):
    //  3b+0: fqkv Q -> fout (attn0 in-place) -> [trA] -> tkT (trB)
    //  3b+1: fqkv K -> foutT (trA) = V of attn1
    //  3b+2: fqkv V -> tqT (trA) -> tmp (attn1_fused in-place over Q)
    //  d_out slice (2 f16 units/batch): th2 q,k halves.
    constexpr int QH = (int)QH_;
    const size_t tail  = (size_t)WTOT * 2 + 1152 * 4 + 4096;
    const size_t need4 = (size_t)12 * QH * 2 + tail;
    const int G = (ws_size >= need4) ? 4 : 2;     // batches per pass

    _Float16* wsh  = (_Float16*)d_ws;
    _Float16* wsp  = wsh + (size_t)3 * G * QH;    // W-split tail
    float*    scsh = (float*)(wsp + WTOT);

    prep_kernel<<<dim3(128), dim3(256), 0, stream>>>(
        W_f, W_t, W_p, b_f, g_f, be_f, m_f, v_f,
        b_t, g_t, be_t, m_t, v_t, b_p, g_p, be_p, m_p, v_p, wsp, scsh);

    for (int p = 0; p < B_ / G; ++p) {
        const float* xb  = inp + (size_t)p * G * QH;
        float*       dob = (float*)d_out + (size_t)p * G * QH;
        _Float16*    doh = (_Float16*)dob;        // th2 (2 units/batch)

        // 1. fused conv_f + conv_t
        conv_ft<<<dim3(640, G), dim3(256), 51200, stream>>>(
            xb, wsp, scsh, a_f, a_t, wsh, doh, QH, 3 * QH, 2 * QH);
        // 2. f-attention (3 blocks/CU diet), O in-place over Q third
        attn_mfma<0><<<dim3(T_ * (F_ / 64), G), dim3(256), 53248, stream>>>(
            wsh, wsh + QH_, wsh + 2 * QH_, wsh, 3 * QH, 3 * QH, 3 * QH, 3 * QH);
        // 3. trA: fout -> foutT (3b+1), th2 q -> tqT (3b+2)
        transpose_trA<<<dim3(480, 4, 2 * G), dim3(256), 0, stream>>>(doh, wsh);
        // 4. trB: th2 k -> tkT (3b+0)
        transpose_trB<<<dim3(480, 4, G), dim3(256), 0, stream>>>(doh, wsh);
        // 5. t-attention + conv_p fused; tmp in-place over tqT (3b+2)
        attn1_fused<<<dim3(F_ * (T_ / 64), G), dim3(256), 71680, stream>>>(
            wsh + 2 * QH_, wsh, wsh + QH_, wsh + 2 * QH_, wsp, scsh, a_p,
            3 * QH, 3 * QH, 3 * QH, 3 * QH);
        // 6. out = transpose(tmp @ 3b+2) + inp
        transpose_hf_res<<<dim3(4, 480, G), dim3(256), 0, stream>>>(
            wsh + 2 * QH_, xb, dob, 3 * QH, QH, QH);
    }
}

// Round 22
// 618.509 us; speedup vs baseline: 1.2715x; 1.0654x over previous
//
#include <hip/hip_runtime.h>
#include <math.h>

typedef float f4 __attribute__((ext_vector_type(4)));
typedef float f2 __attribute__((ext_vector_type(2)));
typedef float f32x4 __attribute__((ext_vector_type(4)));
typedef _Float16 h8 __attribute__((ext_vector_type(8)));

constexpr int B_ = 4, C_ = 96, T_ = 320, F_ = 256;
constexpr int TF_ = T_ * F_;          // 81920
constexpr float EPS_ = 1e-5f;
constexpr size_t QH_ = (size_t)C_ * TF_;   // 7,864,320 elems per (C,T,F) unit

// Packed-W layout (f16, after the data units):
//  [0, 92160):      conv_ft records  [cg5][wm2][m3][kk3][hi/lo] x 512
//  [92160, 110592): conv_p  records  [wm2][m3][kk3][hi/lo] x 512
// Each record = one wave-load: 64 lanes x h8, 1KB contiguous (kills the 4x
// L2 line amplification of the old row-strided layout).
constexpr int WPP = 92160, WTOT = 110592;

// ---------------------------------------------------------------------------
// One-time prep: pack W into fragment-major hi/lo records; BN (sc,sh).
// Lane mapping identical to the old in-kernel fragment load:
//   row = (wm*3+m)*16 + (lane&15), col = kk*32 + (lane>>4)*8 + j.
// ---------------------------------------------------------------------------
__global__ __launch_bounds__(256)
void prep_kernel(const float* __restrict__ Wf, const float* __restrict__ Wt,
                 const float* __restrict__ Wp,
                 const float* __restrict__ bf, const float* __restrict__ gf,
                 const float* __restrict__ bef, const float* __restrict__ mf,
                 const float* __restrict__ vf,
                 const float* __restrict__ bt, const float* __restrict__ gt,
                 const float* __restrict__ bet, const float* __restrict__ mt,
                 const float* __restrict__ vt,
                 const float* __restrict__ bp, const float* __restrict__ gp,
                 const float* __restrict__ bep, const float* __restrict__ mp,
                 const float* __restrict__ vp,
                 _Float16* __restrict__ wsp, float* __restrict__ scsh)
{
    const int gtid = blockIdx.x * 256 + threadIdx.x;
    const int gsz  = gridDim.x * 256;
    // conv_ft: 90 float-records (5cg x 2wm x 3m x 3kk) x 512 elems
    for (int i = gtid; i < 46080; i += gsz) {
        const int frid = i >> 9, le = i & 511;
        const int lane = le >> 3, j = le & 7;
        const int kk = frid % 3, m = (frid / 3) % 3,
                  wm = (frid / 9) & 1, cg = frid / 18;
        const int row = (wm * 3 + m) * 16 + (lane & 15);
        const int col = kk * 32 + (lane >> 4) * 8 + j;
        const float* src = (cg < 3) ? Wf + cg * 9216 : Wt + (cg - 3) * 9216;
        const float w = src[row * 96 + col];
        const _Float16 h = (_Float16)w;
        wsp[(frid * 2 + 0) * 512 + le] = h;
        wsp[(frid * 2 + 1) * 512 + le] = (_Float16)(w - (float)h);
    }
    // conv_p: 18 float-records (2wm x 3m x 3kk) x 512
    for (int i = gtid; i < 9216; i += gsz) {
        const int frid = i >> 9, le = i & 511;
        const int lane = le >> 3, j = le & 7;
        const int kk = frid % 3, m = (frid / 3) % 3, wm = frid / 9;
        const int row = (wm * 3 + m) * 16 + (lane & 15);
        const int col = kk * 32 + (lane >> 4) * 8 + j;
        const float w = Wp[row * 96 + col];
        const _Float16 h = (_Float16)w;
        wsp[WPP + (frid * 2 + 0) * 512 + le] = h;
        wsp[WPP + (frid * 2 + 1) * 512 + le] = (_Float16)(w - (float)h);
    }
    if (gtid < 288) {
        const float sc = gf[gtid] * rsqrtf(vf[gtid] + EPS_);
        scsh[2 * gtid] = sc;
        scsh[2 * gtid + 1] = fmaf(bf[gtid] - mf[gtid], sc, bef[gtid]);
    } else if (gtid < 480) {
        const int i = gtid - 288;
        const float sc = gt[i] * rsqrtf(vt[i] + EPS_);
        scsh[576 + 2 * i] = sc;
        scsh[576 + 2 * i + 1] = fmaf(bt[i] - mt[i], sc, bet[i]);
    } else if (gtid < 576) {
        const int i = gtid - 480;
        const float sc = gp[i] * rsqrtf(vp[i] + EPS_);
        scsh[960 + 2 * i] = sc;
        scsh[960 + 2 * i + 1] = fmaf(bp[i] - mp[i], sc, bep[i]);
    }
}

// ---------------------------------------------------------------------------
// Fused conv_f + conv_t (round-18 structure) + packed coalesced W loads.
// ---------------------------------------------------------------------------
__global__ __launch_bounds__(256, 3)
void conv_ft(const float* __restrict__ x, const _Float16* __restrict__ wsp,
             const float* __restrict__ scsh,
             const float* __restrict__ aPf, const float* __restrict__ aPt,
             _Float16* __restrict__ yf, _Float16* __restrict__ yt,
             int bsx, int bsyf, int bsyt)
{
    constexpr int LS = 200;
    extern __shared__ _Float16 ldsh[];
    _Float16* Xs0 = ldsh;                  // [64][200]: 0-95 hi, 96-191 lo
    _Float16* Xs1 = ldsh + 64 * LS;

    x  += (size_t)blockIdx.y * bsx;
    yf += (size_t)blockIdx.y * bsyf;
    yt += (size_t)blockIdx.y * bsyt;

    const int tid = threadIdx.x;
    const int p0A = blockIdx.x * 128;
    const int p0B = p0A + 64;

    {
        const float* xg = x + p0A;
        for (int e = tid; e < 64 * 12; e += 256) {
            const int p = e & 63, k0 = (e >> 6) * 8;
            const float* xp = xg + (size_t)k0 * TF_ + p;
            h8 hv, lv;
#pragma unroll
            for (int j = 0; j < 8; ++j) {
                const float xv = xp[(size_t)j * TF_];
                const _Float16 xh = (_Float16)xv;
                hv[j] = xh;
                lv[j] = (_Float16)(xv - (float)xh);
            }
            *(h8*)&Xs0[p * LS + k0]      = hv;
            *(h8*)&Xs0[p * LS + 96 + k0] = lv;
        }
    }

    const int lane = tid & 63, wid = tid >> 6;
    const int l16 = lane & 15, lg = lane >> 4;
    const int wm = wid >> 1, wn = wid & 1;       // 2x2 wave grid
    const float af_ = aPf[0], at_ = aPt[0];
    __syncthreads();

    float xpre[3][8];
#pragma unroll
    for (int it = 0; it < 3; ++it) {
        const int e = tid + it * 256;
        const int p = e & 63, k0 = (e >> 6) * 8;
        const float* xp = x + p0B + (size_t)k0 * TF_ + p;
#pragma unroll
        for (int j = 0; j < 8; ++j) xpre[it][j] = xp[(size_t)j * TF_];
    }

    auto compute5 = [&](const _Float16* Xs, int p0) {
#pragma unroll 1
        for (int cg = 0; cg < 5; ++cg) {
            const float* ss; float a; _Float16* yo;
            if (cg < 3) {
                ss = scsh + cg * 192;        a = af_;
                yo = yf + (size_t)cg * QH_;
            } else {
                ss = scsh + 576 + (cg - 3) * 192;  a = at_;
                yo = yt + (size_t)(cg - 3) * QH_;
            }
            // packed base for this (cg, wm): 9 float-records of 1024 f16
            const _Float16* wbase = wsp + (size_t)(cg * 2 + wm) * 9 * 1024 + lane * 8;

            f32x4 acc[3][2];
#pragma unroll
            for (int m = 0; m < 3; ++m)
#pragma unroll
                for (int n = 0; n < 2; ++n) acc[m][n] = (f32x4){0.f, 0.f, 0.f, 0.f};

#pragma unroll
            for (int kk = 0; kk < 3; ++kk) {
                h8 bfh[2], bfl[2];
#pragma unroll
                for (int n = 0; n < 2; ++n) {
                    const int prow = (wn * 2 + n) * 16 + l16;
                    bfh[n] = *(const h8*)&Xs[prow * LS + kk * 32 + lg * 8];
                    bfl[n] = *(const h8*)&Xs[prow * LS + 96 + kk * 32 + lg * 8];
                }
#pragma unroll
                for (int m = 0; m < 3; ++m) {
                    const _Float16* wr = wbase + (size_t)(m * 3 + kk) * 1024;
                    const h8 wh = *(const h8*)&wr[0];
                    const h8 wl = *(const h8*)&wr[512];
#pragma unroll
                    for (int n = 0; n < 2; ++n) {
                        acc[m][n] = __builtin_amdgcn_mfma_f32_16x16x32_f16(wh, bfh[n], acc[m][n], 0, 0, 0);
                        acc[m][n] = __builtin_amdgcn_mfma_f32_16x16x32_f16(wl, bfh[n], acc[m][n], 0, 0, 0);
                        acc[m][n] = __builtin_amdgcn_mfma_f32_16x16x32_f16(wh, bfl[n], acc[m][n], 0, 0, 0);
                    }
                }
            }

#pragma unroll
            for (int m = 0; m < 3; ++m) {
#pragma unroll
                for (int r = 0; r < 4; ++r) {
                    const int col = (wm * 3 + m) * 16 + lg * 4 + r;
                    const f2 sp = *(const f2*)&ss[2 * col];
                    _Float16* yr = yo + (size_t)col * TF_ + p0 + wn * 32 + l16;
#pragma unroll
                    for (int n = 0; n < 2; ++n) {
                        const float v = fmaf(acc[m][n][r], sp[0], sp[1]);
                        yr[n * 16] = (_Float16)(v >= 0.f ? v : a * v);
                    }
                }
            }
        }
    };

    compute5(Xs0, p0A);

#pragma unroll
    for (int it = 0; it < 3; ++it) {
        const int e = tid + it * 256;
        const int p = e & 63, k0 = (e >> 6) * 8;
        h8 hv, lv;
#pragma unroll
        for (int j = 0; j < 8; ++j) {
            const _Float16 xh = (_Float16)xpre[it][j];
            hv[j] = xh;
            lv[j] = (_Float16)(xpre[it][j] - (float)xh);
        }
        *(h8*)&Xs1[p * LS + k0]      = hv;
        *(h8*)&Xs1[p * LS + 96 + k0] = lv;
    }
    __syncthreads();

    compute5(Xs1, p0B);
}

// ---------------------------------------------------------------------------
// 64x64 f16 transpose core: h8 global I/O, XOR-swizzled LDS tile [64][72].
// ---------------------------------------------------------------------------
__device__ __forceinline__ void tr64_body(const _Float16* __restrict__ in,
                                          _Float16* __restrict__ out,
                                          int Mo, int No, int n0, int m0,
                                          _Float16* tile)
{
    const int t = threadIdx.x, ty = t >> 3, tx8 = t & 7;
#pragma unroll
    for (int r = 0; r < 2; ++r) {
        const int n = ty + r * 32;
        const h8 v = *(const h8*)&in[(size_t)(n0 + n) * Mo + m0 + tx8 * 8];
        const int c = tx8 ^ (n >> 3);
        *(h8*)&tile[n * 72 + c * 8] = v;
    }
    __syncthreads();
#pragma unroll
    for (int r = 0; r < 2; ++r) {
        const int mt = ty + r * 32;
        h8 v;
#pragma unroll
        for (int j = 0; j < 8; ++j) {
            const int n = tx8 * 8 + j;
            const int c = (mt >> 3) ^ tx8;           // n>>3 == tx8
            v[j] = tile[n * 72 + c * 8 + (mt & 7)];
        }
        *(h8*)&out[(size_t)(m0 + mt) * No + n0 + tx8 * 8] = v;
    }
}

// trA: per batch 2 slabs (z = b*2+t): t=0 fout->foutT, t=1 th2 q->tqT.
__global__ __launch_bounds__(256)
void transpose_trA(const _Float16* __restrict__ doh, _Float16* __restrict__ wsh)
{
    __shared__ _Float16 tile[64 * 72];
    const int b = blockIdx.z >> 1, t = blockIdx.z & 1;
    const _Float16* in  = t ? doh + (size_t)b * 2 * QH_
                            : wsh + (size_t)b * 3 * QH_;
    _Float16*       out = t ? wsh + (size_t)b * 3 * QH_ + 2 * QH_
                            : wsh + (size_t)b * 3 * QH_ + QH_;
    tr64_body(in, out, F_, C_ * T_, blockIdx.x * 64, blockIdx.y * 64, tile);
}

// trB: th2 k-half -> tkT (unit 3b+0; fout dead after trA).
__global__ __launch_bounds__(256)
void transpose_trB(const _Float16* __restrict__ doh, _Float16* __restrict__ wsh)
{
    __shared__ _Float16 tile[64 * 72];
    const int b = blockIdx.z;
    tr64_body(doh + (size_t)b * 2 * QH_ + QH_, wsh + (size_t)b * 3 * QH_,
              F_, C_ * T_, blockIdx.x * 64, blockIdx.y * 64, tile);
}

// hf_res: tmp (F_, C*T) f16 + res f32 -> out (C*T, F_) f32.
__global__ __launch_bounds__(256)
void transpose_hf_res(const _Float16* __restrict__ in, const float* __restrict__ res,
                      float* __restrict__ out, int si, int sr, int so)
{
    __shared__ _Float16 tile[64 * 72];
    in  += (size_t)blockIdx.z * si;
    res += (size_t)blockIdx.z * sr;
    out += (size_t)blockIdx.z * so;
    const int n0 = blockIdx.x * 64, m0 = blockIdx.y * 64;
    const int t = threadIdx.x, ty = t >> 3, tx8 = t & 7;
#pragma unroll
    for (int r = 0; r < 2; ++r) {
        const int n = ty + r * 32;
        const h8 v = *(const h8*)&in[(size_t)(n0 + n) * (C_ * T_) + m0 + tx8 * 8];
        const int c = tx8 ^ (n >> 3);
        *(h8*)&tile[n * 72 + c * 8] = v;
    }
    __syncthreads();
#pragma unroll
    for (int r = 0; r < 2; ++r) {
        const int mt = ty + r * 32;
        const size_t obase = (size_t)(m0 + mt) * F_ + n0 + tx8 * 8;
        const f4 r0 = *(const f4*)&res[obase];
        const f4 r1 = *(const f4*)&res[obase + 4];
        f4 o0, o1;
#pragma unroll
        for (int j = 0; j < 8; ++j) {
            const int n = tx8 * 8 + j;
            const int c = (mt >> 3) ^ tx8;
            const float v = (float)tile[n * 72 + c * 8 + (mt & 7)];
            if (j < 4) o0[j] = v + r0[j]; else o1[j - 4] = v + r1[j - 4];
        }
        *(f4*)&out[obase]     = o0;
        *(f4*)&out[obase + 4] = o1;
    }
}

// ---------------------------------------------------------------------------
// MFMA f16 f-attention (MODE 0 diet: 3 blocks/CU).  O may alias Q (in-place).
// ---------------------------------------------------------------------------
template<int MODE>
__global__ __launch_bounds__(256, 2)
void attn_mfma(const _Float16* __restrict__ Qb, const _Float16* __restrict__ Kb,
               const _Float16* __restrict__ Vb, _Float16* __restrict__ Ob,
               int qs, int ks, int vs, int os)
{
    constexpr int NY  = (MODE == 0) ? 256 : 320;
    constexpr int LD  = (MODE == 0) ? TF_ : T_;
    constexpr int NT  = NY / 16;
    constexpr int NYK = NY / 32;
    constexpr int KS  = 104;
    constexpr int VPS = (MODE == 0) ? 256 : 344;
    constexpr int KVH = (NY * KS > 96 * VPS) ? NY * KS : 96 * VPS;
    constexpr int PMS = (MODE == 0) ? 32 : 40;     // Pme stride
    constexpr int PWO = (MODE == 0) ? 24576 : KVH; // Pw offset
    constexpr int NG  = (MODE == 0) ? T_ : F_;
    constexpr int GOFF = (MODE == 0) ? F_ : C_ * T_;

    extern __shared__ _Float16 ldsh[];
    _Float16* KV = ldsh;                 // Kt[NY][KS] -> V[96][VPS]
    _Float16* Pw = ldsh + PWO;           // [4][16][PMS]

    const int lb    = blockIdx.y;
    const int strip = blockIdx.x / NG;
    const int grp   = blockIdx.x % NG;
    const int m0    = strip * 64;
    const size_t off = (size_t)grp * GOFF;
    const _Float16* Q = Qb + (size_t)lb * qs + off;
    const _Float16* K = Kb + (size_t)lb * ks + off;
    const _Float16* V = Vb + (size_t)lb * vs + off;
    _Float16*       O = Ob + (size_t)lb * os + off;

    const int tid  = threadIdx.x;
    const int lane = tid & 63, wid = tid >> 6;
    const int l16  = lane & 15, lg = lane >> 4;
    const int mw   = wid * 16;
    const float scale = 0.10206207261596575f;   // 1/sqrt(96)

    for (int e = tid; e < NY * 12; e += 256) {
        const int yy = e % NY, k0 = (e / NY) * 8;
        const _Float16* kp = K + (size_t)k0 * LD + yy;
        h8 hv;
#pragma unroll
        for (int j = 0; j < 8; ++j) hv[j] = kp[(size_t)j * LD];
        *(h8*)&KV[yy * KS + k0] = hv;
    }

    h8 aQ[3];
#pragma unroll
    for (int kk = 0; kk < 3; ++kk) {
        const _Float16* qp = Q + (size_t)(kk * 32 + lg * 8) * LD + m0 + mw + l16;
#pragma unroll
        for (int j = 0; j < 8; ++j) aQ[kk][j] = qp[(size_t)j * LD];
    }
    __syncthreads();

    f32x4 sacc[NT];
#pragma unroll
    for (int t = 0; t < NT; ++t) sacc[t] = (f32x4){0.f, 0.f, 0.f, 0.f};
#pragma unroll
    for (int kk = 0; kk < 3; ++kk) {
#pragma unroll
        for (int t = 0; t < NT; ++t) {
            const h8 bK = *(const h8*)&KV[(t * 16 + l16) * KS + kk * 32 + lg * 8];
            sacc[t] = __builtin_amdgcn_mfma_f32_16x16x32_f16(aQ[kk], bK, sacc[t], 0, 0, 0);
        }
    }

#pragma unroll
    for (int r = 0; r < 4; ++r) {
        float mx = sacc[0][r];
#pragma unroll
        for (int t = 1; t < NT; ++t) mx = fmaxf(mx, sacc[t][r]);
        for (int d = 1; d < 16; d <<= 1) mx = fmaxf(mx, __shfl_xor(mx, d));
        float pv[NT];
        float sum = 0.f;
#pragma unroll
        for (int t = 0; t < NT; ++t) {
            pv[t] = __expf((sacc[t][r] - mx) * scale); sum += pv[t];
        }
        for (int d = 1; d < 16; d <<= 1) sum += __shfl_xor(sum, d);
        const float inv = 1.f / sum;
#pragma unroll
        for (int t = 0; t < NT; ++t) sacc[t][r] = pv[t] * inv;
    }
    __syncthreads();     // all K reads done; K region reusable (V + Pw)

    constexpr int NY8 = NY / 8;
    for (int e = tid; e < 96 * NY8; e += 256) {
        const int c = e / NY8, y8 = e - c * NY8;
        const int yc = (MODE == 0) ? (y8 ^ (c & 31)) : y8;   // V chunk swizzle
        *(h8*)&KV[c * VPS + yc * 8] = *(const h8*)(V + (size_t)c * LD + y8 * 8);
    }
    __syncthreads();

    _Float16* Pme = Pw + wid * (16 * PMS);
    f32x4 oacc[6];
#pragma unroll
    for (int ct = 0; ct < 6; ++ct) oacc[ct] = (f32x4){0.f, 0.f, 0.f, 0.f};

#pragma unroll
    for (int yk = 0; yk < NYK; ++yk) {
#pragma unroll
        for (int h = 0; h < 2; ++h)
#pragma unroll
            for (int r = 0; r < 4; ++r)
                Pme[(lg * 4 + r) * PMS + h * 16 + l16] = (_Float16)sacc[2 * yk + h][r];
        const h8 pf = *(const h8*)&Pme[l16 * PMS + lg * 8];   // in-wave DS order
#pragma unroll
        for (int ct = 0; ct < 6; ++ct) {
            const int c = ct * 16 + l16;
            const int ch = (MODE == 0) ? ((yk * 4 + lg) ^ (c & 31)) : (yk * 4 + lg);
            const h8 av = *(const h8*)&KV[c * VPS + ch * 8];
            oacc[ct] = __builtin_amdgcn_mfma_f32_16x16x32_f16(av, pf, oacc[ct], 0, 0, 0);
        }
    }
#pragma unroll
    for (int ct = 0; ct < 6; ++ct)
#pragma unroll
        for (int r = 0; r < 4; ++r)
            O[(size_t)(ct * 16 + lg * 4 + r) * LD + m0 + mw + l16] = (_Float16)oacc[ct][r];
}

// ---------------------------------------------------------------------------
// attn1_fused: t-attention + conv_p fused; tmp in-place over tqT (proven).
// conv_p W loads now packed/coalesced.
// ---------------------------------------------------------------------------
__global__ __launch_bounds__(256, 2)
void attn1_fused(const _Float16* __restrict__ Qb, const _Float16* __restrict__ Kb,
                 const _Float16* __restrict__ Vb, _Float16* __restrict__ tmpb,
                 const _Float16* __restrict__ wsp, const float* __restrict__ scsh,
                 const float* __restrict__ aPp,
                 int qs, int ks, int vs, int ts)
{
    constexpr int NY = 320, LD = T_, NT = 20, NYK = 10;
    constexpr int KS = 104, VPS = 344;
    constexpr int KVH = NY * KS;
    constexpr int OS  = 104;

    extern __shared__ _Float16 ldsh[];
    _Float16* KV = ldsh;
    _Float16* Pw = ldsh + KVH;
    _Float16* Ot = ldsh;

    const int lb    = blockIdx.y;
    const int strip = blockIdx.x / F_;
    const int grp   = blockIdx.x % F_;
    const int m0    = strip * 64;
    const size_t off = (size_t)grp * (C_ * T_);
    const _Float16* Q = Qb + (size_t)lb * qs + off;
    const _Float16* K = Kb + (size_t)lb * ks + off;
    const _Float16* V = Vb + (size_t)lb * vs + off;
    _Float16*     tmp = tmpb + (size_t)lb * ts + (size_t)grp * (96 * T_);

    const int tid  = threadIdx.x;
    const int lane = tid & 63, wid = tid >> 6;
    const int l16  = lane & 15, lg = lane >> 4;
    const int mw   = wid * 16;
    const float scale = 0.10206207261596575f;

    for (int e = tid; e < NY * 12; e += 256) {
        const int yy = e % NY, k0 = (e / NY) * 8;
        const _Float16* kp = K + (size_t)k0 * LD + yy;
        h8 hv;
#pragma unroll
        for (int j = 0; j < 8; ++j) hv[j] = kp[(size_t)j * LD];
        *(h8*)&KV[yy * KS + k0] = hv;
    }

    h8 aQ[3];
#pragma unroll
    for (int kk = 0; kk < 3; ++kk) {
        const _Float16* qp = Q + (size_t)(kk * 32 + lg * 8) * LD + m0 + mw + l16;
#pragma unroll
        for (int j = 0; j < 8; ++j) aQ[kk][j] = qp[(size_t)j * LD];
    }
    __syncthreads();

    f32x4 sacc[NT];
#pragma unroll
    for (int t = 0; t < NT; ++t) sacc[t] = (f32x4){0.f, 0.f, 0.f, 0.f};
#pragma unroll
    for (int kk = 0; kk < 3; ++kk) {
#pragma unroll
        for (int t = 0; t < NT; ++t) {
            const h8 bK = *(const h8*)&KV[(t * 16 + l16) * KS + kk * 32 + lg * 8];
            sacc[t] = __builtin_amdgcn_mfma_f32_16x16x32_f16(aQ[kk], bK, sacc[t], 0, 0, 0);
        }
    }

#pragma unroll
    for (int r = 0; r < 4; ++r) {
        float mx = sacc[0][r];
#pragma unroll
        for (int t = 1; t < NT; ++t) mx = fmaxf(mx, sacc[t][r]);
        for (int d = 1; d < 16; d <<= 1) mx = fmaxf(mx, __shfl_xor(mx, d));
        float pv[NT];
        float sum = 0.f;
#pragma unroll
        for (int t = 0; t < NT; ++t) {
            pv[t] = __expf((sacc[t][r] - mx) * scale); sum += pv[t];
        }
        for (int d = 1; d < 16; d <<= 1) sum += __shfl_xor(sum, d);
        const float inv = 1.f / sum;
#pragma unroll
        for (int t = 0; t < NT; ++t) sacc[t][r] = pv[t] * inv;
    }
    __syncthreads();

    for (int e = tid; e < 96 * 40; e += 256) {
        const int c = e / 40, y8 = e - c * 40;
        *(h8*)&KV[c * VPS + y8 * 8] = *(const h8*)(V + (size_t)c * LD + y8 * 8);
    }
    __syncthreads();

    _Float16* Pme = Pw + wid * 640;
    f32x4 oacc[6];
#pragma unroll
    for (int ct = 0; ct < 6; ++ct) oacc[ct] = (f32x4){0.f, 0.f, 0.f, 0.f};

#pragma unroll
    for (int yk = 0; yk < NYK; ++yk) {
#pragma unroll
        for (int h = 0; h < 2; ++h)
#pragma unroll
            for (int r = 0; r < 4; ++r)
                Pme[(lg * 4 + r) * 40 + h * 16 + l16] = (_Float16)sacc[2 * yk + h][r];
        const h8 pf = *(const h8*)&Pme[l16 * 40 + lg * 8];
#pragma unroll
        for (int ct = 0; ct < 6; ++ct) {
            const h8 av = *(const h8*)&KV[(ct * 16 + l16) * VPS + yk * 32 + lg * 8];
            oacc[ct] = __builtin_amdgcn_mfma_f32_16x16x32_f16(av, pf, oacc[ct], 0, 0, 0);
        }
    }

    // ---- O tile -> LDS Ot[t][c] over dead V ----
    __syncthreads();
#pragma unroll
    for (int ct = 0; ct < 6; ++ct)
#pragma unroll
        for (int r = 0; r < 4; ++r)
            Ot[(mw + l16) * OS + ct * 16 + lg * 4 + r] = (_Float16)oacc[ct][r];
    __syncthreads();

    // ---- conv_p pass with packed W ----
    const int wm = wid >> 1, wn = wid & 1;
    const float a = aPp[0];
    const float* ss = scsh + 960;
    const _Float16* wbase = wsp + WPP + (size_t)wm * 9 * 1024 + lane * 8;

    f32x4 acc2[3][2];
#pragma unroll
    for (int m = 0; m < 3; ++m)
#pragma unroll
        for (int n = 0; n < 2; ++n) acc2[m][n] = (f32x4){0.f, 0.f, 0.f, 0.f};

#pragma unroll
    for (int kk = 0; kk < 3; ++kk) {
        h8 bf[2];
#pragma unroll
        for (int n = 0; n < 2; ++n)
            bf[n] = *(const h8*)&Ot[((wn * 2 + n) * 16 + l16) * OS + kk * 32 + lg * 8];
#pragma unroll
        for (int m = 0; m < 3; ++m) {
            const _Float16* wr = wbase + (size_t)(m * 3 + kk) * 1024;
            const h8 wh = *(const h8*)&wr[0];
            const h8 wl = *(const h8*)&wr[512];
#pragma unroll
            for (int n = 0; n < 2; ++n) {
                acc2[m][n] = __builtin_amdgcn_mfma_f32_16x16x32_f16(wh, bf[n], acc2[m][n], 0, 0, 0);
                acc2[m][n] = __builtin_amdgcn_mfma_f32_16x16x32_f16(wl, bf[n], acc2[m][n], 0, 0, 0);
            }
        }
    }

#pragma unroll
    for (int m = 0; m < 3; ++m) {
#pragma unroll
        for (int r = 0; r < 4; ++r) {
            const int co = (wm * 3 + m) * 16 + lg * 4 + r;
            const f2 sp = *(const f2*)&ss[2 * co];
            _Float16* yr = tmp + (size_t)co * T_ + m0 + wn * 32 + l16;
#pragma unroll
            for (int n = 0; n < 2; ++n) {
                const float v = fmaf(acc2[m][n][r], sp[0], sp[1]);
                yr[n * 16] = (_Float16)(v >= 0.f ? v : a * v);
            }
        }
    }
}

// ---------------------------------------------------------------------------
extern "C" void kernel_launch(void* const* d_in, const int* in_sizes, int n_in,
                              void* d_out, int out_size, void* d_ws, size_t ws_size,
                              hipStream_t stream)
{
    const float* inp = (const float*)d_in[0];
    const float* W_f = (const float*)d_in[1];  const float* b_f = (const float*)d_in[2];
    const float* g_f = (const float*)d_in[3];  const float* be_f = (const float*)d_in[4];
    const float* m_f = (const float*)d_in[5];  const float* v_f = (const float*)d_in[6];
    const float* a_f = (const float*)d_in[7];
    const float* W_t = (const float*)d_in[8];  const float* b_t = (const float*)d_in[9];
    const float* g_t = (const float*)d_in[10]; const float* be_t = (const float*)d_in[11];
    const float* m_t = (const float*)d_in[12]; const float* v_t = (const float*)d_in[13];
    const float* a_t = (const float*)d_in[14];
    const float* W_p = (const float*)d_in[15]; const float* b_p = (const float*)d_in[16];
    const float* g_p = (const float*)d_in[17]; const float* be_p = (const float*)d_in[18];
    const float* m_p = (const float*)d_in[19]; const float* v_p = (const float*)d_in[20];
    const float* a_p = (const float*)d_in[21];

    hipFuncSetAttribute((const void*)conv_ft,
                        hipFuncAttributeMaxDynamicSharedMemorySize, 51200);
    hipFuncSetAttribute((const void*)attn_mfma<0>,
                        hipFuncAttributeMaxDynamicSharedMemorySize, 53248);
    hipFuncSetAttribute((const void*)attn1_fused,
                        hipFuncAttributeMaxDynamicSharedMemorySize, 71680);

    constexpr int QH = (int)QH_;
    const size_t tail  = (size_t)WTOT * 2 + 1152 * 4 + 4096;
    const size_t need4 = (size_t)12 * QH * 2 + tail;
    const int G = (ws_size >= need4) ? 4 : 2;     // batches per pass

    _Float16* wsh  = (_Float16*)d_ws;
    _Float16* wsp  = wsh + (size_t)3 * G * QH;    // packed-W tail
    float*    scsh = (float*)(wsp + WTOT);

    prep_kernel<<<dim3(128), dim3(256), 0, stream>>>(
        W_f, W_t, W_p, b_f, g_f, be_f, m_f, v_f,
        b_t, g_t, be_t, m_t, v_t, b_p, g_p, be_p, m_p, v_p, wsp, scsh);

    for (int p = 0; p < B_ / G; ++p) {
        const float* xb  = inp + (size_t)p * G * QH;
        float*       dob = (float*)d_out + (size_t)p * G * QH;
        _Float16*    doh = (_Float16*)dob;        // th2 (2 units/batch)

        // 1. fused conv_f + conv_t (packed W)
        conv_ft<<<dim3(640, G), dim3(256), 51200, stream>>>(
            xb, wsp, scsh, a_f, a_t, wsh, doh, QH, 3 * QH, 2 * QH);
        // 2. f-attention (3 blocks/CU diet), O in-place over Q third
        attn_mfma<0><<<dim3(T_ * (F_ / 64), G), dim3(256), 53248, stream>>>(
            wsh, wsh + QH_, wsh + 2 * QH_, wsh, 3 * QH, 3 * QH, 3 * QH, 3 * QH);
        // 3. trA: fout -> foutT (3b+1), th2 q -> tqT (3b+2)
        transpose_trA<<<dim3(480, 4, 2 * G), dim3(256), 0, stream>>>(doh, wsh);
        // 4. trB: th2 k -> tkT (3b+0)
        transpose_trB<<<dim3(480, 4, G), dim3(256), 0, stream>>>(doh, wsh);
        // 5. t-attention + conv_p fused; tmp in-place over tqT (3b+2)
        attn1_fused<<<dim3(F_ * (T_ / 64), G), dim3(256), 71680, stream>>>(
            wsh + 2 * QH_, wsh, wsh + QH_, wsh + 2 * QH_, wsp, scsh, a_p,
            3 * QH, 3 * QH, 3 * QH, 3 * QH);
        // 6. out = transpose(tmp @ 3b+2) + inp
        transpose_hf_res<<<dim3(4, 480, G), dim3(256), 0, stream>>>(
            wsh + 2 * QH_, xb, dob, 3 * QH, QH, QH);
    }
}